// Round 14
// baseline (753.717 us; speedup 1.0000x reference)
//
#include <hip/hip_runtime.h>
#include <math.h>

#define NNODES 20000
#define NPAD   20096   // 157 * 128
#define NEDGES 160000
#define HIDDIM 128
#define NHEADS 8
#define NGRAPH 64
#define KC 384   // concatenated K (hi | lo | hi)
#define GXTILES 157

typedef short short8 __attribute__((ext_vector_type(8)));
typedef float floatx4 __attribute__((ext_vector_type(4)));
typedef unsigned short ushort4v __attribute__((ext_vector_type(4)));

__device__ inline unsigned short f2bf(float x) {
    unsigned u = __float_as_uint(x);
    u += 0x7fff + ((u >> 16) & 1);
    return (unsigned short)(u >> 16);
}
__device__ inline float bf2f(unsigned short h) {
    return __uint_as_float(((unsigned)h) << 16);
}

// ---------------- utility ----------------
__global__ __launch_bounds__(256) void zero_kernel(float* __restrict__ p, int n) {
    int i = blockIdx.x * blockDim.x + threadIdx.x;
    if (i < n) p[i] = 0.f;
}

// ---------------- CSR build ----------------
__global__ __launch_bounds__(256) void count_deg_kernel(const int* __restrict__ dst,
                                                        int* __restrict__ deg, int e) {
    int i = blockIdx.x * blockDim.x + threadIdx.x;
    if (i < e) atomicAdd(&deg[dst[i]], 1);
}

__global__ __launch_bounds__(256) void scan1_kernel(const int* __restrict__ deg,
                                                    int* __restrict__ chunk,
                                                    int* __restrict__ bsum, int n) {
    __shared__ int buf[256];
    int t = threadIdx.x;
    int i = blockIdx.x * 256 + t;
    int v = (i < n) ? deg[i] : 0;
    buf[t] = v;
    __syncthreads();
    for (int off = 1; off < 256; off <<= 1) {
        int tmp = (t >= off) ? buf[t - off] : 0;
        __syncthreads();
        buf[t] += tmp;
        __syncthreads();
    }
    if (i < n) chunk[i] = buf[t];
    if (t == 255) bsum[blockIdx.x] = buf[255];
}

__global__ __launch_bounds__(128) void scan2_kernel(int* __restrict__ bsum, int nb) {
    __shared__ int buf[128];
    int t = threadIdx.x;
    int v = (t < nb) ? bsum[t] : 0;
    buf[t] = v;
    __syncthreads();
    for (int off = 1; off < 128; off <<= 1) {
        int tmp = (t >= off) ? buf[t - off] : 0;
        __syncthreads();
        buf[t] += tmp;
        __syncthreads();
    }
    if (t < nb) bsum[t] = buf[t] - v;
}

__global__ __launch_bounds__(256) void scan3_kernel(const int* __restrict__ chunk,
                                                    const int* __restrict__ bsum,
                                                    int* __restrict__ offs, int n) {
    int i = blockIdx.x * 256 + threadIdx.x;
    if (i < n) offs[i + 1] = chunk[i] + bsum[i >> 8];
    if (i == 0) offs[0] = 0;
}

__global__ __launch_bounds__(256) void scatter_kernel(const int* __restrict__ src,
                                                      const int* __restrict__ dst,
                                                      const int* __restrict__ offs,
                                                      int* __restrict__ cursor,
                                                      int* __restrict__ csr_src, int e) {
    int i = blockIdx.x * blockDim.x + threadIdx.x;
    if (i < e) {
        int d = dst[i];
        int pos = offs[d] + atomicAdd(&cursor[d], 1);
        csr_src[pos] = src[i];
    }
}

// ---------------- weight prep ----------------
// Row map: [0,1152): layers0-2 qkv (li*384 + {q,k,v}*128 + j)
// [1152,1536): layers0-2 s (li*128 + j) ; [1536,1664): Wp ; [1664,1792): Ws3
// [1792,4864): layer3 qkv (h*384 + {q,k,v}*128 + j)
__global__ __launch_bounds__(128) void prep_w_kernel(
    const float* __restrict__ Wq, const float* __restrict__ Wk,
    const float* __restrict__ Wv, const float* __restrict__ Ws,
    const float* __restrict__ Wp, const float* __restrict__ Ws3,
    const float* __restrict__ Wq3, const float* __restrict__ Wk3,
    const float* __restrict__ Wv3, unsigned short* __restrict__ WtAll) {
    int id = blockIdx.x;
    int k = threadIdx.x;
    float w;
    if (id < 1152) {
        int li = id / 384, n = id % 384, sel = n >> 7, np = n & 127;
        const float* W = (sel == 0) ? Wq : (sel == 1) ? Wk : Wv;
        w = W[li * 16384 + k * 128 + np];
    } else if (id < 1536) {
        int r = id - 1152, li = r >> 7, np = r & 127;
        w = Ws[li * 16384 + k * 128 + np];
    } else if (id < 1664) {
        w = Wp[k * 128 + (id - 1536)];
    } else if (id < 1792) {
        w = Ws3[k * 128 + (id - 1664)];
    } else {
        int r = id - 1792, h = r / 384, j = r % 384, sel = j >> 7, jp = j & 127;
        const float* W = (sel == 0) ? Wq3 : (sel == 1) ? Wk3 : Wv3;
        w = W[k * 1024 + h * 128 + jp];
    }
    unsigned short hi = f2bf(w);
    unsigned short lo = f2bf(w - bf2f(hi));
    unsigned short* dst = WtAll + (size_t)id * KC;
    dst[k] = hi;
    dst[128 + k] = hi;
    dst[256 + k] = lo;
}

__global__ __launch_bounds__(256) void prep_bias_kernel(
    const float* __restrict__ bq, const float* __restrict__ bk,
    const float* __restrict__ bv, const float* __restrict__ bs,
    const float* __restrict__ bq3, const float* __restrict__ bk3,
    const float* __restrict__ bv3, float* __restrict__ bcat) {
    int id = blockIdx.x * 256 + threadIdx.x;
    if (id >= 4608) return;
    float v;
    if (id < 1152) {
        int li = id / 384, n = id % 384, sel = n >> 7, np = n & 127;
        const float* b = (sel == 0) ? bq : (sel == 1) ? bk : bv;
        v = b[li * 128 + np];
    } else if (id < 1536) {
        int r = id - 1152, li = r >> 7, np = r & 127;
        v = bs[li * 128 + np];
    } else {
        int r = id - 1536, h = r / 384, j = r % 384, sel = j >> 7, jp = j & 127;
        const float* b = (sel == 0) ? bq3 : (sel == 1) ? bk3 : bv3;
        v = b[h * 128 + jp];
    }
    bcat[id] = v;
}

// ---------------- activation -> split-bf16 A_cat ----------------
__global__ __launch_bounds__(256) void cat_from_kernel(const float* __restrict__ h,
                                                       unsigned short* __restrict__ Acat) {
    int idx = blockIdx.x * 256 + threadIdx.x;
    if (idx >= NPAD * HIDDIM) return;
    int r = idx >> 7, k = idx & 127;
    float x = (r < NNODES) ? h[idx] : 0.f;
    unsigned short hi = f2bf(x);
    unsigned short lo = f2bf(x - bf2f(hi));
    unsigned short* row = Acat + (size_t)r * KC;
    row[k] = hi;
    row[128 + k] = lo;
    row[256 + k] = hi;
}

// ---------------- MFMA GEMM (XCD swizzle, NONTEMPORAL stores) ----------------
// 1-D grid of 160*BY blocks; xcd = id&7, bx = (idx/BY)*8+xcd, by = idx%BY: all
// column passes of one 128-node A stripe stay on ONE XCD -> A L2-resident.
// Output is consumed by other kernels (other XCDs): stream it past L2 with
// nontemporal stores so the k-loop's A/W working set stays L2-resident.
template <typename OutT, int KG, int BY>
__global__ __launch_bounds__(256) void gemm_mfma_kernel(
    const unsigned short* __restrict__ Acat, const unsigned short* __restrict__ Wt,
    const float* __restrict__ bias, OutT* __restrict__ C, int M, int nrows) {
    int id = blockIdx.x;
    int xcd = id & 7;
    int idx = id >> 3;
    int bx = (idx / BY) * 8 + xcd;
    int by = idx % BY;
    if (bx >= GXTILES) return;
    int lane = threadIdx.x & 63;
    int wave = threadIdx.x >> 6;
    int nodeBase = bx * 128 + (wave & 1) * 64;
    int featBase = by * 128 + (wave >> 1) * 64;
    int m = lane & 15;
    int q = lane >> 4;
    int ko = q * 8;
    const unsigned short* wptr = Wt + (size_t)(featBase + m) * KC + ko;    // A operand
    const unsigned short* aptr = Acat + (size_t)(nodeBase + m) * KC + ko;  // B operand
    floatx4 acc[4][4];  // [feat tile r][node tile c]
#pragma unroll
    for (int r = 0; r < 4; ++r)
#pragma unroll
        for (int c = 0; c < 4; ++c) acc[r][c] = (floatx4){0.f, 0.f, 0.f, 0.f};
#pragma unroll
    for (int kg = 0; kg < KG; ++kg) {
        short8 a[4], b[4];
#pragma unroll
        for (int r = 0; r < 4; ++r) a[r] = *(const short8*)(wptr + (size_t)r * 16 * KC + kg * 32);
#pragma unroll
        for (int c = 0; c < 4; ++c) b[c] = *(const short8*)(aptr + (size_t)c * 16 * KC + kg * 32);
#pragma unroll
        for (int r = 0; r < 4; ++r)
#pragma unroll
            for (int c = 0; c < 4; ++c)
                acc[r][c] = __builtin_amdgcn_mfma_f32_16x16x32_bf16(a[r], b[c], acc[r][c], 0, 0, 0);
    }
    float4 bv[4];
#pragma unroll
    for (int r = 0; r < 4; ++r) bv[r] = *(const float4*)(bias + featBase + r * 16 + q * 4);
#pragma unroll
    for (int c = 0; c < 4; ++c) {
        int node = nodeBase + c * 16 + m;
        if (node < nrows) {
#pragma unroll
            for (int r = 0; r < 4; ++r) {
                int f0 = featBase + r * 16 + q * 4;
                float v0 = acc[r][c][0] + bv[r].x;
                float v1 = acc[r][c][1] + bv[r].y;
                float v2 = acc[r][c][2] + bv[r].z;
                float v3 = acc[r][c][3] + bv[r].w;
                if (sizeof(OutT) == 2) {
                    ushort4v o = {f2bf(v0), f2bf(v1), f2bf(v2), f2bf(v3)};
                    __builtin_nontemporal_store(o,
                        (ushort4v*)((unsigned short*)C + (size_t)node * M + f0));
                } else {
                    floatx4 o = {v0, v1, v2, v3};
                    __builtin_nontemporal_store(o,
                        (floatx4*)((float*)C + (size_t)node * M + f0));
                }
            }
        }
    }
}

// ---------------- attention layers 0-2: qkv bf16 [N][384], s fp32 [N][128] ----------------
__global__ __launch_bounds__(64) void attn_small_kernel(
    const unsigned short* __restrict__ qkv, const float* __restrict__ sfp,
    const float* __restrict__ Wb,
    const int* __restrict__ offs, const int* __restrict__ csr_src,
    float* __restrict__ out) {
    int i = blockIdx.x;
    int l = threadIdx.x;
    int g = l >> 5;
    int d0 = (l & 31) * 4;
    uint2 qraw = *(const uint2*)(qkv + (size_t)i * 384 + d0);
    float q0 = bf2f((unsigned short)(qraw.x & 0xffff)), q1 = bf2f((unsigned short)(qraw.x >> 16));
    float q2 = bf2f((unsigned short)(qraw.y & 0xffff)), q3 = bf2f((unsigned short)(qraw.y >> 16));
    int e0 = offs[i], e1 = offs[i + 1];
    float mm = -1e30f, lac = 0.f;
    float a0 = 0.f, a1 = 0.f, a2 = 0.f, a3 = 0.f;
    for (int e = e0 + g; e < e1; e += 2) {
        int sn = csr_src[e];
        const unsigned short* row = qkv + (size_t)sn * 384;
        uint2 kk = *(const uint2*)(row + 128 + d0);
        uint2 vv = *(const uint2*)(row + 256 + d0);
        float k0 = bf2f((unsigned short)(kk.x & 0xffff)), k1 = bf2f((unsigned short)(kk.x >> 16));
        float k2 = bf2f((unsigned short)(kk.y & 0xffff)), k3 = bf2f((unsigned short)(kk.y >> 16));
        float p = q0 * k0 + q1 * k1 + q2 * k2 + q3 * k3;
        p += __shfl_xor(p, 1);
        p += __shfl_xor(p, 2);
        float logit = p * 0.25f;
        float mnew = fmaxf(mm, logit);
        float sc = __expf(mm - mnew);
        float w = __expf(logit - mnew);
        float v0 = bf2f((unsigned short)(vv.x & 0xffff)), v1 = bf2f((unsigned short)(vv.x >> 16));
        float v2 = bf2f((unsigned short)(vv.y & 0xffff)), v3 = bf2f((unsigned short)(vv.y >> 16));
        a0 = a0 * sc + w * v0;
        a1 = a1 * sc + w * v1;
        a2 = a2 * sc + w * v2;
        a3 = a3 * sc + w * v3;
        lac = lac * sc + w;
        mm = mnew;
    }
    float mo = __shfl_xor(mm, 32), lo = __shfl_xor(lac, 32);
    float b0 = __shfl_xor(a0, 32), b1 = __shfl_xor(a1, 32);
    float b2 = __shfl_xor(a2, 32), b3 = __shfl_xor(a3, 32);
    float ms = fmaxf(mm, mo);
    float s0 = __expf(mm - ms), s1 = __expf(mo - ms);
    a0 = a0 * s0 + b0 * s1;
    a1 = a1 * s0 + b1 * s1;
    a2 = a2 * s0 + b2 * s1;
    a3 = a3 * s0 + b3 * s1;
    lac = lac * s0 + lo * s1;
    float inv = 1.f / (lac + 1e-16f);
    float o0 = a0 * inv, o1 = a1 * inv, o2 = a2 * inv, o3 = a3 * inv;
    float4 rv = *(const float4*)(sfp + (size_t)i * HIDDIM + d0);
    float part = o0 * Wb[d0] + o1 * Wb[d0 + 1] + o2 * Wb[d0 + 2] + o3 * Wb[d0 + 3]
               + rv.x * Wb[128 + d0] + rv.y * Wb[128 + d0 + 1]
               + rv.z * Wb[128 + d0 + 2] + rv.w * Wb[128 + d0 + 3]
               + (o0 - rv.x) * Wb[256 + d0] + (o1 - rv.y) * Wb[256 + d0 + 1]
               + (o2 - rv.z) * Wb[256 + d0 + 2] + (o3 - rv.w) * Wb[256 + d0 + 3];
    if (g) part = 0.f;
#pragma unroll
    for (int msk = 1; msk <= 32; msk <<= 1) part += __shfl_xor(part, msk);
    float gg = 1.f / (1.f + __expf(-part));
    if (g == 0) {
        floatx4 o4 = {gg * rv.x + (1.f - gg) * o0, gg * rv.y + (1.f - gg) * o1,
                      gg * rv.z + (1.f - gg) * o2, gg * rv.w + (1.f - gg) * o3};
        __builtin_nontemporal_store(o4, (floatx4*)(out + (size_t)i * HIDDIM + d0));
    }
}

// ---------------- attention layer 3: merged qkv3 bf16 [N][3072] (8 heads) ----------------
__global__ __launch_bounds__(64) void attn_big_kernel(
    const unsigned short* __restrict__ qkv3,
    const int* __restrict__ offs, const int* __restrict__ csr_src,
    unsigned short* __restrict__ obuf8) {
    int i = blockIdx.x;
    int y = blockIdx.y;   // head 0..7
    int l = threadIdx.x;
    int g = l >> 4;
    int s = l & 15;
    uint4 qq = *(const uint4*)(qkv3 + (size_t)i * 3072 + y * 384 + 8 * s);
    float q0 = bf2f((unsigned short)(qq.x & 0xffff)), q1 = bf2f((unsigned short)(qq.x >> 16));
    float q2 = bf2f((unsigned short)(qq.y & 0xffff)), q3f = bf2f((unsigned short)(qq.y >> 16));
    float q4 = bf2f((unsigned short)(qq.z & 0xffff)), q5 = bf2f((unsigned short)(qq.z >> 16));
    float q6 = bf2f((unsigned short)(qq.w & 0xffff)), q7 = bf2f((unsigned short)(qq.w >> 16));
    int e0 = offs[i], e1 = offs[i + 1];
    float mm = -1e30f, lac = 0.f;
    float ac[8];
#pragma unroll
    for (int j = 0; j < 8; ++j) ac[j] = 0.f;
    for (int e = e0 + g; e < e1; e += 4) {
        int sn = csr_src[e];
        const unsigned short* row = qkv3 + (size_t)sn * 3072 + y * 384 + 8 * s;
        uint4 kk = *(const uint4*)(row + 128);
        uint4 vv = *(const uint4*)(row + 256);
        float k0 = bf2f((unsigned short)(kk.x & 0xffff)), k1 = bf2f((unsigned short)(kk.x >> 16));
        float k2 = bf2f((unsigned short)(kk.y & 0xffff)), k3 = bf2f((unsigned short)(kk.y >> 16));
        float k4 = bf2f((unsigned short)(kk.z & 0xffff)), k5 = bf2f((unsigned short)(kk.z >> 16));
        float k6 = bf2f((unsigned short)(kk.w & 0xffff)), k7 = bf2f((unsigned short)(kk.w >> 16));
        float p = q0 * k0 + q1 * k1 + q2 * k2 + q3f * k3
                + q4 * k4 + q5 * k5 + q6 * k6 + q7 * k7;
        p += __shfl_xor(p, 1);
        p += __shfl_xor(p, 2);
        p += __shfl_xor(p, 4);
        p += __shfl_xor(p, 8);
        float logit = p * 0.08838834764831845f;
        float mnew = fmaxf(mm, logit);
        float sc = __expf(mm - mnew);
        float w = __expf(logit - mnew);
        float v0 = bf2f((unsigned short)(vv.x & 0xffff)), v1 = bf2f((unsigned short)(vv.x >> 16));
        float v2 = bf2f((unsigned short)(vv.y & 0xffff)), v3 = bf2f((unsigned short)(vv.y >> 16));
        float v4 = bf2f((unsigned short)(vv.z & 0xffff)), v5 = bf2f((unsigned short)(vv.z >> 16));
        float v6 = bf2f((unsigned short)(vv.w & 0xffff)), v7 = bf2f((unsigned short)(vv.w >> 16));
        ac[0] = ac[0] * sc + w * v0; ac[1] = ac[1] * sc + w * v1;
        ac[2] = ac[2] * sc + w * v2; ac[3] = ac[3] * sc + w * v3;
        ac[4] = ac[4] * sc + w * v4; ac[5] = ac[5] * sc + w * v5;
        ac[6] = ac[6] * sc + w * v6; ac[7] = ac[7] * sc + w * v7;
        lac = lac * sc + w;
        mm = mnew;
    }
#pragma unroll
    for (int msk = 16; msk <= 32; msk <<= 1) {
        float mo = __shfl_xor(mm, msk), lo = __shfl_xor(lac, msk);
        float bo[8];
#pragma unroll
        for (int j = 0; j < 8; ++j) bo[j] = __shfl_xor(ac[j], msk);
        float ms = fmaxf(mm, mo);
        float s0 = __expf(mm - ms), s1 = __expf(mo - ms);
#pragma unroll
        for (int j = 0; j < 8; ++j) ac[j] = ac[j] * s0 + bo[j] * s1;
        lac = lac * s0 + lo * s1;
        mm = ms;
    }
    if (g == 0) {
        float inv = 1.f / (lac + 1e-16f);
        ushort4v w0 = {f2bf(ac[0] * inv), f2bf(ac[1] * inv), f2bf(ac[2] * inv), f2bf(ac[3] * inv)};
        ushort4v w1 = {f2bf(ac[4] * inv), f2bf(ac[5] * inv), f2bf(ac[6] * inv), f2bf(ac[7] * inv)};
        unsigned short* o = obuf8 + ((size_t)y * NNODES + i) * HIDDIM + 8 * s;
        __builtin_nontemporal_store(w0, (ushort4v*)o);
        __builtin_nontemporal_store(w1, (ushort4v*)(o + 4));
    }
}

// ---------------- beta gate layer 3 (head mean over 8 bf16 slices) ----------------
__global__ __launch_bounds__(128) void beta3_kernel(const unsigned short* __restrict__ obuf8,
                                                    const float* __restrict__ s,
                                                    const float* __restrict__ Wb,
                                                    float* __restrict__ out) {
    int i = blockIdx.x, t = threadIdx.x;
    float o = 0.f;
#pragma unroll
    for (int y = 0; y < 8; ++y) o += bf2f(obuf8[((size_t)y * NNODES + i) * HIDDIM + t]);
    o *= 0.125f;
    float r = s[(size_t)i * HIDDIM + t];
    float part = o * Wb[t] + r * Wb[128 + t] + (o - r) * Wb[256 + t];
#pragma unroll
    for (int msk = 1; msk <= 32; msk <<= 1) part += __shfl_xor(part, msk);
    __shared__ float wsum[2];
    if ((t & 63) == 0) wsum[t >> 6] = part;
    __syncthreads();
    float tot = wsum[0] + wsum[1];
    float g = 1.f / (1.f + __expf(-tot));
    out[(size_t)i * HIDDIM + t] = g * r + (1.f - g) * o;
}

// ---------------- batchnorm ----------------
__global__ __launch_bounds__(128) void bn_stats_kernel(const float* __restrict__ x,
                                                       float* __restrict__ stat, int n) {
    int t = threadIdx.x;
    float s = 0.f, sq = 0.f;
    for (int i = blockIdx.x; i < n; i += gridDim.x) {
        float v = x[(size_t)i * HIDDIM + t];
        s += v;
        sq += v * v;
    }
    atomicAdd(&stat[t], s);
    atomicAdd(&stat[HIDDIM + t], sq);
}

__global__ __launch_bounds__(128) void bn_apply_kernel(float* __restrict__ x,
                                                       const float* __restrict__ stat,
                                                       const float* __restrict__ gamma,
                                                       const float* __restrict__ beta, int n,
                                                       unsigned short* __restrict__ cat) {
    int t = threadIdx.x;
    float mu = stat[t] / (float)n;
    float var = stat[HIDDIM + t] / (float)n - mu * mu;
    float rs = rsqrtf(var + 1e-5f);
    float g = gamma[t], b = beta[t];
    for (int i = blockIdx.x; i < n; i += gridDim.x) {
        float v = x[(size_t)i * HIDDIM + t];
        v = fmaxf((v - mu) * rs * g + b, 0.f);
        x[(size_t)i * HIDDIM + t] = v;
        if (cat) {
            unsigned short hi = f2bf(v);
            unsigned short lo = f2bf(v - bf2f(hi));
            unsigned short* row = cat + (size_t)i * KC;
            row[t] = hi;
            row[128 + t] = lo;
            row[256 + t] = hi;
        }
    }
}

// ---------------- pool ----------------
__global__ __launch_bounds__(256) void gb_kernel(const int* __restrict__ batch,
                                                 int* __restrict__ gs,
                                                 int* __restrict__ ge, int n) {
    int i = blockIdx.x * 256 + threadIdx.x;
    if (i >= n) return;
    int b = batch[i];
    if (i == 0 || batch[i - 1] != b) gs[b] = i;
    if (i == n - 1 || batch[i + 1] != b) ge[b] = i + 1;
}

__global__ __launch_bounds__(256) void pool_part_kernel(const float* __restrict__ x,
                                                        const int* __restrict__ gs,
                                                        const int* __restrict__ ge,
                                                        float* __restrict__ out) {
    int g = blockIdx.x, c = blockIdx.y;
    int t = threadIdx.x;
    int f = t & 127, half = t >> 7;
    int s = gs[g], e = ge[g];
    float acc = 0.f;
    for (int i = s + 2 * c + half; i < e; i += 16) acc += x[(size_t)i * HIDDIM + f];
    __shared__ float l0[128];
    if (half == 0) l0[f] = acc;
    __syncthreads();
    if (half == 1) atomicAdd(&out[g * HIDDIM + f], l0[f] + acc);
}

__global__ __launch_bounds__(128) void pool_div_kernel(float* __restrict__ out,
                                                       const int* __restrict__ gs,
                                                       const int* __restrict__ ge) {
    int g = blockIdx.x, t = threadIdx.x;
    int c = ge[g] - gs[g];
    out[g * HIDDIM + t] /= (float)(c > 0 ? c : 1);
}

// ---------------- host ----------------
extern "C" void kernel_launch(void* const* d_in, const int* in_sizes, int n_in,
                              void* d_out, int out_size, void* d_ws, size_t ws_size,
                              hipStream_t stream) {
    const float* x       = (const float*)d_in[0];
    const int*   ei      = (const int*)d_in[1];
    const int*   batch   = (const int*)d_in[2];
    const float* Wp      = (const float*)d_in[3];
    const float* bp      = (const float*)d_in[4];
    const float* Wq      = (const float*)d_in[5];
    const float* bq      = (const float*)d_in[6];
    const float* Wk      = (const float*)d_in[7];
    const float* bk      = (const float*)d_in[8];
    const float* Wv      = (const float*)d_in[9];
    const float* bv      = (const float*)d_in[10];
    const float* Ws      = (const float*)d_in[11];
    const float* bs      = (const float*)d_in[12];
    const float* Wbeta   = (const float*)d_in[13];
    const float* Wq3     = (const float*)d_in[14];
    const float* bq3     = (const float*)d_in[15];
    const float* Wk3     = (const float*)d_in[16];
    const float* bk3     = (const float*)d_in[17];
    const float* Wv3     = (const float*)d_in[18];
    const float* bv3     = (const float*)d_in[19];
    const float* Ws3     = (const float*)d_in[20];
    const float* bs3     = (const float*)d_in[21];
    const float* Wbeta3  = (const float*)d_in[22];
    const float* bn_gamma = (const float*)d_in[23];
    const float* bn_beta  = (const float*)d_in[24];
    float* out = (float*)d_out;

    const int* esrc = ei;
    const int* edst = ei + NEDGES;

    char* wpc = (char*)d_ws;
    auto alloc = [&](size_t nbytes) -> char* {
        char* p = wpc;
        wpc += (nbytes + 255) & ~(size_t)255;
        return p;
    };
    unsigned short* Acat  = (unsigned short*)alloc((size_t)NPAD * KC * 2);      // 15.4 MB
    unsigned short* WtAll = (unsigned short*)alloc((size_t)4864 * KC * 2);      // 3.7 MB
    float* bcat   = (float*)alloc(4608 * 4);
    unsigned short* qkv3b = (unsigned short*)alloc((size_t)NNODES * 3072 * 2);  // 122.9 MB
    float* sfp    = (float*)alloc((size_t)NNODES * HIDDIM * 4);                 // 10.2 MB
    unsigned short* obuf8 = (unsigned short*)alloc((size_t)8 * NNODES * HIDDIM * 2);  // 41 MB
    float* hbuf   = (float*)alloc((size_t)NNODES * HIDDIM * 4);
    float* obuf   = (float*)alloc((size_t)NNODES * HIDDIM * 4);
    float* sb     = (float*)alloc((size_t)NNODES * HIDDIM * 4);
    int*   deg    = (int*)alloc((2 * NNODES + 128 + 4 * 256) * 4);
    int*   cursor = deg + NNODES;
    int*   gs     = deg + 2 * NNODES;
    int*   ge     = gs + NGRAPH;
    float* bnstat4 = (float*)(deg + 2 * NNODES + 128);
    int*   chunk  = (int*)alloc(NNODES * 4);
    int*   bsum   = (int*)alloc(128 * 4);
    int*   offs   = (int*)alloc((NNODES + 1) * 4);
    int*   csrsrc = (int*)alloc(NEDGES * 4);

    unsigned short* WtQKV = WtAll;                       // [3][384][KC]
    unsigned short* WtS   = WtAll + (size_t)1152 * KC;   // [3][128][KC]
    unsigned short* Wpt   = WtAll + (size_t)1536 * KC;
    unsigned short* Ws3t  = WtAll + (size_t)1664 * KC;
    unsigned short* Wt3   = WtAll + (size_t)1792 * KC;   // [8][384][KC]
    float* bQKV = bcat;          // [3][384]
    float* bS   = bcat + 1152;   // [3][128]
    float* b3   = bcat + 1536;   // [3072]
    unsigned short* qkvb = qkv3b;  // layers 0-2 alias: [N][384]

    const int TB = 256;
    const int ZWORDS = 2 * NNODES + 128 + 4 * 256;
    zero_kernel<<<(ZWORDS + TB - 1) / TB, TB, 0, stream>>>((float*)deg, ZWORDS);
    count_deg_kernel<<<(NEDGES + TB - 1) / TB, TB, 0, stream>>>(edst, deg, NEDGES);
    const int NB = (NNODES + 255) / 256;
    scan1_kernel<<<NB, 256, 0, stream>>>(deg, chunk, bsum, NNODES);
    scan2_kernel<<<1, 128, 0, stream>>>(bsum, NB);
    scan3_kernel<<<NB, 256, 0, stream>>>(chunk, bsum, offs, NNODES);
    scatter_kernel<<<(NEDGES + TB - 1) / TB, TB, 0, stream>>>(esrc, edst, offs, cursor, csrsrc, NEDGES);
    gb_kernel<<<(NNODES + TB - 1) / TB, TB, 0, stream>>>(batch, gs, ge, NNODES);

    prep_w_kernel<<<4864, 128, 0, stream>>>(Wq, Wk, Wv, Ws, Wp, Ws3, Wq3, Wk3, Wv3, WtAll);
    prep_bias_kernel<<<(4608 + TB - 1) / TB, TB, 0, stream>>>(bq, bk, bv, bs, bq3, bk3, bv3, bcat);

    const int CATB = (NPAD * HIDDIM + TB - 1) / TB;
    const int GSW = 8 * ((GXTILES + 7) / 8);  // 160 swizzled x-slots

    cat_from_kernel<<<CATB, TB, 0, stream>>>(x, Acat);
    gemm_mfma_kernel<float, 12, 1><<<GSW * 1, 256, 0, stream>>>(Acat, Wpt, bp, hbuf, 128, NNODES);
    cat_from_kernel<<<CATB, TB, 0, stream>>>(hbuf, Acat);

    for (int li = 0; li < 3; ++li) {
        gemm_mfma_kernel<unsigned short, 8, 3><<<GSW * 3, 256, 0, stream>>>(
            Acat, WtQKV + (size_t)li * 384 * KC, bQKV + li * 384, qkvb, 384, NNODES);
        gemm_mfma_kernel<float, 12, 1><<<GSW * 1, 256, 0, stream>>>(
            Acat, WtS + (size_t)li * 128 * KC, bS + li * 128, sfp, 128, NNODES);
        attn_small_kernel<<<NNODES, 64, 0, stream>>>(qkvb, sfp, Wbeta + li * 384,
                                                     offs, csrsrc, obuf);
        float* st = bnstat4 + li * 256;
        bn_stats_kernel<<<640, 128, 0, stream>>>(obuf, st, NNODES);
        bn_apply_kernel<<<512, 128, 0, stream>>>(obuf, st, bn_gamma + li * HIDDIM,
                                                 bn_beta + li * HIDDIM, NNODES, Acat);
    }

    // ---- layer 3: single merged q|k|v GEMM (8 heads) + single attention ----
    gemm_mfma_kernel<unsigned short, 8, 24><<<GSW * 24, 256, 0, stream>>>(
        Acat, Wt3, b3, qkv3b, 3072, NNODES);
    attn_big_kernel<<<dim3(NNODES, 8), 64, 0, stream>>>(qkv3b, offs, csrsrc, obuf8);
    gemm_mfma_kernel<float, 12, 1><<<GSW * 1, 256, 0, stream>>>(Acat, Ws3t, bs3, sb, 128, NNODES);
    beta3_kernel<<<NNODES, 128, 0, stream>>>(obuf8, sb, Wbeta3, hbuf);
    float* st3 = bnstat4 + 3 * 256;
    bn_stats_kernel<<<640, 128, 0, stream>>>(hbuf, st3, NNODES);
    bn_apply_kernel<<<512, 128, 0, stream>>>(hbuf, st3, bn_gamma + 3 * HIDDIM,
                                             bn_beta + 3 * HIDDIM, NNODES, (unsigned short*)0);

    zero_kernel<<<(NGRAPH * HIDDIM + TB - 1) / TB, TB, 0, stream>>>(out, NGRAPH * HIDDIM);
    pool_part_kernel<<<dim3(NGRAPH, 8), 256, 0, stream>>>(hbuf, gs, ge, out);
    pool_div_kernel<<<NGRAPH, 128, 0, stream>>>(out, gs, ge);
}

// Round 15
// 740.413 us; speedup vs baseline: 1.0180x; 1.0180x over previous
//
#include <hip/hip_runtime.h>
#include <math.h>

#define NNODES 20000
#define NPAD   20096   // 157 * 128
#define NEDGES 160000
#define HIDDIM 128
#define NHEADS 8
#define NGRAPH 64
#define KC 384   // concatenated K (hi | lo | hi)
#define GXTILES 157

typedef short short8 __attribute__((ext_vector_type(8)));
typedef float floatx4 __attribute__((ext_vector_type(4)));
typedef unsigned short ushort4v __attribute__((ext_vector_type(4)));

__device__ inline unsigned short f2bf(float x) {
    unsigned u = __float_as_uint(x);
    u += 0x7fff + ((u >> 16) & 1);
    return (unsigned short)(u >> 16);
}
__device__ inline float bf2f(unsigned short h) {
    return __uint_as_float(((unsigned)h) << 16);
}

// ---------------- utility ----------------
__global__ __launch_bounds__(256) void zero_kernel(float* __restrict__ p, int n) {
    int i = blockIdx.x * blockDim.x + threadIdx.x;
    if (i < n) p[i] = 0.f;
}

// ---------------- CSR build ----------------
__global__ __launch_bounds__(256) void count_deg_kernel(const int* __restrict__ dst,
                                                        int* __restrict__ deg, int e) {
    int i = blockIdx.x * blockDim.x + threadIdx.x;
    if (i < e) atomicAdd(&deg[dst[i]], 1);
}

__global__ __launch_bounds__(256) void scan1_kernel(const int* __restrict__ deg,
                                                    int* __restrict__ chunk,
                                                    int* __restrict__ bsum, int n) {
    __shared__ int buf[256];
    int t = threadIdx.x;
    int i = blockIdx.x * 256 + t;
    int v = (i < n) ? deg[i] : 0;
    buf[t] = v;
    __syncthreads();
    for (int off = 1; off < 256; off <<= 1) {
        int tmp = (t >= off) ? buf[t - off] : 0;
        __syncthreads();
        buf[t] += tmp;
        __syncthreads();
    }
    if (i < n) chunk[i] = buf[t];
    if (t == 255) bsum[blockIdx.x] = buf[255];
}

__global__ __launch_bounds__(128) void scan2_kernel(int* __restrict__ bsum, int nb) {
    __shared__ int buf[128];
    int t = threadIdx.x;
    int v = (t < nb) ? bsum[t] : 0;
    buf[t] = v;
    __syncthreads();
    for (int off = 1; off < 128; off <<= 1) {
        int tmp = (t >= off) ? buf[t - off] : 0;
        __syncthreads();
        buf[t] += tmp;
        __syncthreads();
    }
    if (t < nb) bsum[t] = buf[t] - v;
}

__global__ __launch_bounds__(256) void scan3_kernel(const int* __restrict__ chunk,
                                                    const int* __restrict__ bsum,
                                                    int* __restrict__ offs, int n) {
    int i = blockIdx.x * 256 + threadIdx.x;
    if (i < n) offs[i + 1] = chunk[i] + bsum[i >> 8];
    if (i == 0) offs[0] = 0;
}

__global__ __launch_bounds__(256) void scatter_kernel(const int* __restrict__ src,
                                                      const int* __restrict__ dst,
                                                      const int* __restrict__ offs,
                                                      int* __restrict__ cursor,
                                                      int* __restrict__ csr_src, int e) {
    int i = blockIdx.x * blockDim.x + threadIdx.x;
    if (i < e) {
        int d = dst[i];
        int pos = offs[d] + atomicAdd(&cursor[d], 1);
        csr_src[pos] = src[i];
    }
}

// ---------------- weight prep ----------------
// Row map: [0,1152): layers0-2 qkv (li*384 + {q,k,v}*128 + j)
// [1152,1536): layers0-2 s (li*128 + j) ; [1536,1664): Wp ; [1664,1792): Ws3
// [1792,4864): layer3 qkv (h*384 + {q,k,v}*128 + j)
__global__ __launch_bounds__(128) void prep_w_kernel(
    const float* __restrict__ Wq, const float* __restrict__ Wk,
    const float* __restrict__ Wv, const float* __restrict__ Ws,
    const float* __restrict__ Wp, const float* __restrict__ Ws3,
    const float* __restrict__ Wq3, const float* __restrict__ Wk3,
    const float* __restrict__ Wv3, unsigned short* __restrict__ WtAll) {
    int id = blockIdx.x;
    int k = threadIdx.x;
    float w;
    if (id < 1152) {
        int li = id / 384, n = id % 384, sel = n >> 7, np = n & 127;
        const float* W = (sel == 0) ? Wq : (sel == 1) ? Wk : Wv;
        w = W[li * 16384 + k * 128 + np];
    } else if (id < 1536) {
        int r = id - 1152, li = r >> 7, np = r & 127;
        w = Ws[li * 16384 + k * 128 + np];
    } else if (id < 1664) {
        w = Wp[k * 128 + (id - 1536)];
    } else if (id < 1792) {
        w = Ws3[k * 128 + (id - 1664)];
    } else {
        int r = id - 1792, h = r / 384, j = r % 384, sel = j >> 7, jp = j & 127;
        const float* W = (sel == 0) ? Wq3 : (sel == 1) ? Wk3 : Wv3;
        w = W[k * 1024 + h * 128 + jp];
    }
    unsigned short hi = f2bf(w);
    unsigned short lo = f2bf(w - bf2f(hi));
    unsigned short* dst = WtAll + (size_t)id * KC;
    dst[k] = hi;
    dst[128 + k] = hi;
    dst[256 + k] = lo;
}

__global__ __launch_bounds__(256) void prep_bias_kernel(
    const float* __restrict__ bq, const float* __restrict__ bk,
    const float* __restrict__ bv, const float* __restrict__ bs,
    const float* __restrict__ bq3, const float* __restrict__ bk3,
    const float* __restrict__ bv3, float* __restrict__ bcat) {
    int id = blockIdx.x * 256 + threadIdx.x;
    if (id >= 4608) return;
    float v;
    if (id < 1152) {
        int li = id / 384, n = id % 384, sel = n >> 7, np = n & 127;
        const float* b = (sel == 0) ? bq : (sel == 1) ? bk : bv;
        v = b[li * 128 + np];
    } else if (id < 1536) {
        int r = id - 1152, li = r >> 7, np = r & 127;
        v = bs[li * 128 + np];
    } else {
        int r = id - 1536, h = r / 384, j = r % 384, sel = j >> 7, jp = j & 127;
        const float* b = (sel == 0) ? bq3 : (sel == 1) ? bk3 : bv3;
        v = b[h * 128 + jp];
    }
    bcat[id] = v;
}

// ---------------- activation -> split-bf16 A_cat ----------------
__global__ __launch_bounds__(256) void cat_from_kernel(const float* __restrict__ h,
                                                       unsigned short* __restrict__ Acat) {
    int idx = blockIdx.x * 256 + threadIdx.x;
    if (idx >= NPAD * HIDDIM) return;
    int r = idx >> 7, k = idx & 127;
    float x = (r < NNODES) ? h[idx] : 0.f;
    unsigned short hi = f2bf(x);
    unsigned short lo = f2bf(x - bf2f(hi));
    unsigned short* row = Acat + (size_t)r * KC;
    row[k] = hi;
    row[128 + k] = lo;
    row[256 + k] = hi;
}

// ---------------- MFMA GEMM (XCD swizzle, direct stores, line-grouped epilogue) ----------------
template <typename OutT, int KG, int BY>
__global__ __launch_bounds__(256) void gemm_mfma_kernel(
    const unsigned short* __restrict__ Acat, const unsigned short* __restrict__ Wt,
    const float* __restrict__ bias, OutT* __restrict__ C, int M, int nrows) {
    int id = blockIdx.x;
    int xcd = id & 7;
    int idx = id >> 3;
    int bx = (idx / BY) * 8 + xcd;
    int by = idx % BY;
    if (bx >= GXTILES) return;
    int lane = threadIdx.x & 63;
    int wave = threadIdx.x >> 6;
    int nodeBase = bx * 128 + (wave & 1) * 64;
    int featBase = by * 128 + (wave >> 1) * 64;
    int m = lane & 15;
    int q = lane >> 4;
    int ko = q * 8;
    const unsigned short* wptr = Wt + (size_t)(featBase + m) * KC + ko;    // A operand
    const unsigned short* aptr = Acat + (size_t)(nodeBase + m) * KC + ko;  // B operand
    floatx4 acc[4][4];  // [feat tile r][node tile c]
#pragma unroll
    for (int r = 0; r < 4; ++r)
#pragma unroll
        for (int c = 0; c < 4; ++c) acc[r][c] = (floatx4){0.f, 0.f, 0.f, 0.f};
#pragma unroll
    for (int kg = 0; kg < KG; ++kg) {
        short8 a[4], b[4];
#pragma unroll
        for (int r = 0; r < 4; ++r) a[r] = *(const short8*)(wptr + (size_t)r * 16 * KC + kg * 32);
#pragma unroll
        for (int c = 0; c < 4; ++c) b[c] = *(const short8*)(aptr + (size_t)c * 16 * KC + kg * 32);
#pragma unroll
        for (int r = 0; r < 4; ++r)
#pragma unroll
            for (int c = 0; c < 4; ++c)
                acc[r][c] = __builtin_amdgcn_mfma_f32_16x16x32_bf16(a[r], b[c], acc[r][c], 0, 0, 0);
    }
    float4 bv[4];
#pragma unroll
    for (int r = 0; r < 4; ++r) bv[r] = *(const float4*)(bias + featBase + r * 16 + q * 4);
#pragma unroll
    for (int c = 0; c < 4; ++c) {
        int node = nodeBase + c * 16 + m;
        if (node < nrows) {
#pragma unroll
            for (int r = 0; r < 4; ++r) {
                int f0 = featBase + r * 16 + q * 4;
                float v0 = acc[r][c][0] + bv[r].x;
                float v1 = acc[r][c][1] + bv[r].y;
                float v2 = acc[r][c][2] + bv[r].z;
                float v3 = acc[r][c][3] + bv[r].w;
                if (sizeof(OutT) == 2) {
                    ushort4v o = {f2bf(v0), f2bf(v1), f2bf(v2), f2bf(v3)};
                    *(ushort4v*)((unsigned short*)C + (size_t)node * M + f0) = o;
                } else {
                    float4 o = {v0, v1, v2, v3};
                    *(float4*)((float*)C + (size_t)node * M + f0) = o;
                }
            }
        }
    }
}

// ---------------- attention layers 0-2: qkv bf16 [N][384], s fp32 [N][128] ----------------
__global__ __launch_bounds__(64) void attn_small_kernel(
    const unsigned short* __restrict__ qkv, const float* __restrict__ sfp,
    const float* __restrict__ Wb,
    const int* __restrict__ offs, const int* __restrict__ csr_src,
    float* __restrict__ out) {
    int i = blockIdx.x;
    int l = threadIdx.x;
    int g = l >> 5;
    int d0 = (l & 31) * 4;
    uint2 qraw = *(const uint2*)(qkv + (size_t)i * 384 + d0);
    float q0 = bf2f((unsigned short)(qraw.x & 0xffff)), q1 = bf2f((unsigned short)(qraw.x >> 16));
    float q2 = bf2f((unsigned short)(qraw.y & 0xffff)), q3 = bf2f((unsigned short)(qraw.y >> 16));
    int e0 = offs[i], e1 = offs[i + 1];
    float mm = -1e30f, lac = 0.f;
    float a0 = 0.f, a1 = 0.f, a2 = 0.f, a3 = 0.f;
    for (int e = e0 + g; e < e1; e += 2) {
        int sn = csr_src[e];
        const unsigned short* row = qkv + (size_t)sn * 384;
        uint2 kk = *(const uint2*)(row + 128 + d0);
        uint2 vv = *(const uint2*)(row + 256 + d0);
        float k0 = bf2f((unsigned short)(kk.x & 0xffff)), k1 = bf2f((unsigned short)(kk.x >> 16));
        float k2 = bf2f((unsigned short)(kk.y & 0xffff)), k3 = bf2f((unsigned short)(kk.y >> 16));
        float p = q0 * k0 + q1 * k1 + q2 * k2 + q3 * k3;
        p += __shfl_xor(p, 1);
        p += __shfl_xor(p, 2);
        float logit = p * 0.25f;
        float mnew = fmaxf(mm, logit);
        float sc = __expf(mm - mnew);
        float w = __expf(logit - mnew);
        float v0 = bf2f((unsigned short)(vv.x & 0xffff)), v1 = bf2f((unsigned short)(vv.x >> 16));
        float v2 = bf2f((unsigned short)(vv.y & 0xffff)), v3 = bf2f((unsigned short)(vv.y >> 16));
        a0 = a0 * sc + w * v0;
        a1 = a1 * sc + w * v1;
        a2 = a2 * sc + w * v2;
        a3 = a3 * sc + w * v3;
        lac = lac * sc + w;
        mm = mnew;
    }
    float mo = __shfl_xor(mm, 32), lo = __shfl_xor(lac, 32);
    float b0 = __shfl_xor(a0, 32), b1 = __shfl_xor(a1, 32);
    float b2 = __shfl_xor(a2, 32), b3 = __shfl_xor(a3, 32);
    float ms = fmaxf(mm, mo);
    float s0 = __expf(mm - ms), s1 = __expf(mo - ms);
    a0 = a0 * s0 + b0 * s1;
    a1 = a1 * s0 + b1 * s1;
    a2 = a2 * s0 + b2 * s1;
    a3 = a3 * s0 + b3 * s1;
    lac = lac * s0 + lo * s1;
    float inv = 1.f / (lac + 1e-16f);
    float o0 = a0 * inv, o1 = a1 * inv, o2 = a2 * inv, o3 = a3 * inv;
    float4 rv = *(const float4*)(sfp + (size_t)i * HIDDIM + d0);
    float part = o0 * Wb[d0] + o1 * Wb[d0 + 1] + o2 * Wb[d0 + 2] + o3 * Wb[d0 + 3]
               + rv.x * Wb[128 + d0] + rv.y * Wb[128 + d0 + 1]
               + rv.z * Wb[128 + d0 + 2] + rv.w * Wb[128 + d0 + 3]
               + (o0 - rv.x) * Wb[256 + d0] + (o1 - rv.y) * Wb[256 + d0 + 1]
               + (o2 - rv.z) * Wb[256 + d0 + 2] + (o3 - rv.w) * Wb[256 + d0 + 3];
    if (g) part = 0.f;
#pragma unroll
    for (int msk = 1; msk <= 32; msk <<= 1) part += __shfl_xor(part, msk);
    float gg = 1.f / (1.f + __expf(-part));
    if (g == 0) {
        float4 o4 = {gg * rv.x + (1.f - gg) * o0, gg * rv.y + (1.f - gg) * o1,
                     gg * rv.z + (1.f - gg) * o2, gg * rv.w + (1.f - gg) * o3};
        *(float4*)(out + (size_t)i * HIDDIM + d0) = o4;
    }
}

// ---------------- attention layer 3 FUSED with beta gate ----------------
// Block = one node, 512 threads = 8 waves, wave y = head y.
// Per-head: 4 edge slots x 16 lanes x 8 dims (same as before). Head outputs
// land in LDS Os[8][128]; head-mean + beta gate computed in-block; writes hbuf.
__global__ __launch_bounds__(512) void attn_big_fused_kernel(
    const unsigned short* __restrict__ qkv3, const float* __restrict__ sfp,
    const float* __restrict__ Wb,
    const int* __restrict__ offs, const int* __restrict__ csr_src,
    float* __restrict__ out) {
    __shared__ float Os[NHEADS][HIDDIM];
    __shared__ float wsum[2];
    int i = blockIdx.x;
    int y = threadIdx.x >> 6;  // head
    int l = threadIdx.x & 63;
    int g = l >> 4;
    int s = l & 15;
    uint4 qq = *(const uint4*)(qkv3 + (size_t)i * 3072 + y * 384 + 8 * s);
    float q0 = bf2f((unsigned short)(qq.x & 0xffff)), q1 = bf2f((unsigned short)(qq.x >> 16));
    float q2 = bf2f((unsigned short)(qq.y & 0xffff)), q3f = bf2f((unsigned short)(qq.y >> 16));
    float q4 = bf2f((unsigned short)(qq.z & 0xffff)), q5 = bf2f((unsigned short)(qq.z >> 16));
    float q6 = bf2f((unsigned short)(qq.w & 0xffff)), q7 = bf2f((unsigned short)(qq.w >> 16));
    int e0 = offs[i], e1 = offs[i + 1];
    float mm = -1e30f, lac = 0.f;
    float ac[8];
#pragma unroll
    for (int j = 0; j < 8; ++j) ac[j] = 0.f;
    for (int e = e0 + g; e < e1; e += 4) {
        int sn = csr_src[e];
        const unsigned short* row = qkv3 + (size_t)sn * 3072 + y * 384 + 8 * s;
        uint4 kk = *(const uint4*)(row + 128);
        uint4 vv = *(const uint4*)(row + 256);
        float k0 = bf2f((unsigned short)(kk.x & 0xffff)), k1 = bf2f((unsigned short)(kk.x >> 16));
        float k2 = bf2f((unsigned short)(kk.y & 0xffff)), k3 = bf2f((unsigned short)(kk.y >> 16));
        float k4 = bf2f((unsigned short)(kk.z & 0xffff)), k5 = bf2f((unsigned short)(kk.z >> 16));
        float k6 = bf2f((unsigned short)(kk.w & 0xffff)), k7 = bf2f((unsigned short)(kk.w >> 16));
        float p = q0 * k0 + q1 * k1 + q2 * k2 + q3f * k3
                + q4 * k4 + q5 * k5 + q6 * k6 + q7 * k7;
        p += __shfl_xor(p, 1);
        p += __shfl_xor(p, 2);
        p += __shfl_xor(p, 4);
        p += __shfl_xor(p, 8);
        float logit = p * 0.08838834764831845f;
        float mnew = fmaxf(mm, logit);
        float sc = __expf(mm - mnew);
        float w = __expf(logit - mnew);
        float v0 = bf2f((unsigned short)(vv.x & 0xffff)), v1 = bf2f((unsigned short)(vv.x >> 16));
        float v2 = bf2f((unsigned short)(vv.y & 0xffff)), v3 = bf2f((unsigned short)(vv.y >> 16));
        float v4 = bf2f((unsigned short)(vv.z & 0xffff)), v5 = bf2f((unsigned short)(vv.z >> 16));
        float v6 = bf2f((unsigned short)(vv.w & 0xffff)), v7 = bf2f((unsigned short)(vv.w >> 16));
        ac[0] = ac[0] * sc + w * v0; ac[1] = ac[1] * sc + w * v1;
        ac[2] = ac[2] * sc + w * v2; ac[3] = ac[3] * sc + w * v3;
        ac[4] = ac[4] * sc + w * v4; ac[5] = ac[5] * sc + w * v5;
        ac[6] = ac[6] * sc + w * v6; ac[7] = ac[7] * sc + w * v7;
        lac = lac * sc + w;
        mm = mnew;
    }
#pragma unroll
    for (int msk = 16; msk <= 32; msk <<= 1) {
        float mo = __shfl_xor(mm, msk), lo = __shfl_xor(lac, msk);
        float bo[8];
#pragma unroll
        for (int j = 0; j < 8; ++j) bo[j] = __shfl_xor(ac[j], msk);
        float ms = fmaxf(mm, mo);
        float s0 = __expf(mm - ms), s1 = __expf(mo - ms);
#pragma unroll
        for (int j = 0; j < 8; ++j) ac[j] = ac[j] * s0 + bo[j] * s1;
        lac = lac * s0 + lo * s1;
        mm = ms;
    }
    if (g == 0) {
        float inv = 1.f / (lac + 1e-16f);
        float* o = &Os[y][8 * s];
#pragma unroll
        for (int j = 0; j < 8; ++j) o[j] = ac[j] * inv;
    }
    __syncthreads();
    // ---- head mean + beta gate (threads 0..127) ----
    int t = threadIdx.x;
    float o = 0.f, r = 0.f, part = 0.f;
    if (t < HIDDIM) {
#pragma unroll
        for (int yy = 0; yy < NHEADS; ++yy) o += Os[yy][t];
        o *= 0.125f;
        r = sfp[(size_t)i * HIDDIM + t];
        part = o * Wb[t] + r * Wb[128 + t] + (o - r) * Wb[256 + t];
#pragma unroll
        for (int msk = 1; msk <= 32; msk <<= 1) part += __shfl_xor(part, msk);
        if ((t & 63) == 0) wsum[t >> 6] = part;
    }
    __syncthreads();
    if (t < HIDDIM) {
        float tot = wsum[0] + wsum[1];
        float gg = 1.f / (1.f + __expf(-tot));
        out[(size_t)i * HIDDIM + t] = gg * r + (1.f - gg) * o;
    }
}

// ---------------- batchnorm ----------------
__global__ __launch_bounds__(128) void bn_stats_kernel(const float* __restrict__ x,
                                                       float* __restrict__ stat, int n) {
    int t = threadIdx.x;
    float s = 0.f, sq = 0.f;
    for (int i = blockIdx.x; i < n; i += gridDim.x) {
        float v = x[(size_t)i * HIDDIM + t];
        s += v;
        sq += v * v;
    }
    atomicAdd(&stat[t], s);
    atomicAdd(&stat[HIDDIM + t], sq);
}

__global__ __launch_bounds__(128) void bn_apply_kernel(float* __restrict__ x,
                                                       const float* __restrict__ stat,
                                                       const float* __restrict__ gamma,
                                                       const float* __restrict__ beta, int n,
                                                       unsigned short* __restrict__ cat) {
    int t = threadIdx.x;
    float mu = stat[t] / (float)n;
    float var = stat[HIDDIM + t] / (float)n - mu * mu;
    float rs = rsqrtf(var + 1e-5f);
    float g = gamma[t], b = beta[t];
    for (int i = blockIdx.x; i < n; i += gridDim.x) {
        float v = x[(size_t)i * HIDDIM + t];
        v = fmaxf((v - mu) * rs * g + b, 0.f);
        x[(size_t)i * HIDDIM + t] = v;
        if (cat) {
            unsigned short hi = f2bf(v);
            unsigned short lo = f2bf(v - bf2f(hi));
            unsigned short* row = cat + (size_t)i * KC;
            row[t] = hi;
            row[128 + t] = lo;
            row[256 + t] = hi;
        }
    }
}

// ---------------- pool ----------------
__global__ __launch_bounds__(256) void gb_kernel(const int* __restrict__ batch,
                                                 int* __restrict__ gs,
                                                 int* __restrict__ ge, int n) {
    int i = blockIdx.x * 256 + threadIdx.x;
    if (i >= n) return;
    int b = batch[i];
    if (i == 0 || batch[i - 1] != b) gs[b] = i;
    if (i == n - 1 || batch[i + 1] != b) ge[b] = i + 1;
}

__global__ __launch_bounds__(256) void pool_part_kernel(const float* __restrict__ x,
                                                        const int* __restrict__ gs,
                                                        const int* __restrict__ ge,
                                                        float* __restrict__ out) {
    int g = blockIdx.x, c = blockIdx.y;
    int t = threadIdx.x;
    int f = t & 127, half = t >> 7;
    int s = gs[g], e = ge[g];
    float acc = 0.f;
    for (int i = s + 2 * c + half; i < e; i += 16) acc += x[(size_t)i * HIDDIM + f];
    __shared__ float l0[128];
    if (half == 0) l0[f] = acc;
    __syncthreads();
    if (half == 1) atomicAdd(&out[g * HIDDIM + f], l0[f] + acc);
}

__global__ __launch_bounds__(128) void pool_div_kernel(float* __restrict__ out,
                                                       const int* __restrict__ gs,
                                                       const int* __restrict__ ge) {
    int g = blockIdx.x, t = threadIdx.x;
    int c = ge[g] - gs[g];
    out[g * HIDDIM + t] /= (float)(c > 0 ? c : 1);
}

// ---------------- host ----------------
extern "C" void kernel_launch(void* const* d_in, const int* in_sizes, int n_in,
                              void* d_out, int out_size, void* d_ws, size_t ws_size,
                              hipStream_t stream) {
    const float* x       = (const float*)d_in[0];
    const int*   ei      = (const int*)d_in[1];
    const int*   batch   = (const int*)d_in[2];
    const float* Wp      = (const float*)d_in[3];
    const float* bp      = (const float*)d_in[4];
    const float* Wq      = (const float*)d_in[5];
    const float* bq      = (const float*)d_in[6];
    const float* Wk      = (const float*)d_in[7];
    const float* bk      = (const float*)d_in[8];
    const float* Wv      = (const float*)d_in[9];
    const float* bv      = (const float*)d_in[10];
    const float* Ws      = (const float*)d_in[11];
    const float* bs      = (const float*)d_in[12];
    const float* Wbeta   = (const float*)d_in[13];
    const float* Wq3     = (const float*)d_in[14];
    const float* bq3     = (const float*)d_in[15];
    const float* Wk3     = (const float*)d_in[16];
    const float* bk3     = (const float*)d_in[17];
    const float* Wv3     = (const float*)d_in[18];
    const float* bv3     = (const float*)d_in[19];
    const float* Ws3     = (const float*)d_in[20];
    const float* bs3     = (const float*)d_in[21];
    const float* Wbeta3  = (const float*)d_in[22];
    const float* bn_gamma = (const float*)d_in[23];
    const float* bn_beta  = (const float*)d_in[24];
    float* out = (float*)d_out;

    const int* esrc = ei;
    const int* edst = ei + NEDGES;

    char* wpc = (char*)d_ws;
    auto alloc = [&](size_t nbytes) -> char* {
        char* p = wpc;
        wpc += (nbytes + 255) & ~(size_t)255;
        return p;
    };
    unsigned short* Acat  = (unsigned short*)alloc((size_t)NPAD * KC * 2);      // 15.4 MB
    unsigned short* WtAll = (unsigned short*)alloc((size_t)4864 * KC * 2);      // 3.7 MB
    float* bcat   = (float*)alloc(4608 * 4);
    unsigned short* qkv3b = (unsigned short*)alloc((size_t)NNODES * 3072 * 2);  // 122.9 MB
    float* sfp    = (float*)alloc((size_t)NNODES * HIDDIM * 4);                 // 10.2 MB
    float* hbuf   = (float*)alloc((size_t)NNODES * HIDDIM * 4);
    float* obuf   = (float*)alloc((size_t)NNODES * HIDDIM * 4);
    float* sb     = (float*)alloc((size_t)NNODES * HIDDIM * 4);
    int*   deg    = (int*)alloc((2 * NNODES + 128 + 4 * 256) * 4);
    int*   cursor = deg + NNODES;
    int*   gs     = deg + 2 * NNODES;
    int*   ge     = gs + NGRAPH;
    float* bnstat4 = (float*)(deg + 2 * NNODES + 128);
    int*   chunk  = (int*)alloc(NNODES * 4);
    int*   bsum   = (int*)alloc(128 * 4);
    int*   offs   = (int*)alloc((NNODES + 1) * 4);
    int*   csrsrc = (int*)alloc(NEDGES * 4);

    unsigned short* WtQKV = WtAll;                       // [3][384][KC]
    unsigned short* WtS   = WtAll + (size_t)1152 * KC;   // [3][128][KC]
    unsigned short* Wpt   = WtAll + (size_t)1536 * KC;
    unsigned short* Ws3t  = WtAll + (size_t)1664 * KC;
    unsigned short* Wt3   = WtAll + (size_t)1792 * KC;   // [8][384][KC]
    float* bQKV = bcat;          // [3][384]
    float* bS   = bcat + 1152;   // [3][128]
    float* b3   = bcat + 1536;   // [3072]
    unsigned short* qkvb = qkv3b;  // layers 0-2 alias: [N][384]

    const int TB = 256;
    const int ZWORDS = 2 * NNODES + 128 + 4 * 256;
    zero_kernel<<<(ZWORDS + TB - 1) / TB, TB, 0, stream>>>((float*)deg, ZWORDS);
    count_deg_kernel<<<(NEDGES + TB - 1) / TB, TB, 0, stream>>>(edst, deg, NEDGES);
    const int NB = (NNODES + 255) / 256;
    scan1_kernel<<<NB, 256, 0, stream>>>(deg, chunk, bsum, NNODES);
    scan2_kernel<<<1, 128, 0, stream>>>(bsum, NB);
    scan3_kernel<<<NB, 256, 0, stream>>>(chunk, bsum, offs, NNODES);
    scatter_kernel<<<(NEDGES + TB - 1) / TB, TB, 0, stream>>>(esrc, edst, offs, cursor, csrsrc, NEDGES);
    gb_kernel<<<(NNODES + TB - 1) / TB, TB, 0, stream>>>(batch, gs, ge, NNODES);

    prep_w_kernel<<<4864, 128, 0, stream>>>(Wq, Wk, Wv, Ws, Wp, Ws3, Wq3, Wk3, Wv3, WtAll);
    prep_bias_kernel<<<(4608 + TB - 1) / TB, TB, 0, stream>>>(bq, bk, bv, bs, bq3, bk3, bv3, bcat);

    const int CATB = (NPAD * HIDDIM + TB - 1) / TB;
    const int GSW = 8 * ((GXTILES + 7) / 8);  // 160 swizzled x-slots

    cat_from_kernel<<<CATB, TB, 0, stream>>>(x, Acat);
    gemm_mfma_kernel<float, 12, 1><<<GSW * 1, 256, 0, stream>>>(Acat, Wpt, bp, hbuf, 128, NNODES);
    cat_from_kernel<<<CATB, TB, 0, stream>>>(hbuf, Acat);

    for (int li = 0; li < 3; ++li) {
        gemm_mfma_kernel<unsigned short, 8, 3><<<GSW * 3, 256, 0, stream>>>(
            Acat, WtQKV + (size_t)li * 384 * KC, bQKV + li * 384, qkvb, 384, NNODES);
        gemm_mfma_kernel<float, 12, 1><<<GSW * 1, 256, 0, stream>>>(
            Acat, WtS + (size_t)li * 128 * KC, bS + li * 128, sfp, 128, NNODES);
        attn_small_kernel<<<NNODES, 64, 0, stream>>>(qkvb, sfp, Wbeta + li * 384,
                                                     offs, csrsrc, obuf);
        float* st = bnstat4 + li * 256;
        bn_stats_kernel<<<640, 128, 0, stream>>>(obuf, st, NNODES);
        bn_apply_kernel<<<512, 128, 0, stream>>>(obuf, st, bn_gamma + li * HIDDIM,
                                                 bn_beta + li * HIDDIM, NNODES, Acat);
    }

    // ---- layer 3: single merged q|k|v GEMM (8 heads) + fused attention+beta ----
    gemm_mfma_kernel<unsigned short, 8, 24><<<GSW * 24, 256, 0, stream>>>(
        Acat, Wt3, b3, qkv3b, 3072, NNODES);
    gemm_mfma_kernel<float, 12, 1><<<GSW * 1, 256, 0, stream>>>(Acat, Ws3t, bs3, sb, 128, NNODES);
    attn_big_fused_kernel<<<NNODES, 512, 0, stream>>>(qkv3b, sb, Wbeta3, offs, csrsrc, hbuf);
    float* st3 = bnstat4 + 3 * 256;
    bn_stats_kernel<<<640, 128, 0, stream>>>(hbuf, st3, NNODES);
    bn_apply_kernel<<<512, 128, 0, stream>>>(hbuf, st3, bn_gamma + 3 * HIDDIM,
                                             bn_beta + 3 * HIDDIM, NNODES, (unsigned short*)0);

    zero_kernel<<<(NGRAPH * HIDDIM + TB - 1) / TB, TB, 0, stream>>>(out, NGRAPH * HIDDIM);
    pool_part_kernel<<<dim3(NGRAPH, 8), 256, 0, stream>>>(hbuf, gs, ge, out);
    pool_div_kernel<<<NGRAPH, 128, 0, stream>>>(out, gs, ge);
}

// Round 16
// 724.162 us; speedup vs baseline: 1.0408x; 1.0224x over previous
//
#include <hip/hip_runtime.h>
#include <math.h>

#define NNODES 20000
#define NPAD   20096   // 157 * 128
#define NEDGES 160000
#define HIDDIM 128
#define NHEADS 8
#define NGRAPH 64
#define KC 384   // concatenated K (hi | lo | hi)
#define GXTILES 157

typedef short short8 __attribute__((ext_vector_type(8)));
typedef float floatx4 __attribute__((ext_vector_type(4)));
typedef unsigned short ushort4v __attribute__((ext_vector_type(4)));

__device__ inline unsigned short f2bf(float x) {
    unsigned u = __float_as_uint(x);
    u += 0x7fff + ((u >> 16) & 1);
    return (unsigned short)(u >> 16);
}
__device__ inline float bf2f(unsigned short h) {
    return __uint_as_float(((unsigned)h) << 16);
}

// ---------------- utility ----------------
__global__ __launch_bounds__(256) void zero_kernel(float* __restrict__ p, int n) {
    int i = blockIdx.x * blockDim.x + threadIdx.x;
    if (i < n) p[i] = 0.f;
}

// ---------------- CSR build ----------------
__global__ __launch_bounds__(256) void count_deg_kernel(const int* __restrict__ dst,
                                                        int* __restrict__ deg, int e) {
    int i = blockIdx.x * blockDim.x + threadIdx.x;
    if (i < e) atomicAdd(&deg[dst[i]], 1);
}

__global__ __launch_bounds__(256) void scan1_kernel(const int* __restrict__ deg,
                                                    int* __restrict__ chunk,
                                                    int* __restrict__ bsum, int n) {
    __shared__ int buf[256];
    int t = threadIdx.x;
    int i = blockIdx.x * 256 + t;
    int v = (i < n) ? deg[i] : 0;
    buf[t] = v;
    __syncthreads();
    for (int off = 1; off < 256; off <<= 1) {
        int tmp = (t >= off) ? buf[t - off] : 0;
        __syncthreads();
        buf[t] += tmp;
        __syncthreads();
    }
    if (i < n) chunk[i] = buf[t];
    if (t == 255) bsum[blockIdx.x] = buf[255];
}

__global__ __launch_bounds__(128) void scan2_kernel(int* __restrict__ bsum, int nb) {
    __shared__ int buf[128];
    int t = threadIdx.x;
    int v = (t < nb) ? bsum[t] : 0;
    buf[t] = v;
    __syncthreads();
    for (int off = 1; off < 128; off <<= 1) {
        int tmp = (t >= off) ? buf[t - off] : 0;
        __syncthreads();
        buf[t] += tmp;
        __syncthreads();
    }
    if (t < nb) bsum[t] = buf[t] - v;
}

__global__ __launch_bounds__(256) void scan3_kernel(const int* __restrict__ chunk,
                                                    const int* __restrict__ bsum,
                                                    int* __restrict__ offs, int n) {
    int i = blockIdx.x * 256 + threadIdx.x;
    if (i < n) offs[i + 1] = chunk[i] + bsum[i >> 8];
    if (i == 0) offs[0] = 0;
}

__global__ __launch_bounds__(256) void scatter_kernel(const int* __restrict__ src,
                                                      const int* __restrict__ dst,
                                                      const int* __restrict__ offs,
                                                      int* __restrict__ cursor,
                                                      int* __restrict__ csr_src, int e) {
    int i = blockIdx.x * blockDim.x + threadIdx.x;
    if (i < e) {
        int d = dst[i];
        int pos = offs[d] + atomicAdd(&cursor[d], 1);
        csr_src[pos] = src[i];
    }
}

// ---------------- weight prep ----------------
// Row map: [0,1152): layers0-2 qkv (li*384 + {q,k,v}*128 + j)
// [1152,1536): layers0-2 s (li*128 + j) ; [1536,1664): Wp ; [1664,1792): Ws3
// [1792,4864): layer3 qkv (h*384 + {q,k,v}*128 + j)
__global__ __launch_bounds__(128) void prep_w_kernel(
    const float* __restrict__ Wq, const float* __restrict__ Wk,
    const float* __restrict__ Wv, const float* __restrict__ Ws,
    const float* __restrict__ Wp, const float* __restrict__ Ws3,
    const float* __restrict__ Wq3, const float* __restrict__ Wk3,
    const float* __restrict__ Wv3, unsigned short* __restrict__ WtAll) {
    int id = blockIdx.x;
    int k = threadIdx.x;
    float w;
    if (id < 1152) {
        int li = id / 384, n = id % 384, sel = n >> 7, np = n & 127;
        const float* W = (sel == 0) ? Wq : (sel == 1) ? Wk : Wv;
        w = W[li * 16384 + k * 128 + np];
    } else if (id < 1536) {
        int r = id - 1152, li = r >> 7, np = r & 127;
        w = Ws[li * 16384 + k * 128 + np];
    } else if (id < 1664) {
        w = Wp[k * 128 + (id - 1536)];
    } else if (id < 1792) {
        w = Ws3[k * 128 + (id - 1664)];
    } else {
        int r = id - 1792, h = r / 384, j = r % 384, sel = j >> 7, jp = j & 127;
        const float* W = (sel == 0) ? Wq3 : (sel == 1) ? Wk3 : Wv3;
        w = W[k * 1024 + h * 128 + jp];
    }
    unsigned short hi = f2bf(w);
    unsigned short lo = f2bf(w - bf2f(hi));
    unsigned short* dst = WtAll + (size_t)id * KC;
    dst[k] = hi;
    dst[128 + k] = hi;
    dst[256 + k] = lo;
}

__global__ __launch_bounds__(256) void prep_bias_kernel(
    const float* __restrict__ bq, const float* __restrict__ bk,
    const float* __restrict__ bv, const float* __restrict__ bs,
    const float* __restrict__ bq3, const float* __restrict__ bk3,
    const float* __restrict__ bv3, float* __restrict__ bcat) {
    int id = blockIdx.x * 256 + threadIdx.x;
    if (id >= 4608) return;
    float v;
    if (id < 1152) {
        int li = id / 384, n = id % 384, sel = n >> 7, np = n & 127;
        const float* b = (sel == 0) ? bq : (sel == 1) ? bk : bv;
        v = b[li * 128 + np];
    } else if (id < 1536) {
        int r = id - 1152, li = r >> 7, np = r & 127;
        v = bs[li * 128 + np];
    } else {
        int r = id - 1536, h = r / 384, j = r % 384, sel = j >> 7, jp = j & 127;
        const float* b = (sel == 0) ? bq3 : (sel == 1) ? bk3 : bv3;
        v = b[h * 128 + jp];
    }
    bcat[id] = v;
}

// ---------------- activation -> split-bf16 A_cat ----------------
__global__ __launch_bounds__(256) void cat_from_kernel(const float* __restrict__ h,
                                                       unsigned short* __restrict__ Acat) {
    int idx = blockIdx.x * 256 + threadIdx.x;
    if (idx >= NPAD * HIDDIM) return;
    int r = idx >> 7, k = idx & 127;
    float x = (r < NNODES) ? h[idx] : 0.f;
    unsigned short hi = f2bf(x);
    unsigned short lo = f2bf(x - bf2f(hi));
    unsigned short* row = Acat + (size_t)r * KC;
    row[k] = hi;
    row[128 + k] = lo;
    row[256 + k] = hi;
}

// ---------------- MFMA GEMM (XCD swizzle; optional per-head output layout) ----------------
// HT=0: C[node*M + col]. HT>0: head h = by/HT, tile lt = by%HT,
// C[((h*NNODES)+node)*(HT*128) + lt*128 + f] -- per-head contiguous buffers.
template <typename OutT, int KG, int BY, int HT>
__global__ __launch_bounds__(256) void gemm_mfma_kernel(
    const unsigned short* __restrict__ Acat, const unsigned short* __restrict__ Wt,
    const float* __restrict__ bias, OutT* __restrict__ C, int M, int nrows) {
    int id = blockIdx.x;
    int xcd = id & 7;
    int idx = id >> 3;
    int bx = (idx / BY) * 8 + xcd;
    int by = idx % BY;
    if (bx >= GXTILES) return;
    int lane = threadIdx.x & 63;
    int wave = threadIdx.x >> 6;
    int nodeBase = bx * 128 + (wave & 1) * 64;
    int featBase = by * 128 + (wave >> 1) * 64;
    int m = lane & 15;
    int q = lane >> 4;
    int ko = q * 8;
    const unsigned short* wptr = Wt + (size_t)(featBase + m) * KC + ko;    // A operand
    const unsigned short* aptr = Acat + (size_t)(nodeBase + m) * KC + ko;  // B operand
    floatx4 acc[4][4];  // [feat tile r][node tile c]
#pragma unroll
    for (int r = 0; r < 4; ++r)
#pragma unroll
        for (int c = 0; c < 4; ++c) acc[r][c] = (floatx4){0.f, 0.f, 0.f, 0.f};
#pragma unroll
    for (int kg = 0; kg < KG; ++kg) {
        short8 a[4], b[4];
#pragma unroll
        for (int r = 0; r < 4; ++r) a[r] = *(const short8*)(wptr + (size_t)r * 16 * KC + kg * 32);
#pragma unroll
        for (int c = 0; c < 4; ++c) b[c] = *(const short8*)(aptr + (size_t)c * 16 * KC + kg * 32);
#pragma unroll
        for (int r = 0; r < 4; ++r)
#pragma unroll
            for (int c = 0; c < 4; ++c)
                acc[r][c] = __builtin_amdgcn_mfma_f32_16x16x32_bf16(a[r], b[c], acc[r][c], 0, 0, 0);
    }
    // output row base (per-head layout when HT>0)
    size_t rowLen = (HT > 0) ? (size_t)(HT * 128) : (size_t)M;
    size_t headOff = 0;
    int colBase;
    if (HT > 0) {
        int h = by / HT, lt = by % HT;
        headOff = (size_t)h * NNODES * rowLen;
        colBase = lt * 128 + (wave >> 1) * 64;
    } else {
        colBase = featBase;
    }
    float4 bv[4];
#pragma unroll
    for (int r = 0; r < 4; ++r) bv[r] = *(const float4*)(bias + featBase + r * 16 + q * 4);
#pragma unroll
    for (int c = 0; c < 4; ++c) {
        int node = nodeBase + c * 16 + m;
        if (node < nrows) {
            size_t rbase = headOff + (size_t)node * rowLen;
#pragma unroll
            for (int r = 0; r < 4; ++r) {
                int f0 = colBase + r * 16 + q * 4;
                float v0 = acc[r][c][0] + bv[r].x;
                float v1 = acc[r][c][1] + bv[r].y;
                float v2 = acc[r][c][2] + bv[r].z;
                float v3 = acc[r][c][3] + bv[r].w;
                if (sizeof(OutT) == 2) {
                    ushort4v o = {f2bf(v0), f2bf(v1), f2bf(v2), f2bf(v3)};
                    *(ushort4v*)((unsigned short*)C + rbase + f0) = o;
                } else {
                    float4 o = {v0, v1, v2, v3};
                    *(float4*)((float*)C + rbase + f0) = o;
                }
            }
        }
    }
}

// ---------------- attention layers 0-2: qkv bf16 [N][384], s fp32 [N][128] ----------------
__global__ __launch_bounds__(64) void attn_small_kernel(
    const unsigned short* __restrict__ qkv, const float* __restrict__ sfp,
    const float* __restrict__ Wb,
    const int* __restrict__ offs, const int* __restrict__ csr_src,
    float* __restrict__ out) {
    int i = blockIdx.x;
    int l = threadIdx.x;
    int g = l >> 5;
    int d0 = (l & 31) * 4;
    uint2 qraw = *(const uint2*)(qkv + (size_t)i * 384 + d0);
    float q0 = bf2f((unsigned short)(qraw.x & 0xffff)), q1 = bf2f((unsigned short)(qraw.x >> 16));
    float q2 = bf2f((unsigned short)(qraw.y & 0xffff)), q3 = bf2f((unsigned short)(qraw.y >> 16));
    int e0 = offs[i], e1 = offs[i + 1];
    float mm = -1e30f, lac = 0.f;
    float a0 = 0.f, a1 = 0.f, a2 = 0.f, a3 = 0.f;
    for (int e = e0 + g; e < e1; e += 2) {
        int sn = csr_src[e];
        const unsigned short* row = qkv + (size_t)sn * 384;
        uint2 kk = *(const uint2*)(row + 128 + d0);
        uint2 vv = *(const uint2*)(row + 256 + d0);
        float k0 = bf2f((unsigned short)(kk.x & 0xffff)), k1 = bf2f((unsigned short)(kk.x >> 16));
        float k2 = bf2f((unsigned short)(kk.y & 0xffff)), k3 = bf2f((unsigned short)(kk.y >> 16));
        float p = q0 * k0 + q1 * k1 + q2 * k2 + q3 * k3;
        p += __shfl_xor(p, 1);
        p += __shfl_xor(p, 2);
        float logit = p * 0.25f;
        float mnew = fmaxf(mm, logit);
        float sc = __expf(mm - mnew);
        float w = __expf(logit - mnew);
        float v0 = bf2f((unsigned short)(vv.x & 0xffff)), v1 = bf2f((unsigned short)(vv.x >> 16));
        float v2 = bf2f((unsigned short)(vv.y & 0xffff)), v3 = bf2f((unsigned short)(vv.y >> 16));
        a0 = a0 * sc + w * v0;
        a1 = a1 * sc + w * v1;
        a2 = a2 * sc + w * v2;
        a3 = a3 * sc + w * v3;
        lac = lac * sc + w;
        mm = mnew;
    }
    float mo = __shfl_xor(mm, 32), lo = __shfl_xor(lac, 32);
    float b0 = __shfl_xor(a0, 32), b1 = __shfl_xor(a1, 32);
    float b2 = __shfl_xor(a2, 32), b3 = __shfl_xor(a3, 32);
    float ms = fmaxf(mm, mo);
    float s0 = __expf(mm - ms), s1 = __expf(mo - ms);
    a0 = a0 * s0 + b0 * s1;
    a1 = a1 * s0 + b1 * s1;
    a2 = a2 * s0 + b2 * s1;
    a3 = a3 * s0 + b3 * s1;
    lac = lac * s0 + lo * s1;
    float inv = 1.f / (lac + 1e-16f);
    float o0 = a0 * inv, o1 = a1 * inv, o2 = a2 * inv, o3 = a3 * inv;
    float4 rv = *(const float4*)(sfp + (size_t)i * HIDDIM + d0);
    float part = o0 * Wb[d0] + o1 * Wb[d0 + 1] + o2 * Wb[d0 + 2] + o3 * Wb[d0 + 3]
               + rv.x * Wb[128 + d0] + rv.y * Wb[128 + d0 + 1]
               + rv.z * Wb[128 + d0 + 2] + rv.w * Wb[128 + d0 + 3]
               + (o0 - rv.x) * Wb[256 + d0] + (o1 - rv.y) * Wb[256 + d0 + 1]
               + (o2 - rv.z) * Wb[256 + d0 + 2] + (o3 - rv.w) * Wb[256 + d0 + 3];
    if (g) part = 0.f;
#pragma unroll
    for (int msk = 1; msk <= 32; msk <<= 1) part += __shfl_xor(part, msk);
    float gg = 1.f / (1.f + __expf(-part));
    if (g == 0) {
        float4 o4 = {gg * rv.x + (1.f - gg) * o0, gg * rv.y + (1.f - gg) * o1,
                     gg * rv.z + (1.f - gg) * o2, gg * rv.w + (1.f - gg) * o3};
        *(float4*)(out + (size_t)i * HIDDIM + d0) = o4;
    }
}

// ---------------- attention layer 3: per-head qkv3 [8][N][384] ----------------
// grid (N, 8): head y reads only its 24.6 MB slab -> L2/L3 locality.
// writes obuf8 bf16 [8][N][128]
__global__ __launch_bounds__(64) void attn_big_kernel(
    const unsigned short* __restrict__ qkv3,
    const int* __restrict__ offs, const int* __restrict__ csr_src,
    unsigned short* __restrict__ obuf8) {
    int i = blockIdx.x;
    int y = blockIdx.y;
    int l = threadIdx.x;
    int g = l >> 4;
    int s = l & 15;
    const unsigned short* base = qkv3 + (size_t)y * NNODES * 384;
    uint4 qq = *(const uint4*)(base + (size_t)i * 384 + 8 * s);
    float q0 = bf2f((unsigned short)(qq.x & 0xffff)), q1 = bf2f((unsigned short)(qq.x >> 16));
    float q2 = bf2f((unsigned short)(qq.y & 0xffff)), q3f = bf2f((unsigned short)(qq.y >> 16));
    float q4 = bf2f((unsigned short)(qq.z & 0xffff)), q5 = bf2f((unsigned short)(qq.z >> 16));
    float q6 = bf2f((unsigned short)(qq.w & 0xffff)), q7 = bf2f((unsigned short)(qq.w >> 16));
    int e0 = offs[i], e1 = offs[i + 1];
    float mm = -1e30f, lac = 0.f;
    float ac[8];
#pragma unroll
    for (int j = 0; j < 8; ++j) ac[j] = 0.f;
    for (int e = e0 + g; e < e1; e += 4) {
        int sn = csr_src[e];
        const unsigned short* row = base + (size_t)sn * 384 + 8 * s;
        uint4 kk = *(const uint4*)(row + 128);
        uint4 vv = *(const uint4*)(row + 256);
        float k0 = bf2f((unsigned short)(kk.x & 0xffff)), k1 = bf2f((unsigned short)(kk.x >> 16));
        float k2 = bf2f((unsigned short)(kk.y & 0xffff)), k3 = bf2f((unsigned short)(kk.y >> 16));
        float k4 = bf2f((unsigned short)(kk.z & 0xffff)), k5 = bf2f((unsigned short)(kk.z >> 16));
        float k6 = bf2f((unsigned short)(kk.w & 0xffff)), k7 = bf2f((unsigned short)(kk.w >> 16));
        float p = q0 * k0 + q1 * k1 + q2 * k2 + q3f * k3
                + q4 * k4 + q5 * k5 + q6 * k6 + q7 * k7;
        p += __shfl_xor(p, 1);
        p += __shfl_xor(p, 2);
        p += __shfl_xor(p, 4);
        p += __shfl_xor(p, 8);
        float logit = p * 0.08838834764831845f;
        float mnew = fmaxf(mm, logit);
        float sc = __expf(mm - mnew);
        float w = __expf(logit - mnew);
        float v0 = bf2f((unsigned short)(vv.x & 0xffff)), v1 = bf2f((unsigned short)(vv.x >> 16));
        float v2 = bf2f((unsigned short)(vv.y & 0xffff)), v3 = bf2f((unsigned short)(vv.y >> 16));
        float v4 = bf2f((unsigned short)(vv.z & 0xffff)), v5 = bf2f((unsigned short)(vv.z >> 16));
        float v6 = bf2f((unsigned short)(vv.w & 0xffff)), v7 = bf2f((unsigned short)(vv.w >> 16));
        ac[0] = ac[0] * sc + w * v0; ac[1] = ac[1] * sc + w * v1;
        ac[2] = ac[2] * sc + w * v2; ac[3] = ac[3] * sc + w * v3;
        ac[4] = ac[4] * sc + w * v4; ac[5] = ac[5] * sc + w * v5;
        ac[6] = ac[6] * sc + w * v6; ac[7] = ac[7] * sc + w * v7;
        lac = lac * sc + w;
        mm = mnew;
    }
#pragma unroll
    for (int msk = 16; msk <= 32; msk <<= 1) {
        float mo = __shfl_xor(mm, msk), lo = __shfl_xor(lac, msk);
        float bo[8];
#pragma unroll
        for (int j = 0; j < 8; ++j) bo[j] = __shfl_xor(ac[j], msk);
        float ms = fmaxf(mm, mo);
        float s0 = __expf(mm - ms), s1 = __expf(mo - ms);
#pragma unroll
        for (int j = 0; j < 8; ++j) ac[j] = ac[j] * s0 + bo[j] * s1;
        lac = lac * s0 + lo * s1;
        mm = ms;
    }
    if (g == 0) {
        float inv = 1.f / (lac + 1e-16f);
        ushort4v w0 = {f2bf(ac[0] * inv), f2bf(ac[1] * inv), f2bf(ac[2] * inv), f2bf(ac[3] * inv)};
        ushort4v w1 = {f2bf(ac[4] * inv), f2bf(ac[5] * inv), f2bf(ac[6] * inv), f2bf(ac[7] * inv)};
        unsigned short* o = obuf8 + ((size_t)y * NNODES + i) * HIDDIM + 8 * s;
        *(ushort4v*)o = w0;
        *(ushort4v*)(o + 4) = w1;
    }
}

// ---------------- beta gate layer 3 (head mean over 8 bf16 slices) ----------------
__global__ __launch_bounds__(128) void beta3_kernel(const unsigned short* __restrict__ obuf8,
                                                    const float* __restrict__ s,
                                                    const float* __restrict__ Wb,
                                                    float* __restrict__ out) {
    int i = blockIdx.x, t = threadIdx.x;
    float o = 0.f;
#pragma unroll
    for (int y = 0; y < 8; ++y) o += bf2f(obuf8[((size_t)y * NNODES + i) * HIDDIM + t]);
    o *= 0.125f;
    float r = s[(size_t)i * HIDDIM + t];
    float part = o * Wb[t] + r * Wb[128 + t] + (o - r) * Wb[256 + t];
#pragma unroll
    for (int msk = 1; msk <= 32; msk <<= 1) part += __shfl_xor(part, msk);
    __shared__ float wsum[2];
    if ((t & 63) == 0) wsum[t >> 6] = part;
    __syncthreads();
    float tot = wsum[0] + wsum[1];
    float g = 1.f / (1.f + __expf(-tot));
    out[(size_t)i * HIDDIM + t] = g * r + (1.f - g) * o;
}

// ---------------- batchnorm ----------------
__global__ __launch_bounds__(128) void bn_stats_kernel(const float* __restrict__ x,
                                                       float* __restrict__ stat, int n) {
    int t = threadIdx.x;
    float s = 0.f, sq = 0.f;
    for (int i = blockIdx.x; i < n; i += gridDim.x) {
        float v = x[(size_t)i * HIDDIM + t];
        s += v;
        sq += v * v;
    }
    atomicAdd(&stat[t], s);
    atomicAdd(&stat[HIDDIM + t], sq);
}

__global__ __launch_bounds__(128) void bn_apply_kernel(float* __restrict__ x,
                                                       const float* __restrict__ stat,
                                                       const float* __restrict__ gamma,
                                                       const float* __restrict__ beta, int n,
                                                       unsigned short* __restrict__ cat) {
    int t = threadIdx.x;
    float mu = stat[t] / (float)n;
    float var = stat[HIDDIM + t] / (float)n - mu * mu;
    float rs = rsqrtf(var + 1e-5f);
    float g = gamma[t], b = beta[t];
    for (int i = blockIdx.x; i < n; i += gridDim.x) {
        float v = x[(size_t)i * HIDDIM + t];
        v = fmaxf((v - mu) * rs * g + b, 0.f);
        x[(size_t)i * HIDDIM + t] = v;
        if (cat) {
            unsigned short hi = f2bf(v);
            unsigned short lo = f2bf(v - bf2f(hi));
            unsigned short* row = cat + (size_t)i * KC;
            row[t] = hi;
            row[128 + t] = lo;
            row[256 + t] = hi;
        }
    }
}

// ---------------- pool ----------------
__global__ __launch_bounds__(256) void gb_kernel(const int* __restrict__ batch,
                                                 int* __restrict__ gs,
                                                 int* __restrict__ ge, int n) {
    int i = blockIdx.x * 256 + threadIdx.x;
    if (i >= n) return;
    int b = batch[i];
    if (i == 0 || batch[i - 1] != b) gs[b] = i;
    if (i == n - 1 || batch[i + 1] != b) ge[b] = i + 1;
}

__global__ __launch_bounds__(256) void pool_part_kernel(const float* __restrict__ x,
                                                        const int* __restrict__ gs,
                                                        const int* __restrict__ ge,
                                                        float* __restrict__ out) {
    int g = blockIdx.x, c = blockIdx.y;
    int t = threadIdx.x;
    int f = t & 127, half = t >> 7;
    int s = gs[g], e = ge[g];
    float acc = 0.f;
    for (int i = s + 2 * c + half; i < e; i += 16) acc += x[(size_t)i * HIDDIM + f];
    __shared__ float l0[128];
    if (half == 0) l0[f] = acc;
    __syncthreads();
    if (half == 1) atomicAdd(&out[g * HIDDIM + f], l0[f] + acc);
}

__global__ __launch_bounds__(128) void pool_div_kernel(float* __restrict__ out,
                                                       const int* __restrict__ gs,
                                                       const int* __restrict__ ge) {
    int g = blockIdx.x, t = threadIdx.x;
    int c = ge[g] - gs[g];
    out[g * HIDDIM + t] /= (float)(c > 0 ? c : 1);
}

// ---------------- host ----------------
extern "C" void kernel_launch(void* const* d_in, const int* in_sizes, int n_in,
                              void* d_out, int out_size, void* d_ws, size_t ws_size,
                              hipStream_t stream) {
    const float* x       = (const float*)d_in[0];
    const int*   ei      = (const int*)d_in[1];
    const int*   batch   = (const int*)d_in[2];
    const float* Wp      = (const float*)d_in[3];
    const float* bp      = (const float*)d_in[4];
    const float* Wq      = (const float*)d_in[5];
    const float* bq      = (const float*)d_in[6];
    const float* Wk      = (const float*)d_in[7];
    const float* bk      = (const float*)d_in[8];
    const float* Wv      = (const float*)d_in[9];
    const float* bv      = (const float*)d_in[10];
    const float* Ws      = (const float*)d_in[11];
    const float* bs      = (const float*)d_in[12];
    const float* Wbeta   = (const float*)d_in[13];
    const float* Wq3     = (const float*)d_in[14];
    const float* bq3     = (const float*)d_in[15];
    const float* Wk3     = (const float*)d_in[16];
    const float* bk3     = (const float*)d_in[17];
    const float* Wv3     = (const float*)d_in[18];
    const float* bv3     = (const float*)d_in[19];
    const float* Ws3     = (const float*)d_in[20];
    const float* bs3     = (const float*)d_in[21];
    const float* Wbeta3  = (const float*)d_in[22];
    const float* bn_gamma = (const float*)d_in[23];
    const float* bn_beta  = (const float*)d_in[24];
    float* out = (float*)d_out;

    const int* esrc = ei;
    const int* edst = ei + NEDGES;

    char* wpc = (char*)d_ws;
    auto alloc = [&](size_t nbytes) -> char* {
        char* p = wpc;
        wpc += (nbytes + 255) & ~(size_t)255;
        return p;
    };
    unsigned short* Acat  = (unsigned short*)alloc((size_t)NPAD * KC * 2);      // 15.4 MB
    unsigned short* WtAll = (unsigned short*)alloc((size_t)4864 * KC * 2);      // 3.7 MB
    float* bcat   = (float*)alloc(4608 * 4);
    unsigned short* qkv3b = (unsigned short*)alloc((size_t)NHEADS * NNODES * 384 * 2);  // 122.9 MB
    float* sfp    = (float*)alloc((size_t)NNODES * HIDDIM * 4);                 // 10.2 MB
    unsigned short* obuf8 = (unsigned short*)alloc((size_t)8 * NNODES * HIDDIM * 2);    // 41 MB
    float* hbuf   = (float*)alloc((size_t)NNODES * HIDDIM * 4);
    float* obuf   = (float*)alloc((size_t)NNODES * HIDDIM * 4);
    float* sb     = (float*)alloc((size_t)NNODES * HIDDIM * 4);
    int*   deg    = (int*)alloc((2 * NNODES + 128 + 4 * 256) * 4);
    int*   cursor = deg + NNODES;
    int*   gs     = deg + 2 * NNODES;
    int*   ge     = gs + NGRAPH;
    float* bnstat4 = (float*)(deg + 2 * NNODES + 128);
    int*   chunk  = (int*)alloc(NNODES * 4);
    int*   bsum   = (int*)alloc(128 * 4);
    int*   offs   = (int*)alloc((NNODES + 1) * 4);
    int*   csrsrc = (int*)alloc(NEDGES * 4);

    unsigned short* WtQKV = WtAll;                       // [3][384][KC]
    unsigned short* WtS   = WtAll + (size_t)1152 * KC;   // [3][128][KC]
    unsigned short* Wpt   = WtAll + (size_t)1536 * KC;
    unsigned short* Ws3t  = WtAll + (size_t)1664 * KC;
    unsigned short* Wt3   = WtAll + (size_t)1792 * KC;   // [8][384][KC]
    float* bQKV = bcat;          // [3][384]
    float* bS   = bcat + 1152;   // [3][128]
    float* b3   = bcat + 1536;   // [3072]
    unsigned short* qkvb = qkv3b;  // layers 0-2 alias: [N][384]

    const int TB = 256;
    const int ZWORDS = 2 * NNODES + 128 + 4 * 256;
    zero_kernel<<<(ZWORDS + TB - 1) / TB, TB, 0, stream>>>((float*)deg, ZWORDS);
    count_deg_kernel<<<(NEDGES + TB - 1) / TB, TB, 0, stream>>>(edst, deg, NEDGES);
    const int NB = (NNODES + 255) / 256;
    scan1_kernel<<<NB, 256, 0, stream>>>(deg, chunk, bsum, NNODES);
    scan2_kernel<<<1, 128, 0, stream>>>(bsum, NB);
    scan3_kernel<<<NB, 256, 0, stream>>>(chunk, bsum, offs, NNODES);
    scatter_kernel<<<(NEDGES + TB - 1) / TB, TB, 0, stream>>>(esrc, edst, offs, cursor, csrsrc, NEDGES);
    gb_kernel<<<(NNODES + TB - 1) / TB, TB, 0, stream>>>(batch, gs, ge, NNODES);

    prep_w_kernel<<<4864, 128, 0, stream>>>(Wq, Wk, Wv, Ws, Wp, Ws3, Wq3, Wk3, Wv3, WtAll);
    prep_bias_kernel<<<(4608 + TB - 1) / TB, TB, 0, stream>>>(bq, bk, bv, bs, bq3, bk3, bv3, bcat);

    const int CATB = (NPAD * HIDDIM + TB - 1) / TB;
    const int GSW = 8 * ((GXTILES + 7) / 8);  // 160 swizzled x-slots

    cat_from_kernel<<<CATB, TB, 0, stream>>>(x, Acat);
    gemm_mfma_kernel<float, 12, 1, 0><<<GSW * 1, 256, 0, stream>>>(Acat, Wpt, bp, hbuf, 128, NNODES);
    cat_from_kernel<<<CATB, TB, 0, stream>>>(hbuf, Acat);

    for (int li = 0; li < 3; ++li) {
        gemm_mfma_kernel<unsigned short, 8, 3, 0><<<GSW * 3, 256, 0, stream>>>(
            Acat, WtQKV + (size_t)li * 384 * KC, bQKV + li * 384, qkvb, 384, NNODES);
        gemm_mfma_kernel<float, 12, 1, 0><<<GSW * 1, 256, 0, stream>>>(
            Acat, WtS + (size_t)li * 128 * KC, bS + li * 128, sfp, 128, NNODES);
        attn_small_kernel<<<NNODES, 64, 0, stream>>>(qkvb, sfp, Wbeta + li * 384,
                                                     offs, csrsrc, obuf);
        float* st = bnstat4 + li * 256;
        bn_stats_kernel<<<640, 128, 0, stream>>>(obuf, st, NNODES);
        bn_apply_kernel<<<512, 128, 0, stream>>>(obuf, st, bn_gamma + li * HIDDIM,
                                                 bn_beta + li * HIDDIM, NNODES, Acat);
    }

    // ---- layer 3: merged q|k|v GEMM into per-head buffers + attention + beta ----
    gemm_mfma_kernel<unsigned short, 8, 24, 3><<<GSW * 24, 256, 0, stream>>>(
        Acat, Wt3, b3, qkv3b, 3072, NNODES);
    gemm_mfma_kernel<float, 12, 1, 0><<<GSW * 1, 256, 0, stream>>>(Acat, Ws3t, bs3, sb, 128, NNODES);
    attn_big_kernel<<<dim3(NNODES, 8), 64, 0, stream>>>(qkv3b, offs, csrsrc, obuf8);
    beta3_kernel<<<NNODES, 128, 0, stream>>>(obuf8, sb, Wbeta3, hbuf);
    float* st3 = bnstat4 + 3 * 256;
    bn_stats_kernel<<<640, 128, 0, stream>>>(hbuf, st3, NNODES);
    bn_apply_kernel<<<512, 128, 0, stream>>>(hbuf, st3, bn_gamma + 3 * HIDDIM,
                                             bn_beta + 3 * HIDDIM, NNODES, (unsigned short*)0);

    zero_kernel<<<(NGRAPH * HIDDIM + TB - 1) / TB, TB, 0, stream>>>(out, NGRAPH * HIDDIM);
    pool_part_kernel<<<dim3(NGRAPH, 8), 256, 0, stream>>>(hbuf, gs, ge, out);
    pool_div_kernel<<<NGRAPH, 128, 0, stream>>>(out, gs, ge);
}

// Round 17
// 692.561 us; speedup vs baseline: 1.0883x; 1.0456x over previous
//
#include <hip/hip_runtime.h>
#include <math.h>

#define NNODES 20000
#define NPAD   20096   // 157 * 128
#define NEDGES 160000
#define HIDDIM 128
#define NHEADS 8
#define NGRAPH 64
#define KC 384   // concatenated K (hi | lo | hi)
#define GXTILES 157

typedef short short8 __attribute__((ext_vector_type(8)));
typedef float floatx4 __attribute__((ext_vector_type(4)));
typedef unsigned short ushort4v __attribute__((ext_vector_type(4)));

__device__ inline unsigned short f2bf(float x) {
    unsigned u = __float_as_uint(x);
    u += 0x7fff + ((u >> 16) & 1);
    return (unsigned short)(u >> 16);
}
__device__ inline float bf2f(unsigned short h) {
    return __uint_as_float(((unsigned)h) << 16);
}

// ---------------- utility ----------------
__global__ __launch_bounds__(256) void zero_kernel(float* __restrict__ p, int n) {
    int i = blockIdx.x * blockDim.x + threadIdx.x;
    if (i < n) p[i] = 0.f;
}

// ---------------- CSR build ----------------
__global__ __launch_bounds__(256) void count_deg_kernel(const int* __restrict__ dst,
                                                        int* __restrict__ deg, int e) {
    int i = blockIdx.x * blockDim.x + threadIdx.x;
    if (i < e) atomicAdd(&deg[dst[i]], 1);
}

__global__ __launch_bounds__(256) void scan1_kernel(const int* __restrict__ deg,
                                                    int* __restrict__ chunk,
                                                    int* __restrict__ bsum, int n) {
    __shared__ int buf[256];
    int t = threadIdx.x;
    int i = blockIdx.x * 256 + t;
    int v = (i < n) ? deg[i] : 0;
    buf[t] = v;
    __syncthreads();
    for (int off = 1; off < 256; off <<= 1) {
        int tmp = (t >= off) ? buf[t - off] : 0;
        __syncthreads();
        buf[t] += tmp;
        __syncthreads();
    }
    if (i < n) chunk[i] = buf[t];
    if (t == 255) bsum[blockIdx.x] = buf[255];
}

__global__ __launch_bounds__(128) void scan2_kernel(int* __restrict__ bsum, int nb) {
    __shared__ int buf[128];
    int t = threadIdx.x;
    int v = (t < nb) ? bsum[t] : 0;
    buf[t] = v;
    __syncthreads();
    for (int off = 1; off < 128; off <<= 1) {
        int tmp = (t >= off) ? buf[t - off] : 0;
        __syncthreads();
        buf[t] += tmp;
        __syncthreads();
    }
    if (t < nb) bsum[t] = buf[t] - v;
}

__global__ __launch_bounds__(256) void scan3_kernel(const int* __restrict__ chunk,
                                                    const int* __restrict__ bsum,
                                                    int* __restrict__ offs, int n) {
    int i = blockIdx.x * 256 + threadIdx.x;
    if (i < n) offs[i + 1] = chunk[i] + bsum[i >> 8];
    if (i == 0) offs[0] = 0;
}

__global__ __launch_bounds__(256) void scatter_kernel(const int* __restrict__ src,
                                                      const int* __restrict__ dst,
                                                      const int* __restrict__ offs,
                                                      int* __restrict__ cursor,
                                                      int* __restrict__ csr_src, int e) {
    int i = blockIdx.x * blockDim.x + threadIdx.x;
    if (i < e) {
        int d = dst[i];
        int pos = offs[d] + atomicAdd(&cursor[d], 1);
        csr_src[pos] = src[i];
    }
}

// ---------------- weight prep ----------------
// Row map: [0,1152): layers0-2 qkv (li*384 + {q,k,v}*128 + j)
// [1152,1536): layers0-2 s ; [1536,1664): Wp ; [1664,1792): Ws3
// [1792,3840): layer3 t|v rows (h*256 + j): j<128 = t (filled by mqk_kernel,
// skipped here), j>=128 = v from Wv3.
__global__ __launch_bounds__(128) void prep_w_kernel(
    const float* __restrict__ Wq, const float* __restrict__ Wk,
    const float* __restrict__ Wv, const float* __restrict__ Ws,
    const float* __restrict__ Wp, const float* __restrict__ Ws3,
    const float* __restrict__ Wv3, unsigned short* __restrict__ WtAll) {
    int id = blockIdx.x;
    int k = threadIdx.x;
    float w;
    if (id < 1152) {
        int li = id / 384, n = id % 384, sel = n >> 7, np = n & 127;
        const float* W = (sel == 0) ? Wq : (sel == 1) ? Wk : Wv;
        w = W[li * 16384 + k * 128 + np];
    } else if (id < 1536) {
        int r = id - 1152, li = r >> 7, np = r & 127;
        w = Ws[li * 16384 + k * 128 + np];
    } else if (id < 1664) {
        w = Wp[k * 128 + (id - 1536)];
    } else if (id < 1792) {
        w = Ws3[k * 128 + (id - 1664)];
    } else {
        int r = id - 1792, h = r >> 8, j = r & 255;
        if (j < 128) return;  // t rows: filled by mqk_kernel
        w = Wv3[k * 1024 + h * 128 + (j - 128)];
    }
    unsigned short hi = f2bf(w);
    unsigned short lo = f2bf(w - bf2f(hi));
    unsigned short* dst = WtAll + (size_t)id * KC;
    dst[k] = hi;
    dst[128 + k] = hi;
    dst[256 + k] = lo;
}

__global__ __launch_bounds__(256) void prep_bias_kernel(
    const float* __restrict__ bq, const float* __restrict__ bk,
    const float* __restrict__ bv, const float* __restrict__ bs,
    const float* __restrict__ bv3, float* __restrict__ bcat) {
    int id = blockIdx.x * 256 + threadIdx.x;
    if (id >= 3584) return;
    float v;
    if (id < 1152) {
        int li = id / 384, n = id % 384, sel = n >> 7, np = n & 127;
        const float* b = (sel == 0) ? bq : (sel == 1) ? bk : bv;
        v = b[li * 128 + np];
    } else if (id < 1536) {
        int r = id - 1152, li = r >> 7, np = r & 127;
        v = bs[li * 128 + np];
    } else {
        int r = id - 1536, h = r >> 8, j = r & 255;
        if (j < 128) return;  // t bias: filled by mqk_kernel
        v = bv3[h * 128 + (j - 128)];
    }
    bcat[id] = v;
}

// ---------------- layer-3 fused QK weights: M_h = Wq_h Wk_h^T ----------------
// block = (h*128 + b), thread = a. t_i[b] = sum_a h_i[a]*M[a][b] + b'[b].
// M[a][b] = sum_d Wq3[a][h,d]*Wk3[b][h,d]; b'[b] = sum_d bq3[h,d]*Wk3[b][h,d].
// Writes split-bf16 weight row 1792 + h*256 + b and bias 1536 + h*256 + b.
__global__ __launch_bounds__(128) void mqk_kernel(
    const float* __restrict__ Wq3, const float* __restrict__ Wk3,
    const float* __restrict__ bq3,
    unsigned short* __restrict__ WtAll, float* __restrict__ bcat) {
    int hb = blockIdx.x;
    int h = hb >> 7, b = hb & 127;
    int a = threadIdx.x;
    __shared__ float wk[128];
    wk[a] = Wk3[(size_t)b * 1024 + h * 128 + a];
    __syncthreads();
    const float* wq = Wq3 + (size_t)a * 1024 + h * 128;
    float acc = 0.f;
#pragma unroll 16
    for (int d = 0; d < 128; ++d) acc = fmaf(wq[d], wk[d], acc);
    unsigned short hi = f2bf(acc);
    unsigned short lo = f2bf(acc - bf2f(hi));
    unsigned short* dst = WtAll + (size_t)(1792 + h * 256 + b) * KC;
    dst[a] = hi;
    dst[128 + a] = hi;
    dst[256 + a] = lo;
    if (a == 0) {
        float bb = 0.f;
        for (int d = 0; d < 128; ++d) bb = fmaf(bq3[h * 128 + d], wk[d], bb);
        bcat[1536 + h * 256 + b] = bb;
    }
}

// ---------------- activation -> split-bf16 A_cat ----------------
__global__ __launch_bounds__(256) void cat_from_kernel(const float* __restrict__ h,
                                                       unsigned short* __restrict__ Acat) {
    int idx = blockIdx.x * 256 + threadIdx.x;
    if (idx >= NPAD * HIDDIM) return;
    int r = idx >> 7, k = idx & 127;
    float x = (r < NNODES) ? h[idx] : 0.f;
    unsigned short hi = f2bf(x);
    unsigned short lo = f2bf(x - bf2f(hi));
    unsigned short* row = Acat + (size_t)r * KC;
    row[k] = hi;
    row[128 + k] = lo;
    row[256 + k] = hi;
}

// ---------------- MFMA GEMM (XCD swizzle; optional per-head output layout) ----------------
// HT=0: C[node*M + col]. HT>0: head h = by/HT, tile lt = by%HT,
// C[((h*NNODES)+node)*(HT*128) + lt*128 + f].
template <typename OutT, int KG, int BY, int HT>
__global__ __launch_bounds__(256) void gemm_mfma_kernel(
    const unsigned short* __restrict__ Acat, const unsigned short* __restrict__ Wt,
    const float* __restrict__ bias, OutT* __restrict__ C, int M, int nrows) {
    int id = blockIdx.x;
    int xcd = id & 7;
    int idx = id >> 3;
    int bx = (idx / BY) * 8 + xcd;
    int by = idx % BY;
    if (bx >= GXTILES) return;
    int lane = threadIdx.x & 63;
    int wave = threadIdx.x >> 6;
    int nodeBase = bx * 128 + (wave & 1) * 64;
    int featBase = by * 128 + (wave >> 1) * 64;
    int m = lane & 15;
    int q = lane >> 4;
    int ko = q * 8;
    const unsigned short* wptr = Wt + (size_t)(featBase + m) * KC + ko;    // A operand
    const unsigned short* aptr = Acat + (size_t)(nodeBase + m) * KC + ko;  // B operand
    floatx4 acc[4][4];  // [feat tile r][node tile c]
#pragma unroll
    for (int r = 0; r < 4; ++r)
#pragma unroll
        for (int c = 0; c < 4; ++c) acc[r][c] = (floatx4){0.f, 0.f, 0.f, 0.f};
#pragma unroll
    for (int kg = 0; kg < KG; ++kg) {
        short8 a[4], b[4];
#pragma unroll
        for (int r = 0; r < 4; ++r) a[r] = *(const short8*)(wptr + (size_t)r * 16 * KC + kg * 32);
#pragma unroll
        for (int c = 0; c < 4; ++c) b[c] = *(const short8*)(aptr + (size_t)c * 16 * KC + kg * 32);
#pragma unroll
        for (int r = 0; r < 4; ++r)
#pragma unroll
            for (int c = 0; c < 4; ++c)
                acc[r][c] = __builtin_amdgcn_mfma_f32_16x16x32_bf16(a[r], b[c], acc[r][c], 0, 0, 0);
    }
    size_t rowLen = (HT > 0) ? (size_t)(HT * 128) : (size_t)M;
    size_t headOff = 0;
    int colBase;
    if (HT > 0) {
        int h = by / HT, lt = by % HT;
        headOff = (size_t)h * NNODES * rowLen;
        colBase = lt * 128 + (wave >> 1) * 64;
    } else {
        colBase = featBase;
    }
    float4 bv[4];
#pragma unroll
    for (int r = 0; r < 4; ++r) bv[r] = *(const float4*)(bias + featBase + r * 16 + q * 4);
#pragma unroll
    for (int c = 0; c < 4; ++c) {
        int node = nodeBase + c * 16 + m;
        if (node < nrows) {
            size_t rbase = headOff + (size_t)node * rowLen;
#pragma unroll
            for (int r = 0; r < 4; ++r) {
                int f0 = colBase + r * 16 + q * 4;
                float v0 = acc[r][c][0] + bv[r].x;
                float v1 = acc[r][c][1] + bv[r].y;
                float v2 = acc[r][c][2] + bv[r].z;
                float v3 = acc[r][c][3] + bv[r].w;
                if (sizeof(OutT) == 2) {
                    ushort4v o = {f2bf(v0), f2bf(v1), f2bf(v2), f2bf(v3)};
                    *(ushort4v*)((unsigned short*)C + rbase + f0) = o;
                } else {
                    float4 o = {v0, v1, v2, v3};
                    *(float4*)((float*)C + rbase + f0) = o;
                }
            }
        }
    }
}

// ---------------- attention layers 0-2: qkv bf16 [N][384], s fp32 [N][128] ----------------
__global__ __launch_bounds__(64) void attn_small_kernel(
    const unsigned short* __restrict__ qkv, const float* __restrict__ sfp,
    const float* __restrict__ Wb,
    const int* __restrict__ offs, const int* __restrict__ csr_src,
    float* __restrict__ out) {
    int i = blockIdx.x;
    int l = threadIdx.x;
    int g = l >> 5;
    int d0 = (l & 31) * 4;
    uint2 qraw = *(const uint2*)(qkv + (size_t)i * 384 + d0);
    float q0 = bf2f((unsigned short)(qraw.x & 0xffff)), q1 = bf2f((unsigned short)(qraw.x >> 16));
    float q2 = bf2f((unsigned short)(qraw.y & 0xffff)), q3 = bf2f((unsigned short)(qraw.y >> 16));
    int e0 = offs[i], e1 = offs[i + 1];
    float mm = -1e30f, lac = 0.f;
    float a0 = 0.f, a1 = 0.f, a2 = 0.f, a3 = 0.f;
    for (int e = e0 + g; e < e1; e += 2) {
        int sn = csr_src[e];
        const unsigned short* row = qkv + (size_t)sn * 384;
        uint2 kk = *(const uint2*)(row + 128 + d0);
        uint2 vv = *(const uint2*)(row + 256 + d0);
        float k0 = bf2f((unsigned short)(kk.x & 0xffff)), k1 = bf2f((unsigned short)(kk.x >> 16));
        float k2 = bf2f((unsigned short)(kk.y & 0xffff)), k3 = bf2f((unsigned short)(kk.y >> 16));
        float p = q0 * k0 + q1 * k1 + q2 * k2 + q3 * k3;
        p += __shfl_xor(p, 1);
        p += __shfl_xor(p, 2);
        float logit = p * 0.25f;
        float mnew = fmaxf(mm, logit);
        float sc = __expf(mm - mnew);
        float w = __expf(logit - mnew);
        float v0 = bf2f((unsigned short)(vv.x & 0xffff)), v1 = bf2f((unsigned short)(vv.x >> 16));
        float v2 = bf2f((unsigned short)(vv.y & 0xffff)), v3 = bf2f((unsigned short)(vv.y >> 16));
        a0 = a0 * sc + w * v0;
        a1 = a1 * sc + w * v1;
        a2 = a2 * sc + w * v2;
        a3 = a3 * sc + w * v3;
        lac = lac * sc + w;
        mm = mnew;
    }
    float mo = __shfl_xor(mm, 32), lo = __shfl_xor(lac, 32);
    float b0 = __shfl_xor(a0, 32), b1 = __shfl_xor(a1, 32);
    float b2 = __shfl_xor(a2, 32), b3 = __shfl_xor(a3, 32);
    float ms = fmaxf(mm, mo);
    float s0 = __expf(mm - ms), s1 = __expf(mo - ms);
    a0 = a0 * s0 + b0 * s1;
    a1 = a1 * s0 + b1 * s1;
    a2 = a2 * s0 + b2 * s1;
    a3 = a3 * s0 + b3 * s1;
    lac = lac * s0 + lo * s1;
    float inv = 1.f / (lac + 1e-16f);
    float o0 = a0 * inv, o1 = a1 * inv, o2 = a2 * inv, o3 = a3 * inv;
    float4 rv = *(const float4*)(sfp + (size_t)i * HIDDIM + d0);
    float part = o0 * Wb[d0] + o1 * Wb[d0 + 1] + o2 * Wb[d0 + 2] + o3 * Wb[d0 + 3]
               + rv.x * Wb[128 + d0] + rv.y * Wb[128 + d0 + 1]
               + rv.z * Wb[128 + d0 + 2] + rv.w * Wb[128 + d0 + 3]
               + (o0 - rv.x) * Wb[256 + d0] + (o1 - rv.y) * Wb[256 + d0 + 1]
               + (o2 - rv.z) * Wb[256 + d0 + 2] + (o3 - rv.w) * Wb[256 + d0 + 3];
    if (g) part = 0.f;
#pragma unroll
    for (int msk = 1; msk <= 32; msk <<= 1) part += __shfl_xor(part, msk);
    float gg = 1.f / (1.f + __expf(-part));
    if (g == 0) {
        float4 o4 = {gg * rv.x + (1.f - gg) * o0, gg * rv.y + (1.f - gg) * o1,
                     gg * rv.z + (1.f - gg) * o2, gg * rv.w + (1.f - gg) * o3};
        *(float4*)(out + (size_t)i * HIDDIM + d0) = o4;
    }
}

// ---------------- attention layer 3: t|v per head [8][N][256]; k = Acat hi ----------------
// logit = t_i . h_j * rsqrt(128) (softmax-shift trick: q.k = t.h_j + const_i).
// h_j rows (256 B in Acat) are shared across all 8 heads -> L2 reuse.
__global__ __launch_bounds__(64) void attn_big_kernel(
    const unsigned short* __restrict__ qtv, const unsigned short* __restrict__ Acat,
    const int* __restrict__ offs, const int* __restrict__ csr_src,
    unsigned short* __restrict__ obuf8) {
    int i = blockIdx.x;
    int y = blockIdx.y;
    int l = threadIdx.x;
    int g = l >> 4;
    int s = l & 15;
    const unsigned short* base = qtv + (size_t)y * NNODES * 256;
    uint4 qq = *(const uint4*)(base + (size_t)i * 256 + 8 * s);
    float q0 = bf2f((unsigned short)(qq.x & 0xffff)), q1 = bf2f((unsigned short)(qq.x >> 16));
    float q2 = bf2f((unsigned short)(qq.y & 0xffff)), q3f = bf2f((unsigned short)(qq.y >> 16));
    float q4 = bf2f((unsigned short)(qq.z & 0xffff)), q5 = bf2f((unsigned short)(qq.z >> 16));
    float q6 = bf2f((unsigned short)(qq.w & 0xffff)), q7 = bf2f((unsigned short)(qq.w >> 16));
    int e0 = offs[i], e1 = offs[i + 1];
    float mm = -1e30f, lac = 0.f;
    float ac[8];
#pragma unroll
    for (int j = 0; j < 8; ++j) ac[j] = 0.f;
    for (int e = e0 + g; e < e1; e += 4) {
        int sn = csr_src[e];
        uint4 kk = *(const uint4*)(Acat + (size_t)sn * KC + 8 * s);  // h_j hi
        uint4 vv = *(const uint4*)(base + (size_t)sn * 256 + 128 + 8 * s);
        float k0 = bf2f((unsigned short)(kk.x & 0xffff)), k1 = bf2f((unsigned short)(kk.x >> 16));
        float k2 = bf2f((unsigned short)(kk.y & 0xffff)), k3 = bf2f((unsigned short)(kk.y >> 16));
        float k4 = bf2f((unsigned short)(kk.z & 0xffff)), k5 = bf2f((unsigned short)(kk.z >> 16));
        float k6 = bf2f((unsigned short)(kk.w & 0xffff)), k7 = bf2f((unsigned short)(kk.w >> 16));
        float p = q0 * k0 + q1 * k1 + q2 * k2 + q3f * k3
                + q4 * k4 + q5 * k5 + q6 * k6 + q7 * k7;
        p += __shfl_xor(p, 1);
        p += __shfl_xor(p, 2);
        p += __shfl_xor(p, 4);
        p += __shfl_xor(p, 8);
        float logit = p * 0.08838834764831845f;
        float mnew = fmaxf(mm, logit);
        float sc = __expf(mm - mnew);
        float w = __expf(logit - mnew);
        float v0 = bf2f((unsigned short)(vv.x & 0xffff)), v1 = bf2f((unsigned short)(vv.x >> 16));
        float v2 = bf2f((unsigned short)(vv.y & 0xffff)), v3 = bf2f((unsigned short)(vv.y >> 16));
        float v4 = bf2f((unsigned short)(vv.z & 0xffff)), v5 = bf2f((unsigned short)(vv.z >> 16));
        float v6 = bf2f((unsigned short)(vv.w & 0xffff)), v7 = bf2f((unsigned short)(vv.w >> 16));
        ac[0] = ac[0] * sc + w * v0; ac[1] = ac[1] * sc + w * v1;
        ac[2] = ac[2] * sc + w * v2; ac[3] = ac[3] * sc + w * v3;
        ac[4] = ac[4] * sc + w * v4; ac[5] = ac[5] * sc + w * v5;
        ac[6] = ac[6] * sc + w * v6; ac[7] = ac[7] * sc + w * v7;
        lac = lac * sc + w;
        mm = mnew;
    }
#pragma unroll
    for (int msk = 16; msk <= 32; msk <<= 1) {
        float mo = __shfl_xor(mm, msk), lo = __shfl_xor(lac, msk);
        float bo[8];
#pragma unroll
        for (int j = 0; j < 8; ++j) bo[j] = __shfl_xor(ac[j], msk);
        float ms = fmaxf(mm, mo);
        float s0 = __expf(mm - ms), s1 = __expf(mo - ms);
#pragma unroll
        for (int j = 0; j < 8; ++j) ac[j] = ac[j] * s0 + bo[j] * s1;
        lac = lac * s0 + lo * s1;
        mm = ms;
    }
    if (g == 0) {
        float inv = 1.f / (lac + 1e-16f);
        ushort4v w0 = {f2bf(ac[0] * inv), f2bf(ac[1] * inv), f2bf(ac[2] * inv), f2bf(ac[3] * inv)};
        ushort4v w1 = {f2bf(ac[4] * inv), f2bf(ac[5] * inv), f2bf(ac[6] * inv), f2bf(ac[7] * inv)};
        unsigned short* o = obuf8 + ((size_t)y * NNODES + i) * HIDDIM + 8 * s;
        *(ushort4v*)o = w0;
        *(ushort4v*)(o + 4) = w1;
    }
}

// ---------------- beta gate layer 3 (head mean over 8 bf16 slices) ----------------
__global__ __launch_bounds__(128) void beta3_kernel(const unsigned short* __restrict__ obuf8,
                                                    const float* __restrict__ s,
                                                    const float* __restrict__ Wb,
                                                    float* __restrict__ out) {
    int i = blockIdx.x, t = threadIdx.x;
    float o = 0.f;
#pragma unroll
    for (int y = 0; y < 8; ++y) o += bf2f(obuf8[((size_t)y * NNODES + i) * HIDDIM + t]);
    o *= 0.125f;
    float r = s[(size_t)i * HIDDIM + t];
    float part = o * Wb[t] + r * Wb[128 + t] + (o - r) * Wb[256 + t];
#pragma unroll
    for (int msk = 1; msk <= 32; msk <<= 1) part += __shfl_xor(part, msk);
    __shared__ float wsum[2];
    if ((t & 63) == 0) wsum[t >> 6] = part;
    __syncthreads();
    float tot = wsum[0] + wsum[1];
    float g = 1.f / (1.f + __expf(-tot));
    out[(size_t)i * HIDDIM + t] = g * r + (1.f - g) * o;
}

// ---------------- batchnorm ----------------
__global__ __launch_bounds__(128) void bn_stats_kernel(const float* __restrict__ x,
                                                       float* __restrict__ stat, int n) {
    int t = threadIdx.x;
    float s = 0.f, sq = 0.f;
    for (int i = blockIdx.x; i < n; i += gridDim.x) {
        float v = x[(size_t)i * HIDDIM + t];
        s += v;
        sq += v * v;
    }
    atomicAdd(&stat[t], s);
    atomicAdd(&stat[HIDDIM + t], sq);
}

__global__ __launch_bounds__(128) void bn_apply_kernel(float* __restrict__ x,
                                                       const float* __restrict__ stat,
                                                       const float* __restrict__ gamma,
                                                       const float* __restrict__ beta, int n,
                                                       unsigned short* __restrict__ cat) {
    int t = threadIdx.x;
    float mu = stat[t] / (float)n;
    float var = stat[HIDDIM + t] / (float)n - mu * mu;
    float rs = rsqrtf(var + 1e-5f);
    float g = gamma[t], b = beta[t];
    for (int i = blockIdx.x; i < n; i += gridDim.x) {
        float v = x[(size_t)i * HIDDIM + t];
        v = fmaxf((v - mu) * rs * g + b, 0.f);
        x[(size_t)i * HIDDIM + t] = v;
        if (cat) {
            unsigned short hi = f2bf(v);
            unsigned short lo = f2bf(v - bf2f(hi));
            unsigned short* row = cat + (size_t)i * KC;
            row[t] = hi;
            row[128 + t] = lo;
            row[256 + t] = hi;
        }
    }
}

// ---------------- pool ----------------
__global__ __launch_bounds__(256) void gb_kernel(const int* __restrict__ batch,
                                                 int* __restrict__ gs,
                                                 int* __restrict__ ge, int n) {
    int i = blockIdx.x * 256 + threadIdx.x;
    if (i >= n) return;
    int b = batch[i];
    if (i == 0 || batch[i - 1] != b) gs[b] = i;
    if (i == n - 1 || batch[i + 1] != b) ge[b] = i + 1;
}

__global__ __launch_bounds__(256) void pool_part_kernel(const float* __restrict__ x,
                                                        const int* __restrict__ gs,
                                                        const int* __restrict__ ge,
                                                        float* __restrict__ out) {
    int g = blockIdx.x, c = blockIdx.y;
    int t = threadIdx.x;
    int f = t & 127, half = t >> 7;
    int s = gs[g], e = ge[g];
    float acc = 0.f;
    for (int i = s + 2 * c + half; i < e; i += 16) acc += x[(size_t)i * HIDDIM + f];
    __shared__ float l0[128];
    if (half == 0) l0[f] = acc;
    __syncthreads();
    if (half == 1) atomicAdd(&out[g * HIDDIM + f], l0[f] + acc);
}

__global__ __launch_bounds__(128) void pool_div_kernel(float* __restrict__ out,
                                                       const int* __restrict__ gs,
                                                       const int* __restrict__ ge) {
    int g = blockIdx.x, t = threadIdx.x;
    int c = ge[g] - gs[g];
    out[g * HIDDIM + t] /= (float)(c > 0 ? c : 1);
}

// ---------------- host ----------------
extern "C" void kernel_launch(void* const* d_in, const int* in_sizes, int n_in,
                              void* d_out, int out_size, void* d_ws, size_t ws_size,
                              hipStream_t stream) {
    const float* x       = (const float*)d_in[0];
    const int*   ei      = (const int*)d_in[1];
    const int*   batch   = (const int*)d_in[2];
    const float* Wp      = (const float*)d_in[3];
    const float* bp      = (const float*)d_in[4];
    const float* Wq      = (const float*)d_in[5];
    const float* bq      = (const float*)d_in[6];
    const float* Wk      = (const float*)d_in[7];
    const float* bk      = (const float*)d_in[8];
    const float* Wv      = (const float*)d_in[9];
    const float* bv      = (const float*)d_in[10];
    const float* Ws      = (const float*)d_in[11];
    const float* bs      = (const float*)d_in[12];
    const float* Wbeta   = (const float*)d_in[13];
    const float* Wq3     = (const float*)d_in[14];
    const float* bq3     = (const float*)d_in[15];
    const float* Wk3     = (const float*)d_in[16];
    const float* bk3     = (const float*)d_in[17];
    const float* Wv3     = (const float*)d_in[18];
    const float* bv3     = (const float*)d_in[19];
    const float* Ws3     = (const float*)d_in[20];
    const float* bs3     = (const float*)d_in[21];
    const float* Wbeta3  = (const float*)d_in[22];
    const float* bn_gamma = (const float*)d_in[23];
    const float* bn_beta  = (const float*)d_in[24];
    float* out = (float*)d_out;
    (void)bk3;

    const int* esrc = ei;
    const int* edst = ei + NEDGES;

    char* wpc = (char*)d_ws;
    auto alloc = [&](size_t nbytes) -> char* {
        char* p = wpc;
        wpc += (nbytes + 255) & ~(size_t)255;
        return p;
    };
    unsigned short* Acat  = (unsigned short*)alloc((size_t)NPAD * KC * 2);      // 15.4 MB
    unsigned short* WtAll = (unsigned short*)alloc((size_t)3840 * KC * 2);      // 2.9 MB
    float* bcat   = (float*)alloc(3584 * 4);
    unsigned short* qtv   = (unsigned short*)alloc((size_t)NHEADS * NNODES * 256 * 2);  // 81.9 MB
    float* sfp    = (float*)alloc((size_t)NNODES * HIDDIM * 4);                 // 10.2 MB
    unsigned short* obuf8 = (unsigned short*)alloc((size_t)8 * NNODES * HIDDIM * 2);    // 41 MB
    float* hbuf   = (float*)alloc((size_t)NNODES * HIDDIM * 4);
    float* obuf   = (float*)alloc((size_t)NNODES * HIDDIM * 4);
    float* sb     = (float*)alloc((size_t)NNODES * HIDDIM * 4);
    int*   deg    = (int*)alloc((2 * NNODES + 128 + 4 * 256) * 4);
    int*   cursor = deg + NNODES;
    int*   gs     = deg + 2 * NNODES;
    int*   ge     = gs + NGRAPH;
    float* bnstat4 = (float*)(deg + 2 * NNODES + 128);
    int*   chunk  = (int*)alloc(NNODES * 4);
    int*   bsum   = (int*)alloc(128 * 4);
    int*   offs   = (int*)alloc((NNODES + 1) * 4);
    int*   csrsrc = (int*)alloc(NEDGES * 4);

    unsigned short* WtQKV = WtAll;                       // [3][384][KC]
    unsigned short* WtS   = WtAll + (size_t)1152 * KC;   // [3][128][KC]
    unsigned short* Wpt   = WtAll + (size_t)1536 * KC;
    unsigned short* Ws3t  = WtAll + (size_t)1664 * KC;
    unsigned short* Wt3   = WtAll + (size_t)1792 * KC;   // [8][256][KC] t|v
    float* bQKV = bcat;          // [3][384]
    float* bS   = bcat + 1152;   // [3][128]
    float* b3   = bcat + 1536;   // [2048]
    unsigned short* qkvb = qtv;  // layers 0-2 alias: [N][384]

    const int TB = 256;
    const int ZWORDS = 2 * NNODES + 128 + 4 * 256;
    zero_kernel<<<(ZWORDS + TB - 1) / TB, TB, 0, stream>>>((float*)deg, ZWORDS);
    count_deg_kernel<<<(NEDGES + TB - 1) / TB, TB, 0, stream>>>(edst, deg, NEDGES);
    const int NB = (NNODES + 255) / 256;
    scan1_kernel<<<NB, 256, 0, stream>>>(deg, chunk, bsum, NNODES);
    scan2_kernel<<<1, 128, 0, stream>>>(bsum, NB);
    scan3_kernel<<<NB, 256, 0, stream>>>(chunk, bsum, offs, NNODES);
    scatter_kernel<<<(NEDGES + TB - 1) / TB, TB, 0, stream>>>(esrc, edst, offs, cursor, csrsrc, NEDGES);
    gb_kernel<<<(NNODES + TB - 1) / TB, TB, 0, stream>>>(batch, gs, ge, NNODES);

    prep_w_kernel<<<3840, 128, 0, stream>>>(Wq, Wk, Wv, Ws, Wp, Ws3, Wv3, WtAll);
    prep_bias_kernel<<<(3584 + TB - 1) / TB, TB, 0, stream>>>(bq, bk, bv, bs, bv3, bcat);
    mqk_kernel<<<1024, 128, 0, stream>>>(Wq3, Wk3, bq3, WtAll, bcat);

    const int CATB = (NPAD * HIDDIM + TB - 1) / TB;
    const int GSW = 8 * ((GXTILES + 7) / 8);  // 160 swizzled x-slots

    cat_from_kernel<<<CATB, TB, 0, stream>>>(x, Acat);
    gemm_mfma_kernel<float, 12, 1, 0><<<GSW * 1, 256, 0, stream>>>(Acat, Wpt, bp, hbuf, 128, NNODES);
    cat_from_kernel<<<CATB, TB, 0, stream>>>(hbuf, Acat);

    for (int li = 0; li < 3; ++li) {
        gemm_mfma_kernel<unsigned short, 8, 3, 0><<<GSW * 3, 256, 0, stream>>>(
            Acat, WtQKV + (size_t)li * 384 * KC, bQKV + li * 384, qkvb, 384, NNODES);
        gemm_mfma_kernel<float, 12, 1, 0><<<GSW * 1, 256, 0, stream>>>(
            Acat, WtS + (size_t)li * 128 * KC, bS + li * 128, sfp, 128, NNODES);
        attn_small_kernel<<<NNODES, 64, 0, stream>>>(qkvb, sfp, Wbeta + li * 384,
                                                     offs, csrsrc, obuf);
        float* st = bnstat4 + li * 256;
        bn_stats_kernel<<<640, 128, 0, stream>>>(obuf, st, NNODES);
        bn_apply_kernel<<<512, 128, 0, stream>>>(obuf, st, bn_gamma + li * HIDDIM,
                                                 bn_beta + li * HIDDIM, NNODES, Acat);
    }

    // ---- layer 3: t|v GEMM (2048 cols, per-head layout) + attention + beta ----
    gemm_mfma_kernel<unsigned short, 8, 16, 2><<<GSW * 16, 256, 0, stream>>>(
        Acat, Wt3, b3, qtv, 2048, NNODES);
    gemm_mfma_kernel<float, 12, 1, 0><<<GSW * 1, 256, 0, stream>>>(Acat, Ws3t, bs3, sb, 128, NNODES);
    attn_big_kernel<<<dim3(NNODES, 8), 64, 0, stream>>>(qtv, Acat, offs, csrsrc, obuf8);
    beta3_kernel<<<NNODES, 128, 0, stream>>>(obuf8, sb, Wbeta3, hbuf);
    float* st3 = bnstat4 + 3 * 256;
    bn_stats_kernel<<<640, 128, 0, stream>>>(hbuf, st3, NNODES);
    bn_apply_kernel<<<512, 128, 0, stream>>>(hbuf, st3, bn_gamma + 3 * HIDDIM,
                                             bn_beta + 3 * HIDDIM, NNODES, (unsigned short*)0);

    zero_kernel<<<(NGRAPH * HIDDIM + TB - 1) / TB, TB, 0, stream>>>(out, NGRAPH * HIDDIM);
    pool_part_kernel<<<dim3(NGRAPH, 8), 256, 0, stream>>>(hbuf, gs, ge, out);
    pool_div_kernel<<<NGRAPH, 128, 0, stream>>>(out, gs, ge);
}

// Round 18
// 672.935 us; speedup vs baseline: 1.1200x; 1.0292x over previous
//
#include <hip/hip_runtime.h>
#include <math.h>

#define NNODES 20000
#define NPAD   20096   // 157 * 128
#define NEDGES 160000
#define HIDDIM 128
#define NHEADS 8
#define NGRAPH 64
#define KC 384   // concatenated K (hi | lo | hi)
#define GXTILES 157

typedef short short8 __attribute__((ext_vector_type(8)));
typedef float floatx4 __attribute__((ext_vector_type(4)));
typedef unsigned short ushort4v __attribute__((ext_vector_type(4)));

__device__ inline unsigned short f2bf(float x) {
    unsigned u = __float_as_uint(x);
    u += 0x7fff + ((u >> 16) & 1);
    return (unsigned short)(u >> 16);
}
__device__ inline float bf2f(unsigned short h) {
    return __uint_as_float(((unsigned)h) << 16);
}

// ---------------- utility ----------------
__global__ __launch_bounds__(256) void zero_kernel(float* __restrict__ p, int n) {
    int i = blockIdx.x * blockDim.x + threadIdx.x;
    if (i < n) p[i] = 0.f;
}

// ---------------- CSR build ----------------
__global__ __launch_bounds__(256) void count_deg_kernel(const int* __restrict__ dst,
                                                        int* __restrict__ deg, int e) {
    int i = blockIdx.x * blockDim.x + threadIdx.x;
    if (i < e) atomicAdd(&deg[dst[i]], 1);
}

__global__ __launch_bounds__(256) void scan1_kernel(const int* __restrict__ deg,
                                                    int* __restrict__ chunk,
                                                    int* __restrict__ bsum, int n) {
    __shared__ int buf[256];
    int t = threadIdx.x;
    int i = blockIdx.x * 256 + t;
    int v = (i < n) ? deg[i] : 0;
    buf[t] = v;
    __syncthreads();
    for (int off = 1; off < 256; off <<= 1) {
        int tmp = (t >= off) ? buf[t - off] : 0;
        __syncthreads();
        buf[t] += tmp;
        __syncthreads();
    }
    if (i < n) chunk[i] = buf[t];
    if (t == 255) bsum[blockIdx.x] = buf[255];
}

__global__ __launch_bounds__(128) void scan2_kernel(int* __restrict__ bsum, int nb) {
    __shared__ int buf[128];
    int t = threadIdx.x;
    int v = (t < nb) ? bsum[t] : 0;
    buf[t] = v;
    __syncthreads();
    for (int off = 1; off < 128; off <<= 1) {
        int tmp = (t >= off) ? buf[t - off] : 0;
        __syncthreads();
        buf[t] += tmp;
        __syncthreads();
    }
    if (t < nb) bsum[t] = buf[t] - v;
}

__global__ __launch_bounds__(256) void scan3_kernel(const int* __restrict__ chunk,
                                                    const int* __restrict__ bsum,
                                                    int* __restrict__ offs, int n) {
    int i = blockIdx.x * 256 + threadIdx.x;
    if (i < n) offs[i + 1] = chunk[i] + bsum[i >> 8];
    if (i == 0) offs[0] = 0;
}

__global__ __launch_bounds__(256) void scatter_kernel(const int* __restrict__ src,
                                                      const int* __restrict__ dst,
                                                      const int* __restrict__ offs,
                                                      int* __restrict__ cursor,
                                                      int* __restrict__ csr_src, int e) {
    int i = blockIdx.x * blockDim.x + threadIdx.x;
    if (i < e) {
        int d = dst[i];
        int pos = offs[d] + atomicAdd(&cursor[d], 1);
        csr_src[pos] = src[i];
    }
}

// ---------------- weight prep ----------------
// Rows: [0,1152) layers qkv ; [1152,1536) layers s ; [1536,1664) Wp ;
// [1664,1792) Ws3 ; [1792,2816) layer3 t rows (mqk fills) ;
// [2816,3840) layer3 v-proj rows (h*128+j) from Wv3.
__global__ __launch_bounds__(128) void prep_w_kernel(
    const float* __restrict__ Wq, const float* __restrict__ Wk,
    const float* __restrict__ Wv, const float* __restrict__ Ws,
    const float* __restrict__ Wp, const float* __restrict__ Ws3,
    const float* __restrict__ Wv3, unsigned short* __restrict__ WtAll) {
    int id = blockIdx.x;
    int k = threadIdx.x;
    float w;
    if (id < 1152) {
        int li = id / 384, n = id % 384, sel = n >> 7, np = n & 127;
        const float* W = (sel == 0) ? Wq : (sel == 1) ? Wk : Wv;
        w = W[li * 16384 + k * 128 + np];
    } else if (id < 1536) {
        int r = id - 1152, li = r >> 7, np = r & 127;
        w = Ws[li * 16384 + k * 128 + np];
    } else if (id < 1664) {
        w = Wp[k * 128 + (id - 1536)];
    } else if (id < 1792) {
        w = Ws3[k * 128 + (id - 1664)];
    } else if (id < 2816) {
        return;  // t rows: filled by mqk_kernel
    } else {
        int r = id - 2816, h = r >> 7, j = r & 127;
        w = Wv3[k * 1024 + h * 128 + j];
    }
    unsigned short hi = f2bf(w);
    unsigned short lo = f2bf(w - bf2f(hi));
    unsigned short* dst = WtAll + (size_t)id * KC;
    dst[k] = hi;
    dst[128 + k] = hi;
    dst[256 + k] = lo;
}

// bias: [0,1152) qkv ; [1152,1536) s ; [1536,2560) t bias (mqk fills) ;
// [2560,3584) v-proj bias = bv3
__global__ __launch_bounds__(256) void prep_bias_kernel(
    const float* __restrict__ bq, const float* __restrict__ bk,
    const float* __restrict__ bv, const float* __restrict__ bs,
    const float* __restrict__ bv3, float* __restrict__ bcat) {
    int id = blockIdx.x * 256 + threadIdx.x;
    if (id >= 3584) return;
    float v;
    if (id < 1152) {
        int li = id / 384, n = id % 384, sel = n >> 7, np = n & 127;
        const float* b = (sel == 0) ? bq : (sel == 1) ? bk : bv;
        v = b[li * 128 + np];
    } else if (id < 1536) {
        int r = id - 1152, li = r >> 7, np = r & 127;
        v = bs[li * 128 + np];
    } else if (id < 2560) {
        return;  // t bias: mqk fills
    } else {
        v = bv3[id - 2560];
    }
    bcat[id] = v;
}

// ---------------- layer-3 fused QK weights: M_h = Wq_h Wk_h^T ----------------
// t_i[b] = sum_a h_i[a]*M[a][b] + (bq_h . Wk_h[b]); row 1792 + h*128 + b.
__global__ __launch_bounds__(128) void mqk_kernel(
    const float* __restrict__ Wq3, const float* __restrict__ Wk3,
    const float* __restrict__ bq3,
    unsigned short* __restrict__ WtAll, float* __restrict__ bcat) {
    int hb = blockIdx.x;
    int h = hb >> 7, b = hb & 127;
    int a = threadIdx.x;
    __shared__ float wk[128];
    wk[a] = Wk3[(size_t)b * 1024 + h * 128 + a];
    __syncthreads();
    const float* wq = Wq3 + (size_t)a * 1024 + h * 128;
    float acc = 0.f;
#pragma unroll 16
    for (int d = 0; d < 128; ++d) acc = fmaf(wq[d], wk[d], acc);
    unsigned short hi = f2bf(acc);
    unsigned short lo = f2bf(acc - bf2f(hi));
    unsigned short* dst = WtAll + (size_t)(1792 + h * 128 + b) * KC;
    dst[a] = hi;
    dst[128 + a] = hi;
    dst[256 + a] = lo;
    if (a == 0) {
        float bb = 0.f;
        for (int d = 0; d < 128; ++d) bb = fmaf(bq3[h * 128 + d], wk[d], bb);
        bcat[1536 + h * 128 + b] = bb;
    }
}

// ---------------- activation -> split-bf16 A_cat ----------------
__global__ __launch_bounds__(256) void cat_from_kernel(const float* __restrict__ h,
                                                       unsigned short* __restrict__ Acat) {
    int idx = blockIdx.x * 256 + threadIdx.x;
    if (idx >= NPAD * HIDDIM) return;
    int r = idx >> 7, k = idx & 127;
    float x = (r < NNODES) ? h[idx] : 0.f;
    unsigned short hi = f2bf(x);
    unsigned short lo = f2bf(x - bf2f(hi));
    unsigned short* row = Acat + (size_t)r * KC;
    row[k] = hi;
    row[128 + k] = lo;
    row[256 + k] = hi;
}

// ---------------- MFMA GEMM (XCD swizzle; optional per-head output layout) ----------------
template <typename OutT, int KG, int BY, int HT>
__global__ __launch_bounds__(256) void gemm_mfma_kernel(
    const unsigned short* __restrict__ Acat, const unsigned short* __restrict__ Wt,
    const float* __restrict__ bias, OutT* __restrict__ C, int M, int nrows) {
    int id = blockIdx.x;
    int xcd = id & 7;
    int idx = id >> 3;
    int bx = (idx / BY) * 8 + xcd;
    int by = idx % BY;
    if (bx >= GXTILES) return;
    int lane = threadIdx.x & 63;
    int wave = threadIdx.x >> 6;
    int nodeBase = bx * 128 + (wave & 1) * 64;
    int featBase = by * 128 + (wave >> 1) * 64;
    int m = lane & 15;
    int q = lane >> 4;
    int ko = q * 8;
    const unsigned short* wptr = Wt + (size_t)(featBase + m) * KC + ko;
    const unsigned short* aptr = Acat + (size_t)(nodeBase + m) * KC + ko;
    floatx4 acc[4][4];
#pragma unroll
    for (int r = 0; r < 4; ++r)
#pragma unroll
        for (int c = 0; c < 4; ++c) acc[r][c] = (floatx4){0.f, 0.f, 0.f, 0.f};
#pragma unroll
    for (int kg = 0; kg < KG; ++kg) {
        short8 a[4], b[4];
#pragma unroll
        for (int r = 0; r < 4; ++r) a[r] = *(const short8*)(wptr + (size_t)r * 16 * KC + kg * 32);
#pragma unroll
        for (int c = 0; c < 4; ++c) b[c] = *(const short8*)(aptr + (size_t)c * 16 * KC + kg * 32);
#pragma unroll
        for (int r = 0; r < 4; ++r)
#pragma unroll
            for (int c = 0; c < 4; ++c)
                acc[r][c] = __builtin_amdgcn_mfma_f32_16x16x32_bf16(a[r], b[c], acc[r][c], 0, 0, 0);
    }
    size_t rowLen = (HT > 0) ? (size_t)(HT * 128) : (size_t)M;
    size_t headOff = 0;
    int colBase;
    if (HT > 0) {
        int h = by / HT, lt = by % HT;
        headOff = (size_t)h * NNODES * rowLen;
        colBase = lt * 128 + (wave >> 1) * 64;
    } else {
        colBase = featBase;
    }
    float4 bv[4];
#pragma unroll
    for (int r = 0; r < 4; ++r) bv[r] = *(const float4*)(bias + featBase + r * 16 + q * 4);
#pragma unroll
    for (int c = 0; c < 4; ++c) {
        int node = nodeBase + c * 16 + m;
        if (node < nrows) {
            size_t rbase = headOff + (size_t)node * rowLen;
#pragma unroll
            for (int r = 0; r < 4; ++r) {
                int f0 = colBase + r * 16 + q * 4;
                float v0 = acc[r][c][0] + bv[r].x;
                float v1 = acc[r][c][1] + bv[r].y;
                float v2 = acc[r][c][2] + bv[r].z;
                float v3 = acc[r][c][3] + bv[r].w;
                if (sizeof(OutT) == 2) {
                    ushort4v o = {f2bf(v0), f2bf(v1), f2bf(v2), f2bf(v3)};
                    *(ushort4v*)((unsigned short*)C + rbase + f0) = o;
                } else {
                    float4 o = {v0, v1, v2, v3};
                    *(float4*)((float*)C + rbase + f0) = o;
                }
            }
        }
    }
}

// ---------------- per-head projection GEMM: obuf8[h] = agg[h] @ Wv_h + bv_h ----------------
// A: bf16 [8][N][128] (pure bf16 rows), W rows [2816..3840) fmt [hi|hi|lo] (use hi),
// K=128 (KG=4). Grid: GSW*8 swizzled; by = head.
__global__ __launch_bounds__(256) void gemm_head_kernel(
    const unsigned short* __restrict__ A, const unsigned short* __restrict__ Wt,
    const float* __restrict__ bias, unsigned short* __restrict__ C, int nrows) {
    int id = blockIdx.x;
    int xcd = id & 7;
    int idx = id >> 3;
    int bx = (idx / 8) * 8 + xcd;
    int h = idx % 8;
    if (bx >= GXTILES) return;
    int lane = threadIdx.x & 63;
    int wave = threadIdx.x >> 6;
    int nodeBase = bx * 128 + (wave & 1) * 64;
    int featHalf = (wave >> 1) * 64;
    int m = lane & 15;
    int q = lane >> 4;
    const unsigned short* wptr = Wt + (size_t)(h * 128 + featHalf + m) * KC + q * 8;
    const unsigned short* aptr = A + (size_t)h * NNODES * 128 + (size_t)(nodeBase + m) * 128 + q * 8;
    floatx4 acc[4][4];
#pragma unroll
    for (int r = 0; r < 4; ++r)
#pragma unroll
        for (int c = 0; c < 4; ++c) acc[r][c] = (floatx4){0.f, 0.f, 0.f, 0.f};
#pragma unroll
    for (int kg = 0; kg < 4; ++kg) {
        short8 a[4], b[4];
#pragma unroll
        for (int r = 0; r < 4; ++r) a[r] = *(const short8*)(wptr + (size_t)r * 16 * KC + kg * 32);
#pragma unroll
        for (int c = 0; c < 4; ++c) b[c] = *(const short8*)(aptr + (size_t)c * 16 * 128 + kg * 32);
#pragma unroll
        for (int r = 0; r < 4; ++r)
#pragma unroll
            for (int c = 0; c < 4; ++c)
                acc[r][c] = __builtin_amdgcn_mfma_f32_16x16x32_bf16(a[r], b[c], acc[r][c], 0, 0, 0);
    }
    float4 bv[4];
#pragma unroll
    for (int r = 0; r < 4; ++r) bv[r] = *(const float4*)(bias + h * 128 + featHalf + r * 16 + q * 4);
#pragma unroll
    for (int c = 0; c < 4; ++c) {
        int node = nodeBase + c * 16 + m;
        if (node < nrows) {
            size_t rbase = (size_t)h * NNODES * 128 + (size_t)node * 128;
#pragma unroll
            for (int r = 0; r < 4; ++r) {
                int f0 = featHalf + r * 16 + q * 4;
                ushort4v o = {f2bf(acc[r][c][0] + bv[r].x), f2bf(acc[r][c][1] + bv[r].y),
                              f2bf(acc[r][c][2] + bv[r].z), f2bf(acc[r][c][3] + bv[r].w)};
                *(ushort4v*)(C + rbase + f0) = o;
            }
        }
    }
}

// ---------------- attention layers 0-2: qkv bf16 [N][384], s fp32 [N][128] ----------------
__global__ __launch_bounds__(64) void attn_small_kernel(
    const unsigned short* __restrict__ qkv, const float* __restrict__ sfp,
    const float* __restrict__ Wb,
    const int* __restrict__ offs, const int* __restrict__ csr_src,
    float* __restrict__ out) {
    int i = blockIdx.x;
    int l = threadIdx.x;
    int g = l >> 5;
    int d0 = (l & 31) * 4;
    uint2 qraw = *(const uint2*)(qkv + (size_t)i * 384 + d0);
    float q0 = bf2f((unsigned short)(qraw.x & 0xffff)), q1 = bf2f((unsigned short)(qraw.x >> 16));
    float q2 = bf2f((unsigned short)(qraw.y & 0xffff)), q3 = bf2f((unsigned short)(qraw.y >> 16));
    int e0 = offs[i], e1 = offs[i + 1];
    float mm = -1e30f, lac = 0.f;
    float a0 = 0.f, a1 = 0.f, a2 = 0.f, a3 = 0.f;
    for (int e = e0 + g; e < e1; e += 2) {
        int sn = csr_src[e];
        const unsigned short* row = qkv + (size_t)sn * 384;
        uint2 kk = *(const uint2*)(row + 128 + d0);
        uint2 vv = *(const uint2*)(row + 256 + d0);
        float k0 = bf2f((unsigned short)(kk.x & 0xffff)), k1 = bf2f((unsigned short)(kk.x >> 16));
        float k2 = bf2f((unsigned short)(kk.y & 0xffff)), k3 = bf2f((unsigned short)(kk.y >> 16));
        float p = q0 * k0 + q1 * k1 + q2 * k2 + q3 * k3;
        p += __shfl_xor(p, 1);
        p += __shfl_xor(p, 2);
        float logit = p * 0.25f;
        float mnew = fmaxf(mm, logit);
        float sc = __expf(mm - mnew);
        float w = __expf(logit - mnew);
        float v0 = bf2f((unsigned short)(vv.x & 0xffff)), v1 = bf2f((unsigned short)(vv.x >> 16));
        float v2 = bf2f((unsigned short)(vv.y & 0xffff)), v3 = bf2f((unsigned short)(vv.y >> 16));
        a0 = a0 * sc + w * v0;
        a1 = a1 * sc + w * v1;
        a2 = a2 * sc + w * v2;
        a3 = a3 * sc + w * v3;
        lac = lac * sc + w;
        mm = mnew;
    }
    float mo = __shfl_xor(mm, 32), lo = __shfl_xor(lac, 32);
    float b0 = __shfl_xor(a0, 32), b1 = __shfl_xor(a1, 32);
    float b2 = __shfl_xor(a2, 32), b3 = __shfl_xor(a3, 32);
    float ms = fmaxf(mm, mo);
    float s0 = __expf(mm - ms), s1 = __expf(mo - ms);
    a0 = a0 * s0 + b0 * s1;
    a1 = a1 * s0 + b1 * s1;
    a2 = a2 * s0 + b2 * s1;
    a3 = a3 * s0 + b3 * s1;
    lac = lac * s0 + lo * s1;
    float inv = 1.f / (lac + 1e-16f);
    float o0 = a0 * inv, o1 = a1 * inv, o2 = a2 * inv, o3 = a3 * inv;
    float4 rv = *(const float4*)(sfp + (size_t)i * HIDDIM + d0);
    float part = o0 * Wb[d0] + o1 * Wb[d0 + 1] + o2 * Wb[d0 + 2] + o3 * Wb[d0 + 3]
               + rv.x * Wb[128 + d0] + rv.y * Wb[128 + d0 + 1]
               + rv.z * Wb[128 + d0 + 2] + rv.w * Wb[128 + d0 + 3]
               + (o0 - rv.x) * Wb[256 + d0] + (o1 - rv.y) * Wb[256 + d0 + 1]
               + (o2 - rv.z) * Wb[256 + d0 + 2] + (o3 - rv.w) * Wb[256 + d0 + 3];
    if (g) part = 0.f;
#pragma unroll
    for (int msk = 1; msk <= 32; msk <<= 1) part += __shfl_xor(part, msk);
    float gg = 1.f / (1.f + __expf(-part));
    if (g == 0) {
        float4 o4 = {gg * rv.x + (1.f - gg) * o0, gg * rv.y + (1.f - gg) * o1,
                     gg * rv.z + (1.f - gg) * o2, gg * rv.w + (1.f - gg) * o3};
        *(float4*)(out + (size_t)i * HIDDIM + d0) = o4;
    }
}

// ---------------- attention layer 3: aggregate h (V folded out) ----------------
// t per head [8][N][128]; logit = t_i . h_j * rsqrt(128); accumulate
// agg = sum a_j h_j reusing the unpacked h_j from the dot. Writes bf16.
__global__ __launch_bounds__(64) void attn_big_kernel(
    const unsigned short* __restrict__ tbuf, const unsigned short* __restrict__ Acat,
    const int* __restrict__ offs, const int* __restrict__ csr_src,
    unsigned short* __restrict__ agg) {
    int i = blockIdx.x;
    int y = blockIdx.y;
    int l = threadIdx.x;
    int g = l >> 4;
    int s = l & 15;
    uint4 qq = *(const uint4*)(tbuf + (size_t)y * NNODES * 128 + (size_t)i * 128 + 8 * s);
    float q0 = bf2f((unsigned short)(qq.x & 0xffff)), q1 = bf2f((unsigned short)(qq.x >> 16));
    float q2 = bf2f((unsigned short)(qq.y & 0xffff)), q3f = bf2f((unsigned short)(qq.y >> 16));
    float q4 = bf2f((unsigned short)(qq.z & 0xffff)), q5 = bf2f((unsigned short)(qq.z >> 16));
    float q6 = bf2f((unsigned short)(qq.w & 0xffff)), q7 = bf2f((unsigned short)(qq.w >> 16));
    int e0 = offs[i], e1 = offs[i + 1];
    float mm = -1e30f, lac = 0.f;
    float ac[8];
#pragma unroll
    for (int j = 0; j < 8; ++j) ac[j] = 0.f;
    for (int e = e0 + g; e < e1; e += 4) {
        int sn = csr_src[e];
        uint4 kk = *(const uint4*)(Acat + (size_t)sn * KC + 8 * s);  // h_j hi
        float k0 = bf2f((unsigned short)(kk.x & 0xffff)), k1 = bf2f((unsigned short)(kk.x >> 16));
        float k2 = bf2f((unsigned short)(kk.y & 0xffff)), k3 = bf2f((unsigned short)(kk.y >> 16));
        float k4 = bf2f((unsigned short)(kk.z & 0xffff)), k5 = bf2f((unsigned short)(kk.z >> 16));
        float k6 = bf2f((unsigned short)(kk.w & 0xffff)), k7 = bf2f((unsigned short)(kk.w >> 16));
        float p = q0 * k0 + q1 * k1 + q2 * k2 + q3f * k3
                + q4 * k4 + q5 * k5 + q6 * k6 + q7 * k7;
        p += __shfl_xor(p, 1);
        p += __shfl_xor(p, 2);
        p += __shfl_xor(p, 4);
        p += __shfl_xor(p, 8);
        float logit = p * 0.08838834764831845f;
        float mnew = fmaxf(mm, logit);
        float sc = __expf(mm - mnew);
        float w = __expf(logit - mnew);
        ac[0] = ac[0] * sc + w * k0; ac[1] = ac[1] * sc + w * k1;
        ac[2] = ac[2] * sc + w * k2; ac[3] = ac[3] * sc + w * k3;
        ac[4] = ac[4] * sc + w * k4; ac[5] = ac[5] * sc + w * k5;
        ac[6] = ac[6] * sc + w * k6; ac[7] = ac[7] * sc + w * k7;
        lac = lac * sc + w;
        mm = mnew;
    }
#pragma unroll
    for (int msk = 16; msk <= 32; msk <<= 1) {
        float mo = __shfl_xor(mm, msk), lo = __shfl_xor(lac, msk);
        float bo[8];
#pragma unroll
        for (int j = 0; j < 8; ++j) bo[j] = __shfl_xor(ac[j], msk);
        float ms = fmaxf(mm, mo);
        float s0 = __expf(mm - ms), s1 = __expf(mo - ms);
#pragma unroll
        for (int j = 0; j < 8; ++j) ac[j] = ac[j] * s0 + bo[j] * s1;
        lac = lac * s0 + lo * s1;
        mm = ms;
    }
    if (g == 0) {
        float inv = 1.f / (lac + 1e-16f);
        ushort4v w0 = {f2bf(ac[0] * inv), f2bf(ac[1] * inv), f2bf(ac[2] * inv), f2bf(ac[3] * inv)};
        ushort4v w1 = {f2bf(ac[4] * inv), f2bf(ac[5] * inv), f2bf(ac[6] * inv), f2bf(ac[7] * inv)};
        unsigned short* o = agg + ((size_t)y * NNODES + i) * HIDDIM + 8 * s;
        *(ushort4v*)o = w0;
        *(ushort4v*)(o + 4) = w1;
    }
}

// ---------------- beta gate layer 3 (head mean over 8 bf16 slices) ----------------
__global__ __launch_bounds__(128) void beta3_kernel(const unsigned short* __restrict__ obuf8,
                                                    const float* __restrict__ s,
                                                    const float* __restrict__ Wb,
                                                    float* __restrict__ out) {
    int i = blockIdx.x, t = threadIdx.x;
    float o = 0.f;
#pragma unroll
    for (int y = 0; y < 8; ++y) o += bf2f(obuf8[((size_t)y * NNODES + i) * HIDDIM + t]);
    o *= 0.125f;
    float r = s[(size_t)i * HIDDIM + t];
    float part = o * Wb[t] + r * Wb[128 + t] + (o - r) * Wb[256 + t];
#pragma unroll
    for (int msk = 1; msk <= 32; msk <<= 1) part += __shfl_xor(part, msk);
    __shared__ float wsum[2];
    if ((t & 63) == 0) wsum[t >> 6] = part;
    __syncthreads();
    float tot = wsum[0] + wsum[1];
    float g = 1.f / (1.f + __expf(-tot));
    out[(size_t)i * HIDDIM + t] = g * r + (1.f - g) * o;
}

// ---------------- batchnorm ----------------
__global__ __launch_bounds__(128) void bn_stats_kernel(const float* __restrict__ x,
                                                       float* __restrict__ stat, int n) {
    int t = threadIdx.x;
    float s = 0.f, sq = 0.f;
    for (int i = blockIdx.x; i < n; i += gridDim.x) {
        float v = x[(size_t)i * HIDDIM + t];
        s += v;
        sq += v * v;
    }
    atomicAdd(&stat[t], s);
    atomicAdd(&stat[HIDDIM + t], sq);
}

__global__ __launch_bounds__(128) void bn_apply_kernel(float* __restrict__ x,
                                                       const float* __restrict__ stat,
                                                       const float* __restrict__ gamma,
                                                       const float* __restrict__ beta, int n,
                                                       unsigned short* __restrict__ cat) {
    int t = threadIdx.x;
    float mu = stat[t] / (float)n;
    float var = stat[HIDDIM + t] / (float)n - mu * mu;
    float rs = rsqrtf(var + 1e-5f);
    float g = gamma[t], b = beta[t];
    for (int i = blockIdx.x; i < n; i += gridDim.x) {
        float v = x[(size_t)i * HIDDIM + t];
        v = fmaxf((v - mu) * rs * g + b, 0.f);
        x[(size_t)i * HIDDIM + t] = v;
        if (cat) {
            unsigned short hi = f2bf(v);
            unsigned short lo = f2bf(v - bf2f(hi));
            unsigned short* row = cat + (size_t)i * KC;
            row[t] = hi;
            row[128 + t] = lo;
            row[256 + t] = hi;
        }
    }
}

// ---------------- pool ----------------
__global__ __launch_bounds__(256) void gb_kernel(const int* __restrict__ batch,
                                                 int* __restrict__ gs,
                                                 int* __restrict__ ge, int n) {
    int i = blockIdx.x * 256 + threadIdx.x;
    if (i >= n) return;
    int b = batch[i];
    if (i == 0 || batch[i - 1] != b) gs[b] = i;
    if (i == n - 1 || batch[i + 1] != b) ge[b] = i + 1;
}

__global__ __launch_bounds__(256) void pool_part_kernel(const float* __restrict__ x,
                                                        const int* __restrict__ gs,
                                                        const int* __restrict__ ge,
                                                        float* __restrict__ out) {
    int g = blockIdx.x, c = blockIdx.y;
    int t = threadIdx.x;
    int f = t & 127, half = t >> 7;
    int s = gs[g], e = ge[g];
    float acc = 0.f;
    for (int i = s + 2 * c + half; i < e; i += 16) acc += x[(size_t)i * HIDDIM + f];
    __shared__ float l0[128];
    if (half == 0) l0[f] = acc;
    __syncthreads();
    if (half == 1) atomicAdd(&out[g * HIDDIM + f], l0[f] + acc);
}

__global__ __launch_bounds__(128) void pool_div_kernel(float* __restrict__ out,
                                                       const int* __restrict__ gs,
                                                       const int* __restrict__ ge) {
    int g = blockIdx.x, t = threadIdx.x;
    int c = ge[g] - gs[g];
    out[g * HIDDIM + t] /= (float)(c > 0 ? c : 1);
}

// ---------------- host ----------------
extern "C" void kernel_launch(void* const* d_in, const int* in_sizes, int n_in,
                              void* d_out, int out_size, void* d_ws, size_t ws_size,
                              hipStream_t stream) {
    const float* x       = (const float*)d_in[0];
    const int*   ei      = (const int*)d_in[1];
    const int*   batch   = (const int*)d_in[2];
    const float* Wp      = (const float*)d_in[3];
    const float* bp      = (const float*)d_in[4];
    const float* Wq      = (const float*)d_in[5];
    const float* bq      = (const float*)d_in[6];
    const float* Wk      = (const float*)d_in[7];
    const float* bk      = (const float*)d_in[8];
    const float* Wv      = (const float*)d_in[9];
    const float* bv      = (const float*)d_in[10];
    const float* Ws      = (const float*)d_in[11];
    const float* bs      = (const float*)d_in[12];
    const float* Wbeta   = (const float*)d_in[13];
    const float* Wq3     = (const float*)d_in[14];
    const float* bq3     = (const float*)d_in[15];
    const float* Wk3     = (const float*)d_in[16];
    const float* bk3     = (const float*)d_in[17];
    const float* Wv3     = (const float*)d_in[18];
    const float* bv3     = (const float*)d_in[19];
    const float* Ws3     = (const float*)d_in[20];
    const float* bs3     = (const float*)d_in[21];
    const float* Wbeta3  = (const float*)d_in[22];
    const float* bn_gamma = (const float*)d_in[23];
    const float* bn_beta  = (const float*)d_in[24];
    float* out = (float*)d_out;
    (void)bk3;

    const int* esrc = ei;
    const int* edst = ei + NEDGES;

    char* wpc = (char*)d_ws;
    auto alloc = [&](size_t nbytes) -> char* {
        char* p = wpc;
        wpc += (nbytes + 255) & ~(size_t)255;
        return p;
    };
    unsigned short* Acat  = (unsigned short*)alloc((size_t)NPAD * KC * 2);      // 15.4 MB
    unsigned short* WtAll = (unsigned short*)alloc((size_t)3840 * KC * 2);      // 2.9 MB
    float* bcat   = (float*)alloc(3584 * 4);
    unsigned short* tbuf  = (unsigned short*)alloc((size_t)NHEADS * NNODES * 128 * 2);  // 41 MB (alias qkvb)
    unsigned short* aggb  = (unsigned short*)alloc((size_t)NHEADS * NNODES * 128 * 2);  // 41 MB
    unsigned short* obuf8 = (unsigned short*)alloc((size_t)NHEADS * NNODES * 128 * 2);  // 41 MB
    float* sfp    = (float*)alloc((size_t)NNODES * HIDDIM * 4);                 // 10.2 MB
    float* hbuf   = (float*)alloc((size_t)NNODES * HIDDIM * 4);
    float* obuf   = (float*)alloc((size_t)NNODES * HIDDIM * 4);
    float* sb     = (float*)alloc((size_t)NNODES * HIDDIM * 4);
    int*   deg    = (int*)alloc((2 * NNODES + 128 + 4 * 256) * 4);
    int*   cursor = deg + NNODES;
    int*   gs     = deg + 2 * NNODES;
    int*   ge     = gs + NGRAPH;
    float* bnstat4 = (float*)(deg + 2 * NNODES + 128);
    int*   chunk  = (int*)alloc(NNODES * 4);
    int*   bsum   = (int*)alloc(128 * 4);
    int*   offs   = (int*)alloc((NNODES + 1) * 4);
    int*   csrsrc = (int*)alloc(NEDGES * 4);

    unsigned short* WtQKV = WtAll;                       // [3][384][KC]
    unsigned short* WtS   = WtAll + (size_t)1152 * KC;   // [3][128][KC]
    unsigned short* Wpt   = WtAll + (size_t)1536 * KC;
    unsigned short* Ws3t  = WtAll + (size_t)1664 * KC;
    unsigned short* Wt3t  = WtAll + (size_t)1792 * KC;   // [8][128][KC] t
    unsigned short* Wt3v  = WtAll + (size_t)2816 * KC;   // [8][128][KC] v-proj
    float* bQKV = bcat;          // [3][384]
    float* bS   = bcat + 1152;   // [3][128]
    float* b3t  = bcat + 1536;   // [1024]
    float* b3v  = bcat + 2560;   // [1024]
    unsigned short* qkvb = tbuf; // layers 0-2 alias: [N][384]

    const int TB = 256;
    const int ZWORDS = 2 * NNODES + 128 + 4 * 256;
    zero_kernel<<<(ZWORDS + TB - 1) / TB, TB, 0, stream>>>((float*)deg, ZWORDS);
    count_deg_kernel<<<(NEDGES + TB - 1) / TB, TB, 0, stream>>>(edst, deg, NEDGES);
    const int NB = (NNODES + 255) / 256;
    scan1_kernel<<<NB, 256, 0, stream>>>(deg, chunk, bsum, NNODES);
    scan2_kernel<<<1, 128, 0, stream>>>(bsum, NB);
    scan3_kernel<<<NB, 256, 0, stream>>>(chunk, bsum, offs, NNODES);
    scatter_kernel<<<(NEDGES + TB - 1) / TB, TB, 0, stream>>>(esrc, edst, offs, cursor, csrsrc, NEDGES);
    gb_kernel<<<(NNODES + TB - 1) / TB, TB, 0, stream>>>(batch, gs, ge, NNODES);

    prep_w_kernel<<<3840, 128, 0, stream>>>(Wq, Wk, Wv, Ws, Wp, Ws3, Wv3, WtAll);
    prep_bias_kernel<<<(3584 + TB - 1) / TB, TB, 0, stream>>>(bq, bk, bv, bs, bv3, bcat);
    mqk_kernel<<<1024, 128, 0, stream>>>(Wq3, Wk3, bq3, WtAll, bcat);

    const int CATB = (NPAD * HIDDIM + TB - 1) / TB;
    const int GSW = 8 * ((GXTILES + 7) / 8);  // 160 swizzled x-slots

    cat_from_kernel<<<CATB, TB, 0, stream>>>(x, Acat);
    gemm_mfma_kernel<float, 12, 1, 0><<<GSW * 1, 256, 0, stream>>>(Acat, Wpt, bp, hbuf, 128, NNODES);
    cat_from_kernel<<<CATB, TB, 0, stream>>>(hbuf, Acat);

    for (int li = 0; li < 3; ++li) {
        gemm_mfma_kernel<unsigned short, 8, 3, 0><<<GSW * 3, 256, 0, stream>>>(
            Acat, WtQKV + (size_t)li * 384 * KC, bQKV + li * 384, qkvb, 384, NNODES);
        gemm_mfma_kernel<float, 12, 1, 0><<<GSW * 1, 256, 0, stream>>>(
            Acat, WtS + (size_t)li * 128 * KC, bS + li * 128, sfp, 128, NNODES);
        attn_small_kernel<<<NNODES, 64, 0, stream>>>(qkvb, sfp, Wbeta + li * 384,
                                                     offs, csrsrc, obuf);
        float* st = bnstat4 + li * 256;
        bn_stats_kernel<<<640, 128, 0, stream>>>(obuf, st, NNODES);
        bn_apply_kernel<<<512, 128, 0, stream>>>(obuf, st, bn_gamma + li * HIDDIM,
                                                 bn_beta + li * HIDDIM, NNODES, Acat);
    }

    // ---- layer 3: t GEMM -> aggregate h -> per-head V projection -> beta ----
    gemm_mfma_kernel<unsigned short, 8, 8, 1><<<GSW * 8, 256, 0, stream>>>(
        Acat, Wt3t, b3t, tbuf, 1024, NNODES);
    attn_big_kernel<<<dim3(NNODES, 8), 64, 0, stream>>>(tbuf, Acat, offs, csrsrc, aggb);
    gemm_head_kernel<<<GSW * 8, 256, 0, stream>>>(aggb, Wt3v, b3v, obuf8, NNODES);
    gemm_mfma_kernel<float, 12, 1, 0><<<GSW * 1, 256, 0, stream>>>(Acat, Ws3t, bs3, sb, 128, NNODES);
    beta3_kernel<<<NNODES, 128, 0, stream>>>(obuf8, sb, Wbeta3, hbuf);
    float* st3 = bnstat4 + 3 * 256;
    bn_stats_kernel<<<640, 128, 0, stream>>>(hbuf, st3, NNODES);
    bn_apply_kernel<<<512, 128, 0, stream>>>(hbuf, st3, bn_gamma + 3 * HIDDIM,
                                             bn_beta + 3 * HIDDIM, NNODES, (unsigned short*)0);

    zero_kernel<<<(NGRAPH * HIDDIM + TB - 1) / TB, TB, 0, stream>>>(out, NGRAPH * HIDDIM);
    pool_part_kernel<<<dim3(NGRAPH, 8), 256, 0, stream>>>(hbuf, gs, ge, out);
    pool_div_kernel<<<NGRAPH, 128, 0, stream>>>(out, gs, ge);
}

// Round 19
// 663.578 us; speedup vs baseline: 1.1358x; 1.0141x over previous
//
#include <hip/hip_runtime.h>
#include <math.h>

#define NNODES 20000
#define NPAD   20096   // 157 * 128
#define NEDGES 160000
#define HIDDIM 128
#define NHEADS 8
#define NGRAPH 64
#define KC 384   // concatenated K (hi | lo | hi)
#define GXTILES 157

typedef short short8 __attribute__((ext_vector_type(8)));
typedef float floatx4 __attribute__((ext_vector_type(4)));
typedef unsigned short ushort4v __attribute__((ext_vector_type(4)));

__device__ inline unsigned short f2bf(float x) {
    unsigned u = __float_as_uint(x);
    u += 0x7fff + ((u >> 16) & 1);
    return (unsigned short)(u >> 16);
}
__device__ inline float bf2f(unsigned short h) {
    return __uint_as_float(((unsigned)h) << 16);
}

// ---------------- utility ----------------
__global__ __launch_bounds__(256) void zero_kernel(float* __restrict__ p, int n) {
    int i = blockIdx.x * blockDim.x + threadIdx.x;
    if (i < n) p[i] = 0.f;
}

// ---------------- CSR build ----------------
__global__ __launch_bounds__(256) void count_deg_kernel(const int* __restrict__ dst,
                                                        int* __restrict__ deg, int e) {
    int i = blockIdx.x * blockDim.x + threadIdx.x;
    if (i < e) atomicAdd(&deg[dst[i]], 1);
}

__global__ __launch_bounds__(256) void scan1_kernel(const int* __restrict__ deg,
                                                    int* __restrict__ chunk,
                                                    int* __restrict__ bsum, int n) {
    __shared__ int buf[256];
    int t = threadIdx.x;
    int i = blockIdx.x * 256 + t;
    int v = (i < n) ? deg[i] : 0;
    buf[t] = v;
    __syncthreads();
    for (int off = 1; off < 256; off <<= 1) {
        int tmp = (t >= off) ? buf[t - off] : 0;
        __syncthreads();
        buf[t] += tmp;
        __syncthreads();
    }
    if (i < n) chunk[i] = buf[t];
    if (t == 255) bsum[blockIdx.x] = buf[255];
}

__global__ __launch_bounds__(128) void scan2_kernel(int* __restrict__ bsum, int nb) {
    __shared__ int buf[128];
    int t = threadIdx.x;
    int v = (t < nb) ? bsum[t] : 0;
    buf[t] = v;
    __syncthreads();
    for (int off = 1; off < 128; off <<= 1) {
        int tmp = (t >= off) ? buf[t - off] : 0;
        __syncthreads();
        buf[t] += tmp;
        __syncthreads();
    }
    if (t < nb) bsum[t] = buf[t] - v;
}

__global__ __launch_bounds__(256) void scan3_kernel(const int* __restrict__ chunk,
                                                    const int* __restrict__ bsum,
                                                    int* __restrict__ offs, int n) {
    int i = blockIdx.x * 256 + threadIdx.x;
    if (i < n) offs[i + 1] = chunk[i] + bsum[i >> 8];
    if (i == 0) offs[0] = 0;
}

__global__ __launch_bounds__(256) void scatter_kernel(const int* __restrict__ src,
                                                      const int* __restrict__ dst,
                                                      const int* __restrict__ offs,
                                                      int* __restrict__ cursor,
                                                      int* __restrict__ csr_src, int e) {
    int i = blockIdx.x * blockDim.x + threadIdx.x;
    if (i < e) {
        int d = dst[i];
        int pos = offs[d] + atomicAdd(&cursor[d], 1);
        csr_src[pos] = src[i];
    }
}

// ---------------- weight prep ----------------
// Rows: [0,1152) layers qkv ; [1152,1536) layers s ; [1536,1664) Wp ;
// [1664,1792) Ws3 ; [1792,2816) layer3 t rows (mqk fills) ;
// [2816,3840) layer3 v-proj rows (h*128+j) from Wv3.
__global__ __launch_bounds__(128) void prep_w_kernel(
    const float* __restrict__ Wq, const float* __restrict__ Wk,
    const float* __restrict__ Wv, const float* __restrict__ Ws,
    const float* __restrict__ Wp, const float* __restrict__ Ws3,
    const float* __restrict__ Wv3, unsigned short* __restrict__ WtAll) {
    int id = blockIdx.x;
    int k = threadIdx.x;
    float w;
    if (id < 1152) {
        int li = id / 384, n = id % 384, sel = n >> 7, np = n & 127;
        const float* W = (sel == 0) ? Wq : (sel == 1) ? Wk : Wv;
        w = W[li * 16384 + k * 128 + np];
    } else if (id < 1536) {
        int r = id - 1152, li = r >> 7, np = r & 127;
        w = Ws[li * 16384 + k * 128 + np];
    } else if (id < 1664) {
        w = Wp[k * 128 + (id - 1536)];
    } else if (id < 1792) {
        w = Ws3[k * 128 + (id - 1664)];
    } else if (id < 2816) {
        return;  // t rows: filled by mqk_kernel
    } else {
        int r = id - 2816, h = r >> 7, j = r & 127;
        w = Wv3[k * 1024 + h * 128 + j];
    }
    unsigned short hi = f2bf(w);
    unsigned short lo = f2bf(w - bf2f(hi));
    unsigned short* dst = WtAll + (size_t)id * KC;
    dst[k] = hi;
    dst[128 + k] = hi;
    dst[256 + k] = lo;
}

// bias: [0,1152) qkv ; [1152,1536) s ; [1536,2560) t bias (mqk fills) ;
// [2560,3584) v-proj bias = bv3
__global__ __launch_bounds__(256) void prep_bias_kernel(
    const float* __restrict__ bq, const float* __restrict__ bk,
    const float* __restrict__ bv, const float* __restrict__ bs,
    const float* __restrict__ bv3, float* __restrict__ bcat) {
    int id = blockIdx.x * 256 + threadIdx.x;
    if (id >= 3584) return;
    float v;
    if (id < 1152) {
        int li = id / 384, n = id % 384, sel = n >> 7, np = n & 127;
        const float* b = (sel == 0) ? bq : (sel == 1) ? bk : bv;
        v = b[li * 128 + np];
    } else if (id < 1536) {
        int r = id - 1152, li = r >> 7, np = r & 127;
        v = bs[li * 128 + np];
    } else if (id < 2560) {
        return;  // t bias: mqk fills
    } else {
        v = bv3[id - 2560];
    }
    bcat[id] = v;
}

// ---------------- layer-3 fused QK weights: M_h = Wq_h Wk_h^T ----------------
__global__ __launch_bounds__(128) void mqk_kernel(
    const float* __restrict__ Wq3, const float* __restrict__ Wk3,
    const float* __restrict__ bq3,
    unsigned short* __restrict__ WtAll, float* __restrict__ bcat) {
    int hb = blockIdx.x;
    int h = hb >> 7, b = hb & 127;
    int a = threadIdx.x;
    __shared__ float wk[128];
    wk[a] = Wk3[(size_t)b * 1024 + h * 128 + a];
    __syncthreads();
    const float* wq = Wq3 + (size_t)a * 1024 + h * 128;
    float acc = 0.f;
#pragma unroll 16
    for (int d = 0; d < 128; ++d) acc = fmaf(wq[d], wk[d], acc);
    unsigned short hi = f2bf(acc);
    unsigned short lo = f2bf(acc - bf2f(hi));
    unsigned short* dst = WtAll + (size_t)(1792 + h * 128 + b) * KC;
    dst[a] = hi;
    dst[128 + a] = hi;
    dst[256 + a] = lo;
    if (a == 0) {
        float bb = 0.f;
        for (int d = 0; d < 128; ++d) bb = fmaf(bq3[h * 128 + d], wk[d], bb);
        bcat[1536 + h * 128 + b] = bb;
    }
}

// ---------------- activation -> split-bf16 A_cat ----------------
__global__ __launch_bounds__(256) void cat_from_kernel(const float* __restrict__ h,
                                                       unsigned short* __restrict__ Acat) {
    int idx = blockIdx.x * 256 + threadIdx.x;
    if (idx >= NPAD * HIDDIM) return;
    int r = idx >> 7, k = idx & 127;
    float x = (r < NNODES) ? h[idx] : 0.f;
    unsigned short hi = f2bf(x);
    unsigned short lo = f2bf(x - bf2f(hi));
    unsigned short* row = Acat + (size_t)r * KC;
    row[k] = hi;
    row[128 + k] = lo;
    row[256 + k] = hi;
}

// ---------------- MFMA GEMM (XCD swizzle; optional per-head output layout) ----------------
template <typename OutT, int KG, int BY, int HT>
__global__ __launch_bounds__(256) void gemm_mfma_kernel(
    const unsigned short* __restrict__ Acat, const unsigned short* __restrict__ Wt,
    const float* __restrict__ bias, OutT* __restrict__ C, int M, int nrows) {
    int id = blockIdx.x;
    int xcd = id & 7;
    int idx = id >> 3;
    int bx = (idx / BY) * 8 + xcd;
    int by = idx % BY;
    if (bx >= GXTILES) return;
    int lane = threadIdx.x & 63;
    int wave = threadIdx.x >> 6;
    int nodeBase = bx * 128 + (wave & 1) * 64;
    int featBase = by * 128 + (wave >> 1) * 64;
    int m = lane & 15;
    int q = lane >> 4;
    int ko = q * 8;
    const unsigned short* wptr = Wt + (size_t)(featBase + m) * KC + ko;
    const unsigned short* aptr = Acat + (size_t)(nodeBase + m) * KC + ko;
    floatx4 acc[4][4];
#pragma unroll
    for (int r = 0; r < 4; ++r)
#pragma unroll
        for (int c = 0; c < 4; ++c) acc[r][c] = (floatx4){0.f, 0.f, 0.f, 0.f};
#pragma unroll
    for (int kg = 0; kg < KG; ++kg) {
        short8 a[4], b[4];
#pragma unroll
        for (int r = 0; r < 4; ++r) a[r] = *(const short8*)(wptr + (size_t)r * 16 * KC + kg * 32);
#pragma unroll
        for (int c = 0; c < 4; ++c) b[c] = *(const short8*)(aptr + (size_t)c * 16 * KC + kg * 32);
#pragma unroll
        for (int r = 0; r < 4; ++r)
#pragma unroll
            for (int c = 0; c < 4; ++c)
                acc[r][c] = __builtin_amdgcn_mfma_f32_16x16x32_bf16(a[r], b[c], acc[r][c], 0, 0, 0);
    }
    size_t rowLen = (HT > 0) ? (size_t)(HT * 128) : (size_t)M;
    size_t headOff = 0;
    int colBase;
    if (HT > 0) {
        int h = by / HT, lt = by % HT;
        headOff = (size_t)h * NNODES * rowLen;
        colBase = lt * 128 + (wave >> 1) * 64;
    } else {
        colBase = featBase;
    }
    float4 bv[4];
#pragma unroll
    for (int r = 0; r < 4; ++r) bv[r] = *(const float4*)(bias + featBase + r * 16 + q * 4);
#pragma unroll
    for (int c = 0; c < 4; ++c) {
        int node = nodeBase + c * 16 + m;
        if (node < nrows) {
            size_t rbase = headOff + (size_t)node * rowLen;
#pragma unroll
            for (int r = 0; r < 4; ++r) {
                int f0 = colBase + r * 16 + q * 4;
                float v0 = acc[r][c][0] + bv[r].x;
                float v1 = acc[r][c][1] + bv[r].y;
                float v2 = acc[r][c][2] + bv[r].z;
                float v3 = acc[r][c][3] + bv[r].w;
                if (sizeof(OutT) == 2) {
                    ushort4v o = {f2bf(v0), f2bf(v1), f2bf(v2), f2bf(v3)};
                    *(ushort4v*)((unsigned short*)C + rbase + f0) = o;
                } else {
                    float4 o = {v0, v1, v2, v3};
                    *(float4*)((float*)C + rbase + f0) = o;
                }
            }
        }
    }
}

// ---------------- per-head projection GEMM: obuf8[h] = agg[h] @ Wv_h + bv_h ----------------
__global__ __launch_bounds__(256) void gemm_head_kernel(
    const unsigned short* __restrict__ A, const unsigned short* __restrict__ Wt,
    const float* __restrict__ bias, unsigned short* __restrict__ C, int nrows) {
    int id = blockIdx.x;
    int xcd = id & 7;
    int idx = id >> 3;
    int bx = (idx / 8) * 8 + xcd;
    int h = idx % 8;
    if (bx >= GXTILES) return;
    int lane = threadIdx.x & 63;
    int wave = threadIdx.x >> 6;
    int nodeBase = bx * 128 + (wave & 1) * 64;
    int featHalf = (wave >> 1) * 64;
    int m = lane & 15;
    int q = lane >> 4;
    const unsigned short* wptr = Wt + (size_t)(h * 128 + featHalf + m) * KC + q * 8;
    const unsigned short* aptr = A + (size_t)h * NNODES * 128 + (size_t)(nodeBase + m) * 128 + q * 8;
    floatx4 acc[4][4];
#pragma unroll
    for (int r = 0; r < 4; ++r)
#pragma unroll
        for (int c = 0; c < 4; ++c) acc[r][c] = (floatx4){0.f, 0.f, 0.f, 0.f};
#pragma unroll
    for (int kg = 0; kg < 4; ++kg) {
        short8 a[4], b[4];
#pragma unroll
        for (int r = 0; r < 4; ++r) a[r] = *(const short8*)(wptr + (size_t)r * 16 * KC + kg * 32);
#pragma unroll
        for (int c = 0; c < 4; ++c) b[c] = *(const short8*)(aptr + (size_t)c * 16 * 128 + kg * 32);
#pragma unroll
        for (int r = 0; r < 4; ++r)
#pragma unroll
            for (int c = 0; c < 4; ++c)
                acc[r][c] = __builtin_amdgcn_mfma_f32_16x16x32_bf16(a[r], b[c], acc[r][c], 0, 0, 0);
    }
    float4 bv[4];
#pragma unroll
    for (int r = 0; r < 4; ++r) bv[r] = *(const float4*)(bias + h * 128 + featHalf + r * 16 + q * 4);
#pragma unroll
    for (int c = 0; c < 4; ++c) {
        int node = nodeBase + c * 16 + m;
        if (node < nrows) {
            size_t rbase = (size_t)h * NNODES * 128 + (size_t)node * 128;
#pragma unroll
            for (int r = 0; r < 4; ++r) {
                int f0 = featHalf + r * 16 + q * 4;
                ushort4v o = {f2bf(acc[r][c][0] + bv[r].x), f2bf(acc[r][c][1] + bv[r].y),
                              f2bf(acc[r][c][2] + bv[r].z), f2bf(acc[r][c][3] + bv[r].w)};
                *(ushort4v*)(C + rbase + f0) = o;
            }
        }
    }
}

// ---------------- attention layers 0-2 (plain-exp softmax; logits are small) ----------------
__global__ __launch_bounds__(64) void attn_small_kernel(
    const unsigned short* __restrict__ qkv, const float* __restrict__ sfp,
    const float* __restrict__ Wb,
    const int* __restrict__ offs, const int* __restrict__ csr_src,
    float* __restrict__ out) {
    int i = blockIdx.x;
    int l = threadIdx.x;
    int g = l >> 5;
    int d0 = (l & 31) * 4;
    uint2 qraw = *(const uint2*)(qkv + (size_t)i * 384 + d0);
    float q0 = bf2f((unsigned short)(qraw.x & 0xffff)), q1 = bf2f((unsigned short)(qraw.x >> 16));
    float q2 = bf2f((unsigned short)(qraw.y & 0xffff)), q3 = bf2f((unsigned short)(qraw.y >> 16));
    int e0 = offs[i], e1 = offs[i + 1];
    float lac = 0.f;
    float a0 = 0.f, a1 = 0.f, a2 = 0.f, a3 = 0.f;
    for (int e = e0 + g; e < e1; e += 2) {
        int sn = csr_src[e];
        const unsigned short* row = qkv + (size_t)sn * 384;
        uint2 kk = *(const uint2*)(row + 128 + d0);
        uint2 vv = *(const uint2*)(row + 256 + d0);
        float k0 = bf2f((unsigned short)(kk.x & 0xffff)), k1 = bf2f((unsigned short)(kk.x >> 16));
        float k2 = bf2f((unsigned short)(kk.y & 0xffff)), k3 = bf2f((unsigned short)(kk.y >> 16));
        float p = q0 * k0 + q1 * k1 + q2 * k2 + q3 * k3;
        p += __shfl_xor(p, 1);
        p += __shfl_xor(p, 2);
        float w = __expf(p * 0.25f);
        float v0 = bf2f((unsigned short)(vv.x & 0xffff)), v1 = bf2f((unsigned short)(vv.x >> 16));
        float v2 = bf2f((unsigned short)(vv.y & 0xffff)), v3 = bf2f((unsigned short)(vv.y >> 16));
        a0 += w * v0;
        a1 += w * v1;
        a2 += w * v2;
        a3 += w * v3;
        lac += w;
    }
    a0 += __shfl_xor(a0, 32);
    a1 += __shfl_xor(a1, 32);
    a2 += __shfl_xor(a2, 32);
    a3 += __shfl_xor(a3, 32);
    lac += __shfl_xor(lac, 32);
    float inv = 1.f / (lac + 1e-16f);
    float o0 = a0 * inv, o1 = a1 * inv, o2 = a2 * inv, o3 = a3 * inv;
    float4 rv = *(const float4*)(sfp + (size_t)i * HIDDIM + d0);
    float part = o0 * Wb[d0] + o1 * Wb[d0 + 1] + o2 * Wb[d0 + 2] + o3 * Wb[d0 + 3]
               + rv.x * Wb[128 + d0] + rv.y * Wb[128 + d0 + 1]
               + rv.z * Wb[128 + d0 + 2] + rv.w * Wb[128 + d0 + 3]
               + (o0 - rv.x) * Wb[256 + d0] + (o1 - rv.y) * Wb[256 + d0 + 1]
               + (o2 - rv.z) * Wb[256 + d0 + 2] + (o3 - rv.w) * Wb[256 + d0 + 3];
    if (g) part = 0.f;
#pragma unroll
    for (int msk = 1; msk <= 32; msk <<= 1) part += __shfl_xor(part, msk);
    float gg = 1.f / (1.f + __expf(-part));
    if (g == 0) {
        float4 o4 = {gg * rv.x + (1.f - gg) * o0, gg * rv.y + (1.f - gg) * o1,
                     gg * rv.z + (1.f - gg) * o2, gg * rv.w + (1.f - gg) * o3};
        *(float4*)(out + (size_t)i * HIDDIM + d0) = o4;
    }
}

// ---------------- attention layer 3 (plain-exp, V folded out) ----------------
__global__ __launch_bounds__(64) void attn_big_kernel(
    const unsigned short* __restrict__ tbuf, const unsigned short* __restrict__ Acat,
    const int* __restrict__ offs, const int* __restrict__ csr_src,
    unsigned short* __restrict__ agg) {
    int i = blockIdx.x;
    int y = blockIdx.y;
    int l = threadIdx.x;
    int g = l >> 4;
    int s = l & 15;
    uint4 qq = *(const uint4*)(tbuf + (size_t)y * NNODES * 128 + (size_t)i * 128 + 8 * s);
    float q0 = bf2f((unsigned short)(qq.x & 0xffff)), q1 = bf2f((unsigned short)(qq.x >> 16));
    float q2 = bf2f((unsigned short)(qq.y & 0xffff)), q3f = bf2f((unsigned short)(qq.y >> 16));
    float q4 = bf2f((unsigned short)(qq.z & 0xffff)), q5 = bf2f((unsigned short)(qq.z >> 16));
    float q6 = bf2f((unsigned short)(qq.w & 0xffff)), q7 = bf2f((unsigned short)(qq.w >> 16));
    int e0 = offs[i], e1 = offs[i + 1];
    float lac = 0.f;
    float ac[8];
#pragma unroll
    for (int j = 0; j < 8; ++j) ac[j] = 0.f;
    for (int e = e0 + g; e < e1; e += 4) {
        int sn = csr_src[e];
        uint4 kk = *(const uint4*)(Acat + (size_t)sn * KC + 8 * s);  // h_j hi
        float k0 = bf2f((unsigned short)(kk.x & 0xffff)), k1 = bf2f((unsigned short)(kk.x >> 16));
        float k2 = bf2f((unsigned short)(kk.y & 0xffff)), k3 = bf2f((unsigned short)(kk.y >> 16));
        float k4 = bf2f((unsigned short)(kk.z & 0xffff)), k5 = bf2f((unsigned short)(kk.z >> 16));
        float k6 = bf2f((unsigned short)(kk.w & 0xffff)), k7 = bf2f((unsigned short)(kk.w >> 16));
        float p = q0 * k0 + q1 * k1 + q2 * k2 + q3f * k3
                + q4 * k4 + q5 * k5 + q6 * k6 + q7 * k7;
        p += __shfl_xor(p, 1);
        p += __shfl_xor(p, 2);
        p += __shfl_xor(p, 4);
        p += __shfl_xor(p, 8);
        float w = __expf(p * 0.08838834764831845f);
        ac[0] += w * k0; ac[1] += w * k1;
        ac[2] += w * k2; ac[3] += w * k3;
        ac[4] += w * k4; ac[5] += w * k5;
        ac[6] += w * k6; ac[7] += w * k7;
        lac += w;
    }
#pragma unroll
    for (int msk = 16; msk <= 32; msk <<= 1) {
#pragma unroll
        for (int j = 0; j < 8; ++j) ac[j] += __shfl_xor(ac[j], msk);
        lac += __shfl_xor(lac, msk);
    }
    if (g == 0) {
        float inv = 1.f / (lac + 1e-16f);
        ushort4v w0 = {f2bf(ac[0] * inv), f2bf(ac[1] * inv), f2bf(ac[2] * inv), f2bf(ac[3] * inv)};
        ushort4v w1 = {f2bf(ac[4] * inv), f2bf(ac[5] * inv), f2bf(ac[6] * inv), f2bf(ac[7] * inv)};
        unsigned short* o = agg + ((size_t)y * NNODES + i) * HIDDIM + 8 * s;
        *(ushort4v*)o = w0;
        *(ushort4v*)(o + 4) = w1;
    }
}

// ---------------- beta gate layer 3 (head mean over 8 bf16 slices) ----------------
__global__ __launch_bounds__(128) void beta3_kernel(const unsigned short* __restrict__ obuf8,
                                                    const float* __restrict__ s,
                                                    const float* __restrict__ Wb,
                                                    float* __restrict__ out) {
    int i = blockIdx.x, t = threadIdx.x;
    float o = 0.f;
#pragma unroll
    for (int y = 0; y < 8; ++y) o += bf2f(obuf8[((size_t)y * NNODES + i) * HIDDIM + t]);
    o *= 0.125f;
    float r = s[(size_t)i * HIDDIM + t];
    float part = o * Wb[t] + r * Wb[128 + t] + (o - r) * Wb[256 + t];
#pragma unroll
    for (int msk = 1; msk <= 32; msk <<= 1) part += __shfl_xor(part, msk);
    __shared__ float wsum[2];
    if ((t & 63) == 0) wsum[t >> 6] = part;
    __syncthreads();
    float tot = wsum[0] + wsum[1];
    float g = 1.f / (1.f + __expf(-tot));
    out[(size_t)i * HIDDIM + t] = g * r + (1.f - g) * o;
}

// ---------------- batchnorm ----------------
__global__ __launch_bounds__(128) void bn_stats_kernel(const float* __restrict__ x,
                                                       float* __restrict__ stat, int n) {
    int t = threadIdx.x;
    float s = 0.f, sq = 0.f;
    for (int i = blockIdx.x; i < n; i += gridDim.x) {
        float v = x[(size_t)i * HIDDIM + t];
        s += v;
        sq += v * v;
    }
    atomicAdd(&stat[t], s);
    atomicAdd(&stat[HIDDIM + t], sq);
}

__global__ __launch_bounds__(128) void bn_apply_kernel(float* __restrict__ x,
                                                       const float* __restrict__ stat,
                                                       const float* __restrict__ gamma,
                                                       const float* __restrict__ beta, int n,
                                                       unsigned short* __restrict__ cat) {
    int t = threadIdx.x;
    float mu = stat[t] / (float)n;
    float var = stat[HIDDIM + t] / (float)n - mu * mu;
    float rs = rsqrtf(var + 1e-5f);
    float g = gamma[t], b = beta[t];
    for (int i = blockIdx.x; i < n; i += gridDim.x) {
        float v = x[(size_t)i * HIDDIM + t];
        v = fmaxf((v - mu) * rs * g + b, 0.f);
        x[(size_t)i * HIDDIM + t] = v;
        if (cat) {
            unsigned short hi = f2bf(v);
            unsigned short lo = f2bf(v - bf2f(hi));
            unsigned short* row = cat + (size_t)i * KC;
            row[t] = hi;
            row[128 + t] = lo;
            row[256 + t] = hi;
        }
    }
}

// ---------------- pool ----------------
__global__ __launch_bounds__(256) void gb_kernel(const int* __restrict__ batch,
                                                 int* __restrict__ gs,
                                                 int* __restrict__ ge, int n) {
    int i = blockIdx.x * 256 + threadIdx.x;
    if (i >= n) return;
    int b = batch[i];
    if (i == 0 || batch[i - 1] != b) gs[b] = i;
    if (i == n - 1 || batch[i + 1] != b) ge[b] = i + 1;
}

__global__ __launch_bounds__(256) void pool_part_kernel(const float* __restrict__ x,
                                                        const int* __restrict__ gs,
                                                        const int* __restrict__ ge,
                                                        float* __restrict__ out) {
    int g = blockIdx.x, c = blockIdx.y;
    int t = threadIdx.x;
    int f = t & 127, half = t >> 7;
    int s = gs[g], e = ge[g];
    float acc = 0.f;
    for (int i = s + 2 * c + half; i < e; i += 16) acc += x[(size_t)i * HIDDIM + f];
    __shared__ float l0[128];
    if (half == 0) l0[f] = acc;
    __syncthreads();
    if (half == 1) atomicAdd(&out[g * HIDDIM + f], l0[f] + acc);
}

__global__ __launch_bounds__(128) void pool_div_kernel(float* __restrict__ out,
                                                       const int* __restrict__ gs,
                                                       const int* __restrict__ ge) {
    int g = blockIdx.x, t = threadIdx.x;
    int c = ge[g] - gs[g];
    out[g * HIDDIM + t] /= (float)(c > 0 ? c : 1);
}

// ---------------- host ----------------
extern "C" void kernel_launch(void* const* d_in, const int* in_sizes, int n_in,
                              void* d_out, int out_size, void* d_ws, size_t ws_size,
                              hipStream_t stream) {
    const float* x       = (const float*)d_in[0];
    const int*   ei      = (const int*)d_in[1];
    const int*   batch   = (const int*)d_in[2];
    const float* Wp      = (const float*)d_in[3];
    const float* bp      = (const float*)d_in[4];
    const float* Wq      = (const float*)d_in[5];
    const float* bq      = (const float*)d_in[6];
    const float* Wk      = (const float*)d_in[7];
    const float* bk      = (const float*)d_in[8];
    const float* Wv      = (const float*)d_in[9];
    const float* bv      = (const float*)d_in[10];
    const float* Ws      = (const float*)d_in[11];
    const float* bs      = (const float*)d_in[12];
    const float* Wbeta   = (const float*)d_in[13];
    const float* Wq3     = (const float*)d_in[14];
    const float* bq3     = (const float*)d_in[15];
    const float* Wk3     = (const float*)d_in[16];
    const float* bk3     = (const float*)d_in[17];
    const float* Wv3     = (const float*)d_in[18];
    const float* bv3     = (const float*)d_in[19];
    const float* Ws3     = (const float*)d_in[20];
    const float* bs3     = (const float*)d_in[21];
    const float* Wbeta3  = (const float*)d_in[22];
    const float* bn_gamma = (const float*)d_in[23];
    const float* bn_beta  = (const float*)d_in[24];
    float* out = (float*)d_out;
    (void)bk3;

    const int* esrc = ei;
    const int* edst = ei + NEDGES;

    char* wpc = (char*)d_ws;
    auto alloc = [&](size_t nbytes) -> char* {
        char* p = wpc;
        wpc += (nbytes + 255) & ~(size_t)255;
        return p;
    };
    unsigned short* Acat  = (unsigned short*)alloc((size_t)NPAD * KC * 2);      // 15.4 MB
    unsigned short* WtAll = (unsigned short*)alloc((size_t)3840 * KC * 2);      // 2.9 MB
    float* bcat   = (float*)alloc(3584 * 4);
    unsigned short* tbuf  = (unsigned short*)alloc((size_t)NHEADS * NNODES * 128 * 2);  // 41 MB (alias qkvb)
    unsigned short* aggb  = (unsigned short*)alloc((size_t)NHEADS * NNODES * 128 * 2);  // 41 MB
    unsigned short* obuf8 = (unsigned short*)alloc((size_t)NHEADS * NNODES * 128 * 2);  // 41 MB
    float* sfp    = (float*)alloc((size_t)NNODES * HIDDIM * 4);                 // 10.2 MB
    float* hbuf   = (float*)alloc((size_t)NNODES * HIDDIM * 4);
    float* obuf   = (float*)alloc((size_t)NNODES * HIDDIM * 4);
    float* sb     = (float*)alloc((size_t)NNODES * HIDDIM * 4);
    int*   deg    = (int*)alloc((2 * NNODES + 128 + 4 * 256) * 4);
    int*   cursor = deg + NNODES;
    int*   gs     = deg + 2 * NNODES;
    int*   ge     = gs + NGRAPH;
    float* bnstat4 = (float*)(deg + 2 * NNODES + 128);
    int*   chunk  = (int*)alloc(NNODES * 4);
    int*   bsum   = (int*)alloc(128 * 4);
    int*   offs   = (int*)alloc((NNODES + 1) * 4);
    int*   csrsrc = (int*)alloc(NEDGES * 4);

    unsigned short* WtQKV = WtAll;                       // [3][384][KC]
    unsigned short* WtS   = WtAll + (size_t)1152 * KC;   // [3][128][KC]
    unsigned short* Wpt   = WtAll + (size_t)1536 * KC;
    unsigned short* Ws3t  = WtAll + (size_t)1664 * KC;
    unsigned short* Wt3t  = WtAll + (size_t)1792 * KC;   // [8][128][KC] t
    unsigned short* Wt3v  = WtAll + (size_t)2816 * KC;   // [8][128][KC] v-proj
    float* bQKV = bcat;          // [3][384]
    float* bS   = bcat + 1152;   // [3][128]
    float* b3t  = bcat + 1536;   // [1024]
    float* b3v  = bcat + 2560;   // [1024]
    unsigned short* qkvb = tbuf; // layers 0-2 alias: [N][384]

    const int TB = 256;
    const int ZWORDS = 2 * NNODES + 128 + 4 * 256;
    zero_kernel<<<(ZWORDS + TB - 1) / TB, TB, 0, stream>>>((float*)deg, ZWORDS);
    count_deg_kernel<<<(NEDGES + TB - 1) / TB, TB, 0, stream>>>(edst, deg, NEDGES);
    const int NB = (NNODES + 255) / 256;
    scan1_kernel<<<NB, 256, 0, stream>>>(deg, chunk, bsum, NNODES);
    scan2_kernel<<<1, 128, 0, stream>>>(bsum, NB);
    scan3_kernel<<<NB, 256, 0, stream>>>(chunk, bsum, offs, NNODES);
    scatter_kernel<<<(NEDGES + TB - 1) / TB, TB, 0, stream>>>(esrc, edst, offs, cursor, csrsrc, NEDGES);
    gb_kernel<<<(NNODES + TB - 1) / TB, TB, 0, stream>>>(batch, gs, ge, NNODES);

    prep_w_kernel<<<3840, 128, 0, stream>>>(Wq, Wk, Wv, Ws, Wp, Ws3, Wv3, WtAll);
    prep_bias_kernel<<<(3584 + TB - 1) / TB, TB, 0, stream>>>(bq, bk, bv, bs, bv3, bcat);
    mqk_kernel<<<1024, 128, 0, stream>>>(Wq3, Wk3, bq3, WtAll, bcat);

    const int CATB = (NPAD * HIDDIM + TB - 1) / TB;
    const int GSW = 8 * ((GXTILES + 7) / 8);  // 160 swizzled x-slots

    cat_from_kernel<<<CATB, TB, 0, stream>>>(x, Acat);
    gemm_mfma_kernel<float, 12, 1, 0><<<GSW * 1, 256, 0, stream>>>(Acat, Wpt, bp, hbuf, 128, NNODES);
    cat_from_kernel<<<CATB, TB, 0, stream>>>(hbuf, Acat);

    for (int li = 0; li < 3; ++li) {
        gemm_mfma_kernel<unsigned short, 8, 3, 0><<<GSW * 3, 256, 0, stream>>>(
            Acat, WtQKV + (size_t)li * 384 * KC, bQKV + li * 384, qkvb, 384, NNODES);
        gemm_mfma_kernel<float, 12, 1, 0><<<GSW * 1, 256, 0, stream>>>(
            Acat, WtS + (size_t)li * 128 * KC, bS + li * 128, sfp, 128, NNODES);
        attn_small_kernel<<<NNODES, 64, 0, stream>>>(qkvb, sfp, Wbeta + li * 384,
                                                     offs, csrsrc, obuf);
        float* st = bnstat4 + li * 256;
        bn_stats_kernel<<<640, 128, 0, stream>>>(obuf, st, NNODES);
        bn_apply_kernel<<<512, 128, 0, stream>>>(obuf, st, bn_gamma + li * HIDDIM,
                                                 bn_beta + li * HIDDIM, NNODES, Acat);
    }

    // ---- layer 3: t GEMM -> aggregate h -> per-head V projection -> beta ----
    gemm_mfma_kernel<unsigned short, 8, 8, 1><<<GSW * 8, 256, 0, stream>>>(
        Acat, Wt3t, b3t, tbuf, 1024, NNODES);
    attn_big_kernel<<<dim3(NNODES, 8), 64, 0, stream>>>(tbuf, Acat, offs, csrsrc, aggb);
    gemm_head_kernel<<<GSW * 8, 256, 0, stream>>>(aggb, Wt3v, b3v, obuf8, NNODES);
    gemm_mfma_kernel<float, 12, 1, 0><<<GSW * 1, 256, 0, stream>>>(Acat, Ws3t, bs3, sb, 128, NNODES);
    beta3_kernel<<<NNODES, 128, 0, stream>>>(obuf8, sb, Wbeta3, hbuf);
    float* st3 = bnstat4 + 3 * 256;
    bn_stats_kernel<<<640, 128, 0, stream>>>(hbuf, st3, NNODES);
    bn_apply_kernel<<<512, 128, 0, stream>>>(hbuf, st3, bn_gamma + 3 * HIDDIM,
                                             bn_beta + 3 * HIDDIM, NNODES, (unsigned short*)0);

    zero_kernel<<<(NGRAPH * HIDDIM + TB - 1) / TB, TB, 0, stream>>>(out, NGRAPH * HIDDIM);
    pool_part_kernel<<<dim3(NGRAPH, 8), 256, 0, stream>>>(hbuf, gs, ge, out);
    pool_div_kernel<<<NGRAPH, 128, 0, stream>>>(out, gs, ge);
}

// Round 20
// 624.196 us; speedup vs baseline: 1.2075x; 1.0631x over previous
//
#include <hip/hip_runtime.h>
#include <math.h>

#define NNODES 20000
#define NPAD   20096   // 157 * 128
#define NEDGES 160000
#define HIDDIM 128
#define NHEADS 8
#define NGRAPH 64
#define KC 384   // concatenated K (hi | lo | hi)
#define GXTILES 157

typedef short short8 __attribute__((ext_vector_type(8)));
typedef float floatx4 __attribute__((ext_vector_type(4)));
typedef unsigned short ushort4v __attribute__((ext_vector_type(4)));

__device__ inline unsigned short f2bf(float x) {
    unsigned u = __float_as_uint(x);
    u += 0x7fff + ((u >> 16) & 1);
    return (unsigned short)(u >> 16);
}
__device__ inline float bf2f(unsigned short h) {
    return __uint_as_float(((unsigned)h) << 16);
}

// ---------------- utility ----------------
__global__ __launch_bounds__(256) void zero_kernel(float* __restrict__ p, int n) {
    int i = blockIdx.x * blockDim.x + threadIdx.x;
    if (i < n) p[i] = 0.f;
}

// ---------------- CSR build ----------------
__global__ __launch_bounds__(256) void count_deg_kernel(const int* __restrict__ dst,
                                                        int* __restrict__ deg, int e) {
    int i = blockIdx.x * blockDim.x + threadIdx.x;
    if (i < e) atomicAdd(&deg[dst[i]], 1);
}

__global__ __launch_bounds__(256) void scan1_kernel(const int* __restrict__ deg,
                                                    int* __restrict__ chunk,
                                                    int* __restrict__ bsum, int n) {
    __shared__ int buf[256];
    int t = threadIdx.x;
    int i = blockIdx.x * 256 + t;
    int v = (i < n) ? deg[i] : 0;
    buf[t] = v;
    __syncthreads();
    for (int off = 1; off < 256; off <<= 1) {
        int tmp = (t >= off) ? buf[t - off] : 0;
        __syncthreads();
        buf[t] += tmp;
        __syncthreads();
    }
    if (i < n) chunk[i] = buf[t];
    if (t == 255) bsum[blockIdx.x] = buf[255];
}

__global__ __launch_bounds__(128) void scan2_kernel(int* __restrict__ bsum, int nb) {
    __shared__ int buf[128];
    int t = threadIdx.x;
    int v = (t < nb) ? bsum[t] : 0;
    buf[t] = v;
    __syncthreads();
    for (int off = 1; off < 128; off <<= 1) {
        int tmp = (t >= off) ? buf[t - off] : 0;
        __syncthreads();
        buf[t] += tmp;
        __syncthreads();
    }
    if (t < nb) bsum[t] = buf[t] - v;
}

__global__ __launch_bounds__(256) void scan3_kernel(const int* __restrict__ chunk,
                                                    const int* __restrict__ bsum,
                                                    int* __restrict__ offs, int n) {
    int i = blockIdx.x * 256 + threadIdx.x;
    if (i < n) offs[i + 1] = chunk[i] + bsum[i >> 8];
    if (i == 0) offs[0] = 0;
}

__global__ __launch_bounds__(256) void scatter_kernel(const int* __restrict__ src,
                                                      const int* __restrict__ dst,
                                                      const int* __restrict__ offs,
                                                      int* __restrict__ cursor,
                                                      int* __restrict__ csr_src, int e) {
    int i = blockIdx.x * blockDim.x + threadIdx.x;
    if (i < e) {
        int d = dst[i];
        int pos = offs[d] + atomicAdd(&cursor[d], 1);
        csr_src[pos] = src[i];
    }
}

// ---------------- weight prep ----------------
// Rows: [0,1152) layers qkv ; [1152,1536) layers s ; [1536,1664) Wp ;
// [1664,1792) Ws3 ; [1792,2816) layer3 t rows (mqk fills).
__global__ __launch_bounds__(128) void prep_w_kernel(
    const float* __restrict__ Wq, const float* __restrict__ Wk,
    const float* __restrict__ Wv, const float* __restrict__ Ws,
    const float* __restrict__ Wp, const float* __restrict__ Ws3,
    unsigned short* __restrict__ WtAll) {
    int id = blockIdx.x;
    int k = threadIdx.x;
    float w;
    if (id < 1152) {
        int li = id / 384, n = id % 384, sel = n >> 7, np = n & 127;
        const float* W = (sel == 0) ? Wq : (sel == 1) ? Wk : Wv;
        w = W[li * 16384 + k * 128 + np];
    } else if (id < 1536) {
        int r = id - 1152, li = r >> 7, np = r & 127;
        w = Ws[li * 16384 + k * 128 + np];
    } else if (id < 1664) {
        w = Wp[k * 128 + (id - 1536)];
    } else {
        w = Ws3[k * 128 + (id - 1664)];
    }
    unsigned short hi = f2bf(w);
    unsigned short lo = f2bf(w - bf2f(hi));
    unsigned short* dst = WtAll + (size_t)id * KC;
    dst[k] = hi;
    dst[128 + k] = hi;
    dst[256 + k] = lo;
}

__global__ __launch_bounds__(256) void prep_bias_kernel(
    const float* __restrict__ bq, const float* __restrict__ bk,
    const float* __restrict__ bv, const float* __restrict__ bs,
    float* __restrict__ bcat) {
    int id = blockIdx.x * 256 + threadIdx.x;
    if (id >= 1536) return;
    float v;
    if (id < 1152) {
        int li = id / 384, n = id % 384, sel = n >> 7, np = n & 127;
        const float* b = (sel == 0) ? bq : (sel == 1) ? bk : bv;
        v = b[li * 128 + np];
    } else {
        int r = id - 1152, li = r >> 7, np = r & 127;
        v = bs[li * 128 + np];
    }
    bcat[id] = v;
}

// ---------------- layer-3 fused QK weights: M_h = Wq_h Wk_h^T ----------------
// t feature f = h*128+b; weight row 1792+f; bias bcat[1536+f].
__global__ __launch_bounds__(128) void mqk_kernel(
    const float* __restrict__ Wq3, const float* __restrict__ Wk3,
    const float* __restrict__ bq3,
    unsigned short* __restrict__ WtAll, float* __restrict__ bcat) {
    int hb = blockIdx.x;
    int h = hb >> 7, b = hb & 127;
    int a = threadIdx.x;
    __shared__ float wk[128];
    wk[a] = Wk3[(size_t)b * 1024 + h * 128 + a];
    __syncthreads();
    const float* wq = Wq3 + (size_t)a * 1024 + h * 128;
    float acc = 0.f;
#pragma unroll 16
    for (int d = 0; d < 128; ++d) acc = fmaf(wq[d], wk[d], acc);
    unsigned short hi = f2bf(acc);
    unsigned short lo = f2bf(acc - bf2f(hi));
    unsigned short* dst = WtAll + (size_t)(1792 + h * 128 + b) * KC;
    dst[a] = hi;
    dst[128 + a] = hi;
    dst[256 + a] = lo;
    if (a == 0) {
        float bb = 0.f;
        for (int d = 0; d < 128; ++d) bb = fmaf(bq3[h * 128 + d], wk[d], bb);
        bcat[1536 + h * 128 + b] = bb;
    }
}

// ---------------- mean-V weights: Wvm[j][h*128+a] = Wv3[a][h*128+j]/8 ----------------
__global__ __launch_bounds__(128) void prep_wvm_kernel(
    const float* __restrict__ Wv3, const float* __restrict__ bv3,
    unsigned short* __restrict__ Wvm, float* __restrict__ bvm) {
    int j = blockIdx.x;
    int a = threadIdx.x;
#pragma unroll
    for (int h = 0; h < 8; ++h) {
        float w = Wv3[(size_t)a * 1024 + h * 128 + j] * 0.125f;
        Wvm[(size_t)j * 1024 + h * 128 + a] = f2bf(w);
    }
    if (a == 0) {
        float s = 0.f;
        for (int h = 0; h < 8; ++h) s += bv3[h * 128 + j];
        bvm[j] = s * 0.125f;
    }
}

// ---------------- activation -> split-bf16 A_cat ----------------
__global__ __launch_bounds__(256) void cat_from_kernel(const float* __restrict__ h,
                                                       unsigned short* __restrict__ Acat) {
    int idx = blockIdx.x * 256 + threadIdx.x;
    if (idx >= NPAD * HIDDIM) return;
    int r = idx >> 7, k = idx & 127;
    float x = (r < NNODES) ? h[idx] : 0.f;
    unsigned short hi = f2bf(x);
    unsigned short lo = f2bf(x - bf2f(hi));
    unsigned short* row = Acat + (size_t)r * KC;
    row[k] = hi;
    row[128 + k] = lo;
    row[256 + k] = hi;
}

// ---------------- MFMA GEMM (XCD swizzle) ----------------
template <typename OutT, int KG, int BY>
__global__ __launch_bounds__(256) void gemm_mfma_kernel(
    const unsigned short* __restrict__ Acat, const unsigned short* __restrict__ Wt,
    const float* __restrict__ bias, OutT* __restrict__ C, int M, int nrows) {
    int id = blockIdx.x;
    int xcd = id & 7;
    int idx = id >> 3;
    int bx = (idx / BY) * 8 + xcd;
    int by = idx % BY;
    if (bx >= GXTILES) return;
    int lane = threadIdx.x & 63;
    int wave = threadIdx.x >> 6;
    int nodeBase = bx * 128 + (wave & 1) * 64;
    int featBase = by * 128 + (wave >> 1) * 64;
    int m = lane & 15;
    int q = lane >> 4;
    int ko = q * 8;
    const unsigned short* wptr = Wt + (size_t)(featBase + m) * KC + ko;
    const unsigned short* aptr = Acat + (size_t)(nodeBase + m) * KC + ko;
    floatx4 acc[4][4];
#pragma unroll
    for (int r = 0; r < 4; ++r)
#pragma unroll
        for (int c = 0; c < 4; ++c) acc[r][c] = (floatx4){0.f, 0.f, 0.f, 0.f};
#pragma unroll
    for (int kg = 0; kg < KG; ++kg) {
        short8 a[4], b[4];
#pragma unroll
        for (int r = 0; r < 4; ++r) a[r] = *(const short8*)(wptr + (size_t)r * 16 * KC + kg * 32);
#pragma unroll
        for (int c = 0; c < 4; ++c) b[c] = *(const short8*)(aptr + (size_t)c * 16 * KC + kg * 32);
#pragma unroll
        for (int r = 0; r < 4; ++r)
#pragma unroll
            for (int c = 0; c < 4; ++c)
                acc[r][c] = __builtin_amdgcn_mfma_f32_16x16x32_bf16(a[r], b[c], acc[r][c], 0, 0, 0);
    }
    float4 bv[4];
#pragma unroll
    for (int r = 0; r < 4; ++r) bv[r] = *(const float4*)(bias + featBase + r * 16 + q * 4);
#pragma unroll
    for (int c = 0; c < 4; ++c) {
        int node = nodeBase + c * 16 + m;
        if (node < nrows) {
#pragma unroll
            for (int r = 0; r < 4; ++r) {
                int f0 = featBase + r * 16 + q * 4;
                float v0 = acc[r][c][0] + bv[r].x;
                float v1 = acc[r][c][1] + bv[r].y;
                float v2 = acc[r][c][2] + bv[r].z;
                float v3 = acc[r][c][3] + bv[r].w;
                if (sizeof(OutT) == 2) {
                    ushort4v o = {f2bf(v0), f2bf(v1), f2bf(v2), f2bf(v3)};
                    *(ushort4v*)((unsigned short*)C + (size_t)node * M + f0) = o;
                } else {
                    float4 o = {v0, v1, v2, v3};
                    *(float4*)((float*)C + (size_t)node * M + f0) = o;
                }
            }
        }
    }
}

// ---------------- mean-V GEMM: omean[N][128] = agg[N][1024] @ Wvm^T + bvm ----------------
__global__ __launch_bounds__(256) void gemm_vmean_kernel(
    const unsigned short* __restrict__ agg, const unsigned short* __restrict__ Wvm,
    const float* __restrict__ bvm, float* __restrict__ omean, int nrows) {
    int id = blockIdx.x;
    int xcd = id & 7;
    int idx = id >> 3;
    int bx = idx * 8 + xcd;
    if (bx >= GXTILES) return;
    int lane = threadIdx.x & 63;
    int wave = threadIdx.x >> 6;
    int nodeBase = bx * 128 + (wave & 1) * 64;
    int featHalf = (wave >> 1) * 64;
    int m = lane & 15;
    int q = lane >> 4;
    const unsigned short* wptr = Wvm + (size_t)(featHalf + m) * 1024 + q * 8;
    const unsigned short* aptr = agg + (size_t)(nodeBase + m) * 1024 + q * 8;
    floatx4 acc[4][4];
#pragma unroll
    for (int r = 0; r < 4; ++r)
#pragma unroll
        for (int c = 0; c < 4; ++c) acc[r][c] = (floatx4){0.f, 0.f, 0.f, 0.f};
#pragma unroll
    for (int kg = 0; kg < 32; ++kg) {
        short8 a[4], b[4];
#pragma unroll
        for (int r = 0; r < 4; ++r) a[r] = *(const short8*)(wptr + (size_t)r * 16 * 1024 + kg * 32);
#pragma unroll
        for (int c = 0; c < 4; ++c) b[c] = *(const short8*)(aptr + (size_t)c * 16 * 1024 + kg * 32);
#pragma unroll
        for (int r = 0; r < 4; ++r)
#pragma unroll
            for (int c = 0; c < 4; ++c)
                acc[r][c] = __builtin_amdgcn_mfma_f32_16x16x32_bf16(a[r], b[c], acc[r][c], 0, 0, 0);
    }
    float4 bv[4];
#pragma unroll
    for (int r = 0; r < 4; ++r) bv[r] = *(const float4*)(bvm + featHalf + r * 16 + q * 4);
#pragma unroll
    for (int c = 0; c < 4; ++c) {
        int node = nodeBase + c * 16 + m;
        if (node < nrows) {
#pragma unroll
            for (int r = 0; r < 4; ++r) {
                int f0 = featHalf + r * 16 + q * 4;
                float4 o = {acc[r][c][0] + bv[r].x, acc[r][c][1] + bv[r].y,
                            acc[r][c][2] + bv[r].z, acc[r][c][3] + bv[r].w};
                *(float4*)(omean + (size_t)node * HIDDIM + f0) = o;
            }
        }
    }
}

// ---------------- attention layers 0-2 (plain-exp softmax) ----------------
__global__ __launch_bounds__(64) void attn_small_kernel(
    const unsigned short* __restrict__ qkv, const float* __restrict__ sfp,
    const float* __restrict__ Wb,
    const int* __restrict__ offs, const int* __restrict__ csr_src,
    float* __restrict__ out) {
    int i = blockIdx.x;
    int l = threadIdx.x;
    int g = l >> 5;
    int d0 = (l & 31) * 4;
    uint2 qraw = *(const uint2*)(qkv + (size_t)i * 384 + d0);
    float q0 = bf2f((unsigned short)(qraw.x & 0xffff)), q1 = bf2f((unsigned short)(qraw.x >> 16));
    float q2 = bf2f((unsigned short)(qraw.y & 0xffff)), q3 = bf2f((unsigned short)(qraw.y >> 16));
    int e0 = offs[i], e1 = offs[i + 1];
    float lac = 0.f;
    float a0 = 0.f, a1 = 0.f, a2 = 0.f, a3 = 0.f;
    for (int e = e0 + g; e < e1; e += 2) {
        int sn = csr_src[e];
        const unsigned short* row = qkv + (size_t)sn * 384;
        uint2 kk = *(const uint2*)(row + 128 + d0);
        uint2 vv = *(const uint2*)(row + 256 + d0);
        float k0 = bf2f((unsigned short)(kk.x & 0xffff)), k1 = bf2f((unsigned short)(kk.x >> 16));
        float k2 = bf2f((unsigned short)(kk.y & 0xffff)), k3 = bf2f((unsigned short)(kk.y >> 16));
        float p = q0 * k0 + q1 * k1 + q2 * k2 + q3 * k3;
        p += __shfl_xor(p, 1);
        p += __shfl_xor(p, 2);
        float w = __expf(p * 0.25f);
        float v0 = bf2f((unsigned short)(vv.x & 0xffff)), v1 = bf2f((unsigned short)(vv.x >> 16));
        float v2 = bf2f((unsigned short)(vv.y & 0xffff)), v3 = bf2f((unsigned short)(vv.y >> 16));
        a0 += w * v0;
        a1 += w * v1;
        a2 += w * v2;
        a3 += w * v3;
        lac += w;
    }
    a0 += __shfl_xor(a0, 32);
    a1 += __shfl_xor(a1, 32);
    a2 += __shfl_xor(a2, 32);
    a3 += __shfl_xor(a3, 32);
    lac += __shfl_xor(lac, 32);
    float inv = 1.f / (lac + 1e-16f);
    float o0 = a0 * inv, o1 = a1 * inv, o2 = a2 * inv, o3 = a3 * inv;
    float4 rv = *(const float4*)(sfp + (size_t)i * HIDDIM + d0);
    float part = o0 * Wb[d0] + o1 * Wb[d0 + 1] + o2 * Wb[d0 + 2] + o3 * Wb[d0 + 3]
               + rv.x * Wb[128 + d0] + rv.y * Wb[128 + d0 + 1]
               + rv.z * Wb[128 + d0 + 2] + rv.w * Wb[128 + d0 + 3]
               + (o0 - rv.x) * Wb[256 + d0] + (o1 - rv.y) * Wb[256 + d0 + 1]
               + (o2 - rv.z) * Wb[256 + d0 + 2] + (o3 - rv.w) * Wb[256 + d0 + 3];
    if (g) part = 0.f;
#pragma unroll
    for (int msk = 1; msk <= 32; msk <<= 1) part += __shfl_xor(part, msk);
    float gg = 1.f / (1.f + __expf(-part));
    if (g == 0) {
        float4 o4 = {gg * rv.x + (1.f - gg) * o0, gg * rv.y + (1.f - gg) * o1,
                     gg * rv.z + (1.f - gg) * o2, gg * rv.w + (1.f - gg) * o3};
        *(float4*)(out + (size_t)i * HIDDIM + d0) = o4;
    }
}

// ---------------- attention layer 3: ALL 8 heads in one block ----------------
// 64 lanes = 8 heads x 8 lanes x 16 dims. t node-major [N][1024]; each h_j row
// (256 B of Acat hi) fetched ONCE per edge and shared by all heads in-wave.
// agg written node-major [N][1024] bf16 (contiguous 2 KB per node).
__global__ __launch_bounds__(64) void attn_big_kernel(
    const unsigned short* __restrict__ tbuf, const unsigned short* __restrict__ Acat,
    const int* __restrict__ offs, const int* __restrict__ csr_src,
    unsigned short* __restrict__ agg) {
    int i = blockIdx.x;
    int l = threadIdx.x;
    int doff = (l & 7) * 16;   // dim offset within 128
    const unsigned short* tp = tbuf + (size_t)i * 1024 + l * 16;
    uint4 t0 = *(const uint4*)tp;
    uint4 t1 = *(const uint4*)(tp + 8);
    float tq[16];
    tq[0] = bf2f((unsigned short)(t0.x & 0xffff)); tq[1] = bf2f((unsigned short)(t0.x >> 16));
    tq[2] = bf2f((unsigned short)(t0.y & 0xffff)); tq[3] = bf2f((unsigned short)(t0.y >> 16));
    tq[4] = bf2f((unsigned short)(t0.z & 0xffff)); tq[5] = bf2f((unsigned short)(t0.z >> 16));
    tq[6] = bf2f((unsigned short)(t0.w & 0xffff)); tq[7] = bf2f((unsigned short)(t0.w >> 16));
    tq[8] = bf2f((unsigned short)(t1.x & 0xffff)); tq[9] = bf2f((unsigned short)(t1.x >> 16));
    tq[10] = bf2f((unsigned short)(t1.y & 0xffff)); tq[11] = bf2f((unsigned short)(t1.y >> 16));
    tq[12] = bf2f((unsigned short)(t1.z & 0xffff)); tq[13] = bf2f((unsigned short)(t1.z >> 16));
    tq[14] = bf2f((unsigned short)(t1.w & 0xffff)); tq[15] = bf2f((unsigned short)(t1.w >> 16));
    int e0 = offs[i], e1 = offs[i + 1];
    float ac[16];
#pragma unroll
    for (int j = 0; j < 16; ++j) ac[j] = 0.f;
    float lac = 0.f;
    for (int e = e0; e < e1; ++e) {
        int sn = csr_src[e];
        const unsigned short* hp = Acat + (size_t)sn * KC + doff;
        uint4 k0 = *(const uint4*)hp;
        uint4 k1 = *(const uint4*)(hp + 8);
        float kk[16];
        kk[0] = bf2f((unsigned short)(k0.x & 0xffff)); kk[1] = bf2f((unsigned short)(k0.x >> 16));
        kk[2] = bf2f((unsigned short)(k0.y & 0xffff)); kk[3] = bf2f((unsigned short)(k0.y >> 16));
        kk[4] = bf2f((unsigned short)(k0.z & 0xffff)); kk[5] = bf2f((unsigned short)(k0.z >> 16));
        kk[6] = bf2f((unsigned short)(k0.w & 0xffff)); kk[7] = bf2f((unsigned short)(k0.w >> 16));
        kk[8] = bf2f((unsigned short)(k1.x & 0xffff)); kk[9] = bf2f((unsigned short)(k1.x >> 16));
        kk[10] = bf2f((unsigned short)(k1.y & 0xffff)); kk[11] = bf2f((unsigned short)(k1.y >> 16));
        kk[12] = bf2f((unsigned short)(k1.z & 0xffff)); kk[13] = bf2f((unsigned short)(k1.z >> 16));
        kk[14] = bf2f((unsigned short)(k1.w & 0xffff)); kk[15] = bf2f((unsigned short)(k1.w >> 16));
        float p = 0.f;
#pragma unroll
        for (int j = 0; j < 16; ++j) p = fmaf(tq[j], kk[j], p);
        p += __shfl_xor(p, 1);
        p += __shfl_xor(p, 2);
        p += __shfl_xor(p, 4);   // dot over this head's 8-lane group (128 dims)
        float w = __expf(p * 0.08838834764831845f);
#pragma unroll
        for (int j = 0; j < 16; ++j) ac[j] = fmaf(w, kk[j], ac[j]);
        lac += w;
    }
    float inv = 1.f / (lac + 1e-16f);
    unsigned short* o = agg + (size_t)i * 1024 + l * 16;
    ushort4v o0 = {f2bf(ac[0] * inv), f2bf(ac[1] * inv), f2bf(ac[2] * inv), f2bf(ac[3] * inv)};
    ushort4v o1 = {f2bf(ac[4] * inv), f2bf(ac[5] * inv), f2bf(ac[6] * inv), f2bf(ac[7] * inv)};
    ushort4v o2 = {f2bf(ac[8] * inv), f2bf(ac[9] * inv), f2bf(ac[10] * inv), f2bf(ac[11] * inv)};
    ushort4v o3 = {f2bf(ac[12] * inv), f2bf(ac[13] * inv), f2bf(ac[14] * inv), f2bf(ac[15] * inv)};
    *(ushort4v*)o = o0;
    *(ushort4v*)(o + 4) = o1;
    *(ushort4v*)(o + 8) = o2;
    *(ushort4v*)(o + 12) = o3;
}

// ---------------- beta gate layer 3 (omean already head-meaned) ----------------
__global__ __launch_bounds__(128) void beta3_kernel(const float* __restrict__ omean,
                                                    const float* __restrict__ s,
                                                    const float* __restrict__ Wb,
                                                    float* __restrict__ out) {
    int i = blockIdx.x, t = threadIdx.x;
    float o = omean[(size_t)i * HIDDIM + t];
    float r = s[(size_t)i * HIDDIM + t];
    float part = o * Wb[t] + r * Wb[128 + t] + (o - r) * Wb[256 + t];
#pragma unroll
    for (int msk = 1; msk <= 32; msk <<= 1) part += __shfl_xor(part, msk);
    __shared__ float wsum[2];
    if ((t & 63) == 0) wsum[t >> 6] = part;
    __syncthreads();
    float tot = wsum[0] + wsum[1];
    float g = 1.f / (1.f + __expf(-tot));
    out[(size_t)i * HIDDIM + t] = g * r + (1.f - g) * o;
}

// ---------------- batchnorm ----------------
__global__ __launch_bounds__(128) void bn_stats_kernel(const float* __restrict__ x,
                                                       float* __restrict__ stat, int n) {
    int t = threadIdx.x;
    float s = 0.f, sq = 0.f;
    for (int i = blockIdx.x; i < n; i += gridDim.x) {
        float v = x[(size_t)i * HIDDIM + t];
        s += v;
        sq += v * v;
    }
    atomicAdd(&stat[t], s);
    atomicAdd(&stat[HIDDIM + t], sq);
}

__global__ __launch_bounds__(128) void bn_apply_kernel(float* __restrict__ x,
                                                       const float* __restrict__ stat,
                                                       const float* __restrict__ gamma,
                                                       const float* __restrict__ beta, int n,
                                                       unsigned short* __restrict__ cat) {
    int t = threadIdx.x;
    float mu = stat[t] / (float)n;
    float var = stat[HIDDIM + t] / (float)n - mu * mu;
    float rs = rsqrtf(var + 1e-5f);
    float g = gamma[t], b = beta[t];
    for (int i = blockIdx.x; i < n; i += gridDim.x) {
        float v = x[(size_t)i * HIDDIM + t];
        v = fmaxf((v - mu) * rs * g + b, 0.f);
        x[(size_t)i * HIDDIM + t] = v;
        if (cat) {
            unsigned short hi = f2bf(v);
            unsigned short lo = f2bf(v - bf2f(hi));
            unsigned short* row = cat + (size_t)i * KC;
            row[t] = hi;
            row[128 + t] = lo;
            row[256 + t] = hi;
        }
    }
}

// ---------------- pool ----------------
__global__ __launch_bounds__(256) void gb_kernel(const int* __restrict__ batch,
                                                 int* __restrict__ gs,
                                                 int* __restrict__ ge, int n) {
    int i = blockIdx.x * 256 + threadIdx.x;
    if (i >= n) return;
    int b = batch[i];
    if (i == 0 || batch[i - 1] != b) gs[b] = i;
    if (i == n - 1 || batch[i + 1] != b) ge[b] = i + 1;
}

__global__ __launch_bounds__(256) void pool_part_kernel(const float* __restrict__ x,
                                                        const int* __restrict__ gs,
                                                        const int* __restrict__ ge,
                                                        float* __restrict__ out) {
    int g = blockIdx.x, c = blockIdx.y;
    int t = threadIdx.x;
    int f = t & 127, half = t >> 7;
    int s = gs[g], e = ge[g];
    float acc = 0.f;
    for (int i = s + 2 * c + half; i < e; i += 16) acc += x[(size_t)i * HIDDIM + f];
    __shared__ float l0[128];
    if (half == 0) l0[f] = acc;
    __syncthreads();
    if (half == 1) atomicAdd(&out[g * HIDDIM + f], l0[f] + acc);
}

__global__ __launch_bounds__(128) void pool_div_kernel(float* __restrict__ out,
                                                       const int* __restrict__ gs,
                                                       const int* __restrict__ ge) {
    int g = blockIdx.x, t = threadIdx.x;
    int c = ge[g] - gs[g];
    out[g * HIDDIM + t] /= (float)(c > 0 ? c : 1);
}

// ---------------- host ----------------
extern "C" void kernel_launch(void* const* d_in, const int* in_sizes, int n_in,
                              void* d_out, int out_size, void* d_ws, size_t ws_size,
                              hipStream_t stream) {
    const float* x       = (const float*)d_in[0];
    const int*   ei      = (const int*)d_in[1];
    const int*   batch   = (const int*)d_in[2];
    const float* Wp      = (const float*)d_in[3];
    const float* bp      = (const float*)d_in[4];
    const float* Wq      = (const float*)d_in[5];
    const float* bq      = (const float*)d_in[6];
    const float* Wk      = (const float*)d_in[7];
    const float* bk      = (const float*)d_in[8];
    const float* Wv      = (const float*)d_in[9];
    const float* bv      = (const float*)d_in[10];
    const float* Ws      = (const float*)d_in[11];
    const float* bs      = (const float*)d_in[12];
    const float* Wbeta   = (const float*)d_in[13];
    const float* Wq3     = (const float*)d_in[14];
    const float* bq3     = (const float*)d_in[15];
    const float* Wk3     = (const float*)d_in[16];
    const float* bk3     = (const float*)d_in[17];
    const float* Wv3     = (const float*)d_in[18];
    const float* bv3     = (const float*)d_in[19];
    const float* Ws3     = (const float*)d_in[20];
    const float* bs3     = (const float*)d_in[21];
    const float* Wbeta3  = (const float*)d_in[22];
    const float* bn_gamma = (const float*)d_in[23];
    const float* bn_beta  = (const float*)d_in[24];
    float* out = (float*)d_out;
    (void)bk3;

    const int* esrc = ei;
    const int* edst = ei + NEDGES;

    char* wpc = (char*)d_ws;
    auto alloc = [&](size_t nbytes) -> char* {
        char* p = wpc;
        wpc += (nbytes + 255) & ~(size_t)255;
        return p;
    };
    unsigned short* Acat  = (unsigned short*)alloc((size_t)NPAD * KC * 2);      // 15.4 MB
    unsigned short* WtAll = (unsigned short*)alloc((size_t)2816 * KC * 2);      // 2.2 MB
    float* bcat   = (float*)alloc(2560 * 4);
    unsigned short* Wvm   = (unsigned short*)alloc((size_t)128 * 1024 * 2);     // 256 KB
    float* bvm    = (float*)alloc(128 * 4);
    unsigned short* tbuf  = (unsigned short*)alloc((size_t)NPAD * 1024 * 2);    // 41 MB (alias qkvb)
    unsigned short* aggb  = (unsigned short*)alloc((size_t)NPAD * 1024 * 2);    // 41 MB
    float* omean  = (float*)alloc((size_t)NNODES * HIDDIM * 4);                 // 10.2 MB
    float* sfp    = (float*)alloc((size_t)NNODES * HIDDIM * 4);                 // 10.2 MB
    float* hbuf   = (float*)alloc((size_t)NNODES * HIDDIM * 4);
    float* obuf   = (float*)alloc((size_t)NNODES * HIDDIM * 4);
    float* sb     = (float*)alloc((size_t)NNODES * HIDDIM * 4);
    int*   deg    = (int*)alloc((2 * NNODES + 128 + 4 * 256) * 4);
    int*   cursor = deg + NNODES;
    int*   gs     = deg + 2 * NNODES;
    int*   ge     = gs + NGRAPH;
    float* bnstat4 = (float*)(deg + 2 * NNODES + 128);
    int*   chunk  = (int*)alloc(NNODES * 4);
    int*   bsum   = (int*)alloc(128 * 4);
    int*   offs   = (int*)alloc((NNODES + 1) * 4);
    int*   csrsrc = (int*)alloc(NEDGES * 4);

    unsigned short* WtQKV = WtAll;                       // [3][384][KC]
    unsigned short* WtS   = WtAll + (size_t)1152 * KC;   // [3][128][KC]
    unsigned short* Wpt   = WtAll + (size_t)1536 * KC;
    unsigned short* Ws3t  = WtAll + (size_t)1664 * KC;
    unsigned short* Wt3t  = WtAll + (size_t)1792 * KC;   // [1024][KC] t (feature-major)
    float* bQKV = bcat;          // [3][384]
    float* bS   = bcat + 1152;   // [3][128]
    float* b3t  = bcat + 1536;   // [1024]
    unsigned short* qkvb = tbuf; // layers 0-2 alias: [N][384]

    const int TB = 256;
    const int ZWORDS = 2 * NNODES + 128 + 4 * 256;
    zero_kernel<<<(ZWORDS + TB - 1) / TB, TB, 0, stream>>>((float*)deg, ZWORDS);
    count_deg_kernel<<<(NEDGES + TB - 1) / TB, TB, 0, stream>>>(edst, deg, NEDGES);
    const int NB = (NNODES + 255) / 256;
    scan1_kernel<<<NB, 256, 0, stream>>>(deg, chunk, bsum, NNODES);
    scan2_kernel<<<1, 128, 0, stream>>>(bsum, NB);
    scan3_kernel<<<NB, 256, 0, stream>>>(chunk, bsum, offs, NNODES);
    scatter_kernel<<<(NEDGES + TB - 1) / TB, TB, 0, stream>>>(esrc, edst, offs, cursor, csrsrc, NEDGES);
    gb_kernel<<<(NNODES + TB - 1) / TB, TB, 0, stream>>>(batch, gs, ge, NNODES);

    prep_w_kernel<<<1792, 128, 0, stream>>>(Wq, Wk, Wv, Ws, Wp, Ws3, WtAll);
    prep_bias_kernel<<<(1536 + TB - 1) / TB, TB, 0, stream>>>(bq, bk, bv, bs, bcat);
    mqk_kernel<<<1024, 128, 0, stream>>>(Wq3, Wk3, bq3, WtAll, bcat);
    prep_wvm_kernel<<<128, 128, 0, stream>>>(Wv3, bv3, Wvm, bvm);

    const int CATB = (NPAD * HIDDIM + TB - 1) / TB;
    const int GSW = 8 * ((GXTILES + 7) / 8);  // 160 swizzled x-slots

    cat_from_kernel<<<CATB, TB, 0, stream>>>(x, Acat);
    gemm_mfma_kernel<float, 12, 1><<<GSW * 1, 256, 0, stream>>>(Acat, Wpt, bp, hbuf, 128, NNODES);
    cat_from_kernel<<<CATB, TB, 0, stream>>>(hbuf, Acat);

    for (int li = 0; li < 3; ++li) {
        gemm_mfma_kernel<unsigned short, 8, 3><<<GSW * 3, 256, 0, stream>>>(
            Acat, WtQKV + (size_t)li * 384 * KC, bQKV + li * 384, qkvb, 384, NNODES);
        gemm_mfma_kernel<float, 12, 1><<<GSW * 1, 256, 0, stream>>>(
            Acat, WtS + (size_t)li * 128 * KC, bS + li * 128, sfp, 128, NNODES);
        attn_small_kernel<<<NNODES, 64, 0, stream>>>(qkvb, sfp, Wbeta + li * 384,
                                                     offs, csrsrc, obuf);
        float* st = bnstat4 + li * 256;
        bn_stats_kernel<<<640, 128, 0, stream>>>(obuf, st, NNODES);
        bn_apply_kernel<<<512, 128, 0, stream>>>(obuf, st, bn_gamma + li * HIDDIM,
                                                 bn_beta + li * HIDDIM, NNODES, Acat);
    }

    // ---- layer 3: t GEMM (node-major) -> fused 8-head aggregate -> mean-V GEMM -> beta ----
    gemm_mfma_kernel<unsigned short, 8, 8><<<GSW * 8, 256, 0, stream>>>(
        Acat, Wt3t, b3t, tbuf, 1024, NNODES);
    attn_big_kernel<<<NNODES, 64, 0, stream>>>(tbuf, Acat, offs, csrsrc, aggb);
    gemm_vmean_kernel<<<GSW, 256, 0, stream>>>(aggb, Wvm, bvm, omean, NNODES);
    gemm_mfma_kernel<float, 12, 1><<<GSW * 1, 256, 0, stream>>>(Acat, Ws3t, bs3, sb, 128, NNODES);
    beta3_kernel<<<NNODES, 128, 0, stream>>>(omean, sb, Wbeta3, hbuf);
    float* st3 = bnstat4 + 3 * 256;
    bn_stats_kernel<<<640, 128, 0, stream>>>(hbuf, st3, NNODES);
    bn_apply_kernel<<<512, 128, 0, stream>>>(hbuf, st3, bn_gamma + 3 * HIDDIM,
                                             bn_beta + 3 * HIDDIM, NNODES, (unsigned short*)0);

    zero_kernel<<<(NGRAPH * HIDDIM + TB - 1) / TB, TB, 0, stream>>>(out, NGRAPH * HIDDIM);
    pool_part_kernel<<<dim3(NGRAPH, 8), 256, 0, stream>>>(hbuf, gs, ge, out);
    pool_div_kernel<<<NGRAPH, 128, 0, stream>>>(out, gs, ge);
}

// Round 21
// 598.271 us; speedup vs baseline: 1.2598x; 1.0433x over previous
//
#include <hip/hip_runtime.h>
#include <math.h>

#define NNODES 20000
#define NPAD   20096   // 157 * 128
#define NEDGES 160000
#define HIDDIM 128
#define NHEADS 8
#define NGRAPH 64
#define KC 384   // concatenated K (hi | lo | hi)
#define GXTILES 157

typedef short short8 __attribute__((ext_vector_type(8)));
typedef float floatx4 __attribute__((ext_vector_type(4)));
typedef unsigned short ushort4v __attribute__((ext_vector_type(4)));

__device__ inline unsigned short f2bf(float x) {
    unsigned u = __float_as_uint(x);
    u += 0x7fff + ((u >> 16) & 1);
    return (unsigned short)(u >> 16);
}
__device__ inline float bf2f(unsigned short h) {
    return __uint_as_float(((unsigned)h) << 16);
}

// ---------------- utility ----------------
__global__ __launch_bounds__(256) void zero_kernel(float* __restrict__ p, int n) {
    int i = blockIdx.x * blockDim.x + threadIdx.x;
    if (i < n) p[i] = 0.f;
}

// ---------------- CSR build ----------------
__global__ __launch_bounds__(256) void count_deg_kernel(const int* __restrict__ dst,
                                                        int* __restrict__ deg, int e) {
    int i = blockIdx.x * blockDim.x + threadIdx.x;
    if (i < e) atomicAdd(&deg[dst[i]], 1);
}

__global__ __launch_bounds__(256) void scan1_kernel(const int* __restrict__ deg,
                                                    int* __restrict__ chunk,
                                                    int* __restrict__ bsum, int n) {
    __shared__ int buf[256];
    int t = threadIdx.x;
    int i = blockIdx.x * 256 + t;
    int v = (i < n) ? deg[i] : 0;
    buf[t] = v;
    __syncthreads();
    for (int off = 1; off < 256; off <<= 1) {
        int tmp = (t >= off) ? buf[t - off] : 0;
        __syncthreads();
        buf[t] += tmp;
        __syncthreads();
    }
    if (i < n) chunk[i] = buf[t];
    if (t == 255) bsum[blockIdx.x] = buf[255];
}

__global__ __launch_bounds__(128) void scan2_kernel(int* __restrict__ bsum, int nb) {
    __shared__ int buf[128];
    int t = threadIdx.x;
    int v = (t < nb) ? bsum[t] : 0;
    buf[t] = v;
    __syncthreads();
    for (int off = 1; off < 128; off <<= 1) {
        int tmp = (t >= off) ? buf[t - off] : 0;
        __syncthreads();
        buf[t] += tmp;
        __syncthreads();
    }
    if (t < nb) bsum[t] = buf[t] - v;
}

__global__ __launch_bounds__(256) void scan3_kernel(const int* __restrict__ chunk,
                                                    const int* __restrict__ bsum,
                                                    int* __restrict__ offs, int n) {
    int i = blockIdx.x * 256 + threadIdx.x;
    if (i < n) offs[i + 1] = chunk[i] + bsum[i >> 8];
    if (i == 0) offs[0] = 0;
}

__global__ __launch_bounds__(256) void scatter_kernel(const int* __restrict__ src,
                                                      const int* __restrict__ dst,
                                                      const int* __restrict__ offs,
                                                      int* __restrict__ cursor,
                                                      int* __restrict__ csr_src, int e) {
    int i = blockIdx.x * blockDim.x + threadIdx.x;
    if (i < e) {
        int d = dst[i];
        int pos = offs[d] + atomicAdd(&cursor[d], 1);
        csr_src[pos] = src[i];
    }
}

// ---------------- weight prep ----------------
// Rows: [0,1536) layers 0-2 q|k|v|s (li*512 + sel*128 + j) ; [1536,1664) Wp ;
// [1664,2688) layer3 t rows (mqk fills) ; [2688,2816) layer3 s rows (Ws3).
__global__ __launch_bounds__(128) void prep_w_kernel(
    const float* __restrict__ Wq, const float* __restrict__ Wk,
    const float* __restrict__ Wv, const float* __restrict__ Ws,
    const float* __restrict__ Wp, const float* __restrict__ Ws3,
    unsigned short* __restrict__ WtAll) {
    int id = blockIdx.x;
    int k = threadIdx.x;
    float w;
    if (id < 1536) {
        int li = id / 512, n = id % 512, sel = n >> 7, np = n & 127;
        const float* W = (sel == 0) ? Wq : (sel == 1) ? Wk : (sel == 2) ? Wv : Ws;
        w = W[li * 16384 + k * 128 + np];
    } else if (id < 1664) {
        w = Wp[k * 128 + (id - 1536)];
    } else if (id < 2688) {
        return;  // t rows: filled by mqk_kernel
    } else {
        w = Ws3[k * 128 + (id - 2688)];
    }
    unsigned short hi = f2bf(w);
    unsigned short lo = f2bf(w - bf2f(hi));
    unsigned short* dst = WtAll + (size_t)id * KC;
    dst[k] = hi;
    dst[128 + k] = hi;
    dst[256 + k] = lo;
}

// bias: [0,1536) layers q|k|v|s ; [1536,2560) t bias (mqk fills) ;
// [2560,2688) layer3 s bias = bs3
__global__ __launch_bounds__(256) void prep_bias_kernel(
    const float* __restrict__ bq, const float* __restrict__ bk,
    const float* __restrict__ bv, const float* __restrict__ bs,
    const float* __restrict__ bs3, float* __restrict__ bcat) {
    int id = blockIdx.x * 256 + threadIdx.x;
    if (id >= 2688) return;
    float v;
    if (id < 1536) {
        int li = id / 512, n = id % 512, sel = n >> 7, np = n & 127;
        const float* b = (sel == 0) ? bq : (sel == 1) ? bk : (sel == 2) ? bv : bs;
        v = b[li * 128 + np];
    } else if (id < 2560) {
        return;  // t bias: mqk fills
    } else {
        v = bs3[id - 2560];
    }
    bcat[id] = v;
}

// ---------------- layer-3 fused QK weights: M_h = Wq_h Wk_h^T ----------------
// t feature f = h*128+b; weight row 1664+f; bias bcat[1536+f].
__global__ __launch_bounds__(128) void mqk_kernel(
    const float* __restrict__ Wq3, const float* __restrict__ Wk3,
    const float* __restrict__ bq3,
    unsigned short* __restrict__ WtAll, float* __restrict__ bcat) {
    int hb = blockIdx.x;
    int h = hb >> 7, b = hb & 127;
    int a = threadIdx.x;
    __shared__ float wk[128];
    wk[a] = Wk3[(size_t)b * 1024 + h * 128 + a];
    __syncthreads();
    const float* wq = Wq3 + (size_t)a * 1024 + h * 128;
    float acc = 0.f;
#pragma unroll 16
    for (int d = 0; d < 128; ++d) acc = fmaf(wq[d], wk[d], acc);
    unsigned short hi = f2bf(acc);
    unsigned short lo = f2bf(acc - bf2f(hi));
    unsigned short* dst = WtAll + (size_t)(1664 + h * 128 + b) * KC;
    dst[a] = hi;
    dst[128 + a] = hi;
    dst[256 + a] = lo;
    if (a == 0) {
        float bb = 0.f;
        for (int d = 0; d < 128; ++d) bb = fmaf(bq3[h * 128 + d], wk[d], bb);
        bcat[1536 + h * 128 + b] = bb;
    }
}

// ---------------- mean-V weights: Wvm[j][h*128+a] = Wv3[a][h*128+j]/8 ----------------
__global__ __launch_bounds__(128) void prep_wvm_kernel(
    const float* __restrict__ Wv3, const float* __restrict__ bv3,
    unsigned short* __restrict__ Wvm, float* __restrict__ bvm) {
    int j = blockIdx.x;
    int a = threadIdx.x;
#pragma unroll
    for (int h = 0; h < 8; ++h) {
        float w = Wv3[(size_t)a * 1024 + h * 128 + j] * 0.125f;
        Wvm[(size_t)j * 1024 + h * 128 + a] = f2bf(w);
    }
    if (a == 0) {
        float s = 0.f;
        for (int h = 0; h < 8; ++h) s += bv3[h * 128 + j];
        bvm[j] = s * 0.125f;
    }
}

// ---------------- activation -> split-bf16 A_cat ----------------
__global__ __launch_bounds__(256) void cat_from_kernel(const float* __restrict__ h,
                                                       unsigned short* __restrict__ Acat) {
    int idx = blockIdx.x * 256 + threadIdx.x;
    if (idx >= NPAD * HIDDIM) return;
    int r = idx >> 7, k = idx & 127;
    float x = (r < NNODES) ? h[idx] : 0.f;
    unsigned short hi = f2bf(x);
    unsigned short lo = f2bf(x - bf2f(hi));
    unsigned short* row = Acat + (size_t)r * KC;
    row[k] = hi;
    row[128 + k] = lo;
    row[256 + k] = hi;
}

// ---------------- MFMA GEMM (XCD swizzle) ----------------
template <typename OutT, int KG, int BY>
__global__ __launch_bounds__(256) void gemm_mfma_kernel(
    const unsigned short* __restrict__ Acat, const unsigned short* __restrict__ Wt,
    const float* __restrict__ bias, OutT* __restrict__ C, int M, int nrows) {
    int id = blockIdx.x;
    int xcd = id & 7;
    int idx = id >> 3;
    int bx = (idx / BY) * 8 + xcd;
    int by = idx % BY;
    if (bx >= GXTILES) return;
    int lane = threadIdx.x & 63;
    int wave = threadIdx.x >> 6;
    int nodeBase = bx * 128 + (wave & 1) * 64;
    int featBase = by * 128 + (wave >> 1) * 64;
    int m = lane & 15;
    int q = lane >> 4;
    int ko = q * 8;
    const unsigned short* wptr = Wt + (size_t)(featBase + m) * KC + ko;
    const unsigned short* aptr = Acat + (size_t)(nodeBase + m) * KC + ko;
    floatx4 acc[4][4];
#pragma unroll
    for (int r = 0; r < 4; ++r)
#pragma unroll
        for (int c = 0; c < 4; ++c) acc[r][c] = (floatx4){0.f, 0.f, 0.f, 0.f};
#pragma unroll
    for (int kg = 0; kg < KG; ++kg) {
        short8 a[4], b[4];
#pragma unroll
        for (int r = 0; r < 4; ++r) a[r] = *(const short8*)(wptr + (size_t)r * 16 * KC + kg * 32);
#pragma unroll
        for (int c = 0; c < 4; ++c) b[c] = *(const short8*)(aptr + (size_t)c * 16 * KC + kg * 32);
#pragma unroll
        for (int r = 0; r < 4; ++r)
#pragma unroll
            for (int c = 0; c < 4; ++c)
                acc[r][c] = __builtin_amdgcn_mfma_f32_16x16x32_bf16(a[r], b[c], acc[r][c], 0, 0, 0);
    }
    float4 bv[4];
#pragma unroll
    for (int r = 0; r < 4; ++r) bv[r] = *(const float4*)(bias + featBase + r * 16 + q * 4);
#pragma unroll
    for (int c = 0; c < 4; ++c) {
        int node = nodeBase + c * 16 + m;
        if (node < nrows) {
#pragma unroll
            for (int r = 0; r < 4; ++r) {
                int f0 = featBase + r * 16 + q * 4;
                float v0 = acc[r][c][0] + bv[r].x;
                float v1 = acc[r][c][1] + bv[r].y;
                float v2 = acc[r][c][2] + bv[r].z;
                float v3 = acc[r][c][3] + bv[r].w;
                if (sizeof(OutT) == 2) {
                    ushort4v o = {f2bf(v0), f2bf(v1), f2bf(v2), f2bf(v3)};
                    *(ushort4v*)((unsigned short*)C + (size_t)node * M + f0) = o;
                } else {
                    float4 o = {v0, v1, v2, v3};
                    *(float4*)((float*)C + (size_t)node * M + f0) = o;
                }
            }
        }
    }
}

// ---------------- mean-V GEMM: omean[N][128] = agg[N][1024] @ Wvm^T + bvm ----------------
__global__ __launch_bounds__(256) void gemm_vmean_kernel(
    const unsigned short* __restrict__ agg, const unsigned short* __restrict__ Wvm,
    const float* __restrict__ bvm, float* __restrict__ omean, int nrows) {
    int id = blockIdx.x;
    int xcd = id & 7;
    int idx = id >> 3;
    int bx = idx * 8 + xcd;
    if (bx >= GXTILES) return;
    int lane = threadIdx.x & 63;
    int wave = threadIdx.x >> 6;
    int nodeBase = bx * 128 + (wave & 1) * 64;
    int featHalf = (wave >> 1) * 64;
    int m = lane & 15;
    int q = lane >> 4;
    const unsigned short* wptr = Wvm + (size_t)(featHalf + m) * 1024 + q * 8;
    const unsigned short* aptr = agg + (size_t)(nodeBase + m) * 1024 + q * 8;
    floatx4 acc[4][4];
#pragma unroll
    for (int r = 0; r < 4; ++r)
#pragma unroll
        for (int c = 0; c < 4; ++c) acc[r][c] = (floatx4){0.f, 0.f, 0.f, 0.f};
#pragma unroll
    for (int kg = 0; kg < 32; ++kg) {
        short8 a[4], b[4];
#pragma unroll
        for (int r = 0; r < 4; ++r) a[r] = *(const short8*)(wptr + (size_t)r * 16 * 1024 + kg * 32);
#pragma unroll
        for (int c = 0; c < 4; ++c) b[c] = *(const short8*)(aptr + (size_t)c * 16 * 1024 + kg * 32);
#pragma unroll
        for (int r = 0; r < 4; ++r)
#pragma unroll
            for (int c = 0; c < 4; ++c)
                acc[r][c] = __builtin_amdgcn_mfma_f32_16x16x32_bf16(a[r], b[c], acc[r][c], 0, 0, 0);
    }
    float4 bv[4];
#pragma unroll
    for (int r = 0; r < 4; ++r) bv[r] = *(const float4*)(bvm + featHalf + r * 16 + q * 4);
#pragma unroll
    for (int c = 0; c < 4; ++c) {
        int node = nodeBase + c * 16 + m;
        if (node < nrows) {
#pragma unroll
            for (int r = 0; r < 4; ++r) {
                int f0 = featHalf + r * 16 + q * 4;
                float4 o = {acc[r][c][0] + bv[r].x, acc[r][c][1] + bv[r].y,
                            acc[r][c][2] + bv[r].z, acc[r][c][3] + bv[r].w};
                *(float4*)(omean + (size_t)node * HIDDIM + f0) = o;
            }
        }
    }
}

// ---------------- attention layers 0-2 (plain-exp; qkvs bf16 [N][512]) ----------------
__global__ __launch_bounds__(64) void attn_small_kernel(
    const unsigned short* __restrict__ qkvs,
    const float* __restrict__ Wb,
    const int* __restrict__ offs, const int* __restrict__ csr_src,
    float* __restrict__ out) {
    int i = blockIdx.x;
    int l = threadIdx.x;
    int g = l >> 5;
    int d0 = (l & 31) * 4;
    uint2 qraw = *(const uint2*)(qkvs + (size_t)i * 512 + d0);
    float q0 = bf2f((unsigned short)(qraw.x & 0xffff)), q1 = bf2f((unsigned short)(qraw.x >> 16));
    float q2 = bf2f((unsigned short)(qraw.y & 0xffff)), q3 = bf2f((unsigned short)(qraw.y >> 16));
    int e0 = offs[i], e1 = offs[i + 1];
    float lac = 0.f;
    float a0 = 0.f, a1 = 0.f, a2 = 0.f, a3 = 0.f;
    for (int e = e0 + g; e < e1; e += 2) {
        int sn = csr_src[e];
        const unsigned short* row = qkvs + (size_t)sn * 512;
        uint2 kk = *(const uint2*)(row + 128 + d0);
        uint2 vv = *(const uint2*)(row + 256 + d0);
        float k0 = bf2f((unsigned short)(kk.x & 0xffff)), k1 = bf2f((unsigned short)(kk.x >> 16));
        float k2 = bf2f((unsigned short)(kk.y & 0xffff)), k3 = bf2f((unsigned short)(kk.y >> 16));
        float p = q0 * k0 + q1 * k1 + q2 * k2 + q3 * k3;
        p += __shfl_xor(p, 1);
        p += __shfl_xor(p, 2);
        float w = __expf(p * 0.25f);
        float v0 = bf2f((unsigned short)(vv.x & 0xffff)), v1 = bf2f((unsigned short)(vv.x >> 16));
        float v2 = bf2f((unsigned short)(vv.y & 0xffff)), v3 = bf2f((unsigned short)(vv.y >> 16));
        a0 += w * v0;
        a1 += w * v1;
        a2 += w * v2;
        a3 += w * v3;
        lac += w;
    }
    a0 += __shfl_xor(a0, 32);
    a1 += __shfl_xor(a1, 32);
    a2 += __shfl_xor(a2, 32);
    a3 += __shfl_xor(a3, 32);
    lac += __shfl_xor(lac, 32);
    float inv = 1.f / (lac + 1e-16f);
    float o0 = a0 * inv, o1 = a1 * inv, o2 = a2 * inv, o3 = a3 * inv;
    uint2 rraw = *(const uint2*)(qkvs + (size_t)i * 512 + 384 + d0);
    float r0 = bf2f((unsigned short)(rraw.x & 0xffff)), r1 = bf2f((unsigned short)(rraw.x >> 16));
    float r2 = bf2f((unsigned short)(rraw.y & 0xffff)), r3 = bf2f((unsigned short)(rraw.y >> 16));
    float part = o0 * Wb[d0] + o1 * Wb[d0 + 1] + o2 * Wb[d0 + 2] + o3 * Wb[d0 + 3]
               + r0 * Wb[128 + d0] + r1 * Wb[128 + d0 + 1]
               + r2 * Wb[128 + d0 + 2] + r3 * Wb[128 + d0 + 3]
               + (o0 - r0) * Wb[256 + d0] + (o1 - r1) * Wb[256 + d0 + 1]
               + (o2 - r2) * Wb[256 + d0 + 2] + (o3 - r3) * Wb[256 + d0 + 3];
    if (g) part = 0.f;
#pragma unroll
    for (int msk = 1; msk <= 32; msk <<= 1) part += __shfl_xor(part, msk);
    float gg = 1.f / (1.f + __expf(-part));
    if (g == 0) {
        float4 o4 = {gg * r0 + (1.f - gg) * o0, gg * r1 + (1.f - gg) * o1,
                     gg * r2 + (1.f - gg) * o2, gg * r3 + (1.f - gg) * o3};
        *(float4*)(out + (size_t)i * HIDDIM + d0) = o4;
    }
}

// ---------------- attention layer 3: ALL 8 heads in one block ----------------
// t node-major [N][1152] (t at 0, s at 1024). agg node-major [N][1024] bf16.
__global__ __launch_bounds__(64) void attn_big_kernel(
    const unsigned short* __restrict__ tbuf, const unsigned short* __restrict__ Acat,
    const int* __restrict__ offs, const int* __restrict__ csr_src,
    unsigned short* __restrict__ agg) {
    int i = blockIdx.x;
    int l = threadIdx.x;
    int doff = (l & 7) * 16;
    const unsigned short* tp = tbuf + (size_t)i * 1152 + l * 16;
    uint4 t0 = *(const uint4*)tp;
    uint4 t1 = *(const uint4*)(tp + 8);
    float tq[16];
    tq[0] = bf2f((unsigned short)(t0.x & 0xffff)); tq[1] = bf2f((unsigned short)(t0.x >> 16));
    tq[2] = bf2f((unsigned short)(t0.y & 0xffff)); tq[3] = bf2f((unsigned short)(t0.y >> 16));
    tq[4] = bf2f((unsigned short)(t0.z & 0xffff)); tq[5] = bf2f((unsigned short)(t0.z >> 16));
    tq[6] = bf2f((unsigned short)(t0.w & 0xffff)); tq[7] = bf2f((unsigned short)(t0.w >> 16));
    tq[8] = bf2f((unsigned short)(t1.x & 0xffff)); tq[9] = bf2f((unsigned short)(t1.x >> 16));
    tq[10] = bf2f((unsigned short)(t1.y & 0xffff)); tq[11] = bf2f((unsigned short)(t1.y >> 16));
    tq[12] = bf2f((unsigned short)(t1.z & 0xffff)); tq[13] = bf2f((unsigned short)(t1.z >> 16));
    tq[14] = bf2f((unsigned short)(t1.w & 0xffff)); tq[15] = bf2f((unsigned short)(t1.w >> 16));
    int e0 = offs[i], e1 = offs[i + 1];
    float ac[16];
#pragma unroll
    for (int j = 0; j < 16; ++j) ac[j] = 0.f;
    float lac = 0.f;
    for (int e = e0; e < e1; ++e) {
        int sn = csr_src[e];
        const unsigned short* hp = Acat + (size_t)sn * KC + doff;
        uint4 k0 = *(const uint4*)hp;
        uint4 k1 = *(const uint4*)(hp + 8);
        float kk[16];
        kk[0] = bf2f((unsigned short)(k0.x & 0xffff)); kk[1] = bf2f((unsigned short)(k0.x >> 16));
        kk[2] = bf2f((unsigned short)(k0.y & 0xffff)); kk[3] = bf2f((unsigned short)(k0.y >> 16));
        kk[4] = bf2f((unsigned short)(k0.z & 0xffff)); kk[5] = bf2f((unsigned short)(k0.z >> 16));
        kk[6] = bf2f((unsigned short)(k0.w & 0xffff)); kk[7] = bf2f((unsigned short)(k0.w >> 16));
        kk[8] = bf2f((unsigned short)(k1.x & 0xffff)); kk[9] = bf2f((unsigned short)(k1.x >> 16));
        kk[10] = bf2f((unsigned short)(k1.y & 0xffff)); kk[11] = bf2f((unsigned short)(k1.y >> 16));
        kk[12] = bf2f((unsigned short)(k1.z & 0xffff)); kk[13] = bf2f((unsigned short)(k1.z >> 16));
        kk[14] = bf2f((unsigned short)(k1.w & 0xffff)); kk[15] = bf2f((unsigned short)(k1.w >> 16));
        float p = 0.f;
#pragma unroll
        for (int j = 0; j < 16; ++j) p = fmaf(tq[j], kk[j], p);
        p += __shfl_xor(p, 1);
        p += __shfl_xor(p, 2);
        p += __shfl_xor(p, 4);
        float w = __expf(p * 0.08838834764831845f);
#pragma unroll
        for (int j = 0; j < 16; ++j) ac[j] = fmaf(w, kk[j], ac[j]);
        lac += w;
    }
    float inv = 1.f / (lac + 1e-16f);
    unsigned short* o = agg + (size_t)i * 1024 + l * 16;
    ushort4v o0 = {f2bf(ac[0] * inv), f2bf(ac[1] * inv), f2bf(ac[2] * inv), f2bf(ac[3] * inv)};
    ushort4v o1 = {f2bf(ac[4] * inv), f2bf(ac[5] * inv), f2bf(ac[6] * inv), f2bf(ac[7] * inv)};
    ushort4v o2 = {f2bf(ac[8] * inv), f2bf(ac[9] * inv), f2bf(ac[10] * inv), f2bf(ac[11] * inv)};
    ushort4v o3 = {f2bf(ac[12] * inv), f2bf(ac[13] * inv), f2bf(ac[14] * inv), f2bf(ac[15] * inv)};
    *(ushort4v*)o = o0;
    *(ushort4v*)(o + 4) = o1;
    *(ushort4v*)(o + 8) = o2;
    *(ushort4v*)(o + 12) = o3;
}

// ---------------- beta gate layer 3 (s bf16 from tbuf offset 1024) ----------------
__global__ __launch_bounds__(128) void beta3_kernel(const float* __restrict__ omean,
                                                    const unsigned short* __restrict__ tbuf,
                                                    const float* __restrict__ Wb,
                                                    float* __restrict__ out) {
    int i = blockIdx.x, t = threadIdx.x;
    float o = omean[(size_t)i * HIDDIM + t];
    float r = bf2f(tbuf[(size_t)i * 1152 + 1024 + t]);
    float part = o * Wb[t] + r * Wb[128 + t] + (o - r) * Wb[256 + t];
#pragma unroll
    for (int msk = 1; msk <= 32; msk <<= 1) part += __shfl_xor(part, msk);
    __shared__ float wsum[2];
    if ((t & 63) == 0) wsum[t >> 6] = part;
    __syncthreads();
    float tot = wsum[0] + wsum[1];
    float g = 1.f / (1.f + __expf(-tot));
    out[(size_t)i * HIDDIM + t] = g * r + (1.f - g) * o;
}

// ---------------- batchnorm ----------------
__global__ __launch_bounds__(128) void bn_stats_kernel(const float* __restrict__ x,
                                                       float* __restrict__ stat, int n) {
    int t = threadIdx.x;
    float s = 0.f, sq = 0.f;
    for (int i = blockIdx.x; i < n; i += gridDim.x) {
        float v = x[(size_t)i * HIDDIM + t];
        s += v;
        sq += v * v;
    }
    atomicAdd(&stat[t], s);
    atomicAdd(&stat[HIDDIM + t], sq);
}

__global__ __launch_bounds__(128) void bn_apply_kernel(float* __restrict__ x,
                                                       const float* __restrict__ stat,
                                                       const float* __restrict__ gamma,
                                                       const float* __restrict__ beta, int n,
                                                       unsigned short* __restrict__ cat) {
    int t = threadIdx.x;
    float mu = stat[t] / (float)n;
    float var = stat[HIDDIM + t] / (float)n - mu * mu;
    float rs = rsqrtf(var + 1e-5f);
    float g = gamma[t], b = beta[t];
    for (int i = blockIdx.x; i < n; i += gridDim.x) {
        float v = x[(size_t)i * HIDDIM + t];
        v = fmaxf((v - mu) * rs * g + b, 0.f);
        x[(size_t)i * HIDDIM + t] = v;
        if (cat) {
            unsigned short hi = f2bf(v);
            unsigned short lo = f2bf(v - bf2f(hi));
            unsigned short* row = cat + (size_t)i * KC;
            row[t] = hi;
            row[128 + t] = lo;
            row[256 + t] = hi;
        }
    }
}

// ---------------- pool ----------------
__global__ __launch_bounds__(256) void gb_kernel(const int* __restrict__ batch,
                                                 int* __restrict__ gs,
                                                 int* __restrict__ ge, int n) {
    int i = blockIdx.x * 256 + threadIdx.x;
    if (i >= n) return;
    int b = batch[i];
    if (i == 0 || batch[i - 1] != b) gs[b] = i;
    if (i == n - 1 || batch[i + 1] != b) ge[b] = i + 1;
}

__global__ __launch_bounds__(256) void pool_part_kernel(const float* __restrict__ x,
                                                        const int* __restrict__ gs,
                                                        const int* __restrict__ ge,
                                                        float* __restrict__ out) {
    int g = blockIdx.x, c = blockIdx.y;
    int t = threadIdx.x;
    int f = t & 127, half = t >> 7;
    int s = gs[g], e = ge[g];
    float acc = 0.f;
    for (int i = s + 2 * c + half; i < e; i += 16) acc += x[(size_t)i * HIDDIM + f];
    __shared__ float l0[128];
    if (half == 0) l0[f] = acc;
    __syncthreads();
    if (half == 1) atomicAdd(&out[g * HIDDIM + f], l0[f] + acc);
}

__global__ __launch_bounds__(128) void pool_div_kernel(float* __restrict__ out,
                                                       const int* __restrict__ gs,
                                                       const int* __restrict__ ge) {
    int g = blockIdx.x, t = threadIdx.x;
    int c = ge[g] - gs[g];
    out[g * HIDDIM + t] /= (float)(c > 0 ? c : 1);
}

// ---------------- host ----------------
extern "C" void kernel_launch(void* const* d_in, const int* in_sizes, int n_in,
                              void* d_out, int out_size, void* d_ws, size_t ws_size,
                              hipStream_t stream) {
    const float* x       = (const float*)d_in[0];
    const int*   ei      = (const int*)d_in[1];
    const int*   batch   = (const int*)d_in[2];
    const float* Wp      = (const float*)d_in[3];
    const float* bp      = (const float*)d_in[4];
    const float* Wq      = (const float*)d_in[5];
    const float* bq      = (const float*)d_in[6];
    const float* Wk      = (const float*)d_in[7];
    const float* bk      = (const float*)d_in[8];
    const float* Wv      = (const float*)d_in[9];
    const float* bv      = (const float*)d_in[10];
    const float* Ws      = (const float*)d_in[11];
    const float* bs      = (const float*)d_in[12];
    const float* Wbeta   = (const float*)d_in[13];
    const float* Wq3     = (const float*)d_in[14];
    const float* bq3     = (const float*)d_in[15];
    const float* Wk3     = (const float*)d_in[16];
    const float* bk3     = (const float*)d_in[17];
    const float* Wv3     = (const float*)d_in[18];
    const float* bv3     = (const float*)d_in[19];
    const float* Ws3     = (const float*)d_in[20];
    const float* bs3     = (const float*)d_in[21];
    const float* Wbeta3  = (const float*)d_in[22];
    const float* bn_gamma = (const float*)d_in[23];
    const float* bn_beta  = (const float*)d_in[24];
    float* out = (float*)d_out;
    (void)bk3;

    const int* esrc = ei;
    const int* edst = ei + NEDGES;

    char* wpc = (char*)d_ws;
    auto alloc = [&](size_t nbytes) -> char* {
        char* p = wpc;
        wpc += (nbytes + 255) & ~(size_t)255;
        return p;
    };
    unsigned short* Acat  = (unsigned short*)alloc((size_t)NPAD * KC * 2);      // 15.4 MB
    unsigned short* WtAll = (unsigned short*)alloc((size_t)2816 * KC * 2);      // 2.2 MB
    float* bcat   = (float*)alloc(2688 * 4);
    unsigned short* Wvm   = (unsigned short*)alloc((size_t)128 * 1024 * 2);     // 256 KB
    float* bvm    = (float*)alloc(128 * 4);
    unsigned short* tbuf  = (unsigned short*)alloc((size_t)NPAD * 1152 * 2);    // 46.3 MB (alias qkvs)
    unsigned short* aggb  = (unsigned short*)alloc((size_t)NPAD * 1024 * 2);    // 41 MB
    float* omean  = (float*)alloc((size_t)NNODES * HIDDIM * 4);                 // 10.2 MB
    float* hbuf   = (float*)alloc((size_t)NNODES * HIDDIM * 4);
    float* obuf   = (float*)alloc((size_t)NNODES * HIDDIM * 4);
    int*   deg    = (int*)alloc((2 * NNODES + 128 + 4 * 256) * 4);
    int*   cursor = deg + NNODES;
    int*   gs     = deg + 2 * NNODES;
    int*   ge     = gs + NGRAPH;
    float* bnstat4 = (float*)(deg + 2 * NNODES + 128);
    int*   chunk  = (int*)alloc(NNODES * 4);
    int*   bsum   = (int*)alloc(128 * 4);
    int*   offs   = (int*)alloc((NNODES + 1) * 4);
    int*   csrsrc = (int*)alloc(NEDGES * 4);

    unsigned short* WtQKVS = WtAll;                      // [3][512][KC] q|k|v|s
    unsigned short* Wpt    = WtAll + (size_t)1536 * KC;
    unsigned short* Wt3    = WtAll + (size_t)1664 * KC;  // [1152][KC] t|s3
    float* bQKVS = bcat;          // [3][512]
    float* b3    = bcat + 1536;   // [1152] t|s3
    unsigned short* qkvs = tbuf;  // layers 0-2 alias: [N][512]

    const int TB = 256;
    const int ZWORDS = 2 * NNODES + 128 + 4 * 256;
    zero_kernel<<<(ZWORDS + TB - 1) / TB, TB, 0, stream>>>((float*)deg, ZWORDS);
    count_deg_kernel<<<(NEDGES + TB - 1) / TB, TB, 0, stream>>>(edst, deg, NEDGES);
    const int NB = (NNODES + 255) / 256;
    scan1_kernel<<<NB, 256, 0, stream>>>(deg, chunk, bsum, NNODES);
    scan2_kernel<<<1, 128, 0, stream>>>(bsum, NB);
    scan3_kernel<<<NB, 256, 0, stream>>>(chunk, bsum, offs, NNODES);
    scatter_kernel<<<(NEDGES + TB - 1) / TB, TB, 0, stream>>>(esrc, edst, offs, cursor, csrsrc, NEDGES);
    gb_kernel<<<(NNODES + TB - 1) / TB, TB, 0, stream>>>(batch, gs, ge, NNODES);

    prep_w_kernel<<<2816, 128, 0, stream>>>(Wq, Wk, Wv, Ws, Wp, Ws3, WtAll);
    prep_bias_kernel<<<(2688 + TB - 1) / TB, TB, 0, stream>>>(bq, bk, bv, bs, bs3, bcat);
    mqk_kernel<<<1024, 128, 0, stream>>>(Wq3, Wk3, bq3, WtAll, bcat);
    prep_wvm_kernel<<<128, 128, 0, stream>>>(Wv3, bv3, Wvm, bvm);

    const int CATB = (NPAD * HIDDIM + TB - 1) / TB;
    const int GSW = 8 * ((GXTILES + 7) / 8);  // 160 swizzled x-slots

    cat_from_kernel<<<CATB, TB, 0, stream>>>(x, Acat);
    gemm_mfma_kernel<float, 12, 1><<<GSW * 1, 256, 0, stream>>>(Acat, Wpt, bp, hbuf, 128, NNODES);
    cat_from_kernel<<<CATB, TB, 0, stream>>>(hbuf, Acat);

    for (int li = 0; li < 3; ++li) {
        gemm_mfma_kernel<unsigned short, 8, 4><<<GSW * 4, 256, 0, stream>>>(
            Acat, WtQKVS + (size_t)li * 512 * KC, bQKVS + li * 512, qkvs, 512, NNODES);
        attn_small_kernel<<<NNODES, 64, 0, stream>>>(qkvs, Wbeta + li * 384,
                                                     offs, csrsrc, obuf);
        float* st = bnstat4 + li * 256;
        bn_stats_kernel<<<640, 128, 0, stream>>>(obuf, st, NNODES);
        bn_apply_kernel<<<512, 128, 0, stream>>>(obuf, st, bn_gamma + li * HIDDIM,
                                                 bn_beta + li * HIDDIM, NNODES, Acat);
    }

    // ---- layer 3: t|s GEMM -> fused 8-head aggregate -> mean-V GEMM -> beta ----
    gemm_mfma_kernel<unsigned short, 8, 9><<<GSW * 9, 256, 0, stream>>>(
        Acat, Wt3, b3, tbuf, 1152, NNODES);
    attn_big_kernel<<<NNODES, 64, 0, stream>>>(tbuf, Acat, offs, csrsrc, aggb);
    gemm_vmean_kernel<<<GSW, 256, 0, stream>>>(aggb, Wvm, bvm, omean, NNODES);
    beta3_kernel<<<NNODES, 128, 0, stream>>>(omean, tbuf, Wbeta3, hbuf);
    float* st3 = bnstat4 + 3 * 256;
    bn_stats_kernel<<<640, 128, 0, stream>>>(hbuf, st3, NNODES);
    bn_apply_kernel<<<512, 128, 0, stream>>>(hbuf, st3, bn_gamma + 3 * HIDDIM,
                                             bn_beta + 3 * HIDDIM, NNODES, (unsigned short*)0);

    zero_kernel<<<(NGRAPH * HIDDIM + TB - 1) / TB, TB, 0, stream>>>(out, NGRAPH * HIDDIM);
    pool_part_kernel<<<dim3(NGRAPH, 8), 256, 0, stream>>>(hbuf, gs, ge, out);
    pool_div_kernel<<<NGRAPH, 128, 0, stream>>>(out, gs, ge);
}